// Round 5
// baseline (532.352 us; speedup 1.0000x reference)
//
#include <hip/hip_runtime.h>
#include <cstdint>
#include <cstddef>

#define NVv 192
#define NAa 64
#define TT 128
#define FDd 1024
#define CCc 128
#define EEe 262144
#define NNn 32768

typedef _Float16 f16x8 __attribute__((ext_vector_type(8)));
typedef float f32x4 __attribute__((ext_vector_type(4)));

#define CAP0 65536
#define CAP1 65536
#define CAP2 65536
#define CAP3 98304
#define CAP4 98304
#define CAP5 147456
#define ARENA_TOTAL (CAP0+CAP1+CAP2+CAP3+CAP4+CAP5)   // 540672
#define OFF0 0
#define OFF1 CAP0
#define OFF2 (CAP0+CAP1)
#define OFF3 (CAP0+CAP1+CAP2)
#define OFF4 (CAP0+CAP1+CAP2+CAP3)
#define OFF5 (CAP0+CAP1+CAP2+CAP3+CAP4)

// Edge-MLP LDS row stride: MUST be 136 (272B = 17x16B) so f16x8 LDS ops stay
// 16B-aligned. 132 (264B) made odd rows 8B-aligned -> ds_*_b128 misalignment,
// 2x kernel regression (Round 2 A/B). NOTE (Round 4): SQ_LDS_BANK_CONFLICT
// ~2.76M here is inherent b128 multi-phase counting (2-way, free per HW);
// the scalar-phase swizzle below is kept (harmless) but conflicts are NOT
// the cost driver.
#define MPAD 136

__device__ __forceinline__ void eval_masks(int a, bool m[6]) {
    m[0] = (a == -3); m[1] = (a == -2); m[2] = (a == 3);
    m[3] = (a >= 0) & (a <= 1);
    m[4] = (a >= -1) & (a <= 0);
    m[5] = (a >= -1) & (a <= 1);
}

struct WSmall { const float* p[14]; };
struct PV3  { const _Float16* Wd[3]; const _Float16* Wv[3]; const float* b1[3];
              _Float16* P[3]; _Float16* V[3]; };
struct MLP3 { const _Float16* W2[3]; const float* b2[3];
              const _Float16* P[3]; const _Float16* V[3]; float* AH[3]; };

// ---------------- merged setup: wprep_big | wprep_small | zero(hist+fill) ----------------
__global__ __launch_bounds__(256) void k_setup(
    const float* __restrict__ W011, const float* __restrict__ W012,
    WSmall wsm, _Float16* __restrict__ WT, _Float16* __restrict__ WTs,
    float* __restrict__ hf)
{
    int blk = blockIdx.x, tid = threadIdx.x;
    if (blk < 1024) {                       // wprep_big: 262144 elems
        int idx = blk * 256 + tid;
        int which = idx >> 17;
        int r = idx & 131071;
        int n = r >> 10, k = r & 1023;
        const float* src = which ? W012 : W011;
        WT[idx] = (_Float16)src[k * 128 + n];
    } else if (blk < 1920) {                // wprep_small: 229376 elems
        int idx = (blk - 1024) * 256 + tid;
        int seg = idx >> 14;
        int r = idx & 16383;
        int n = r >> 7, k = r & 127;
        const float* src = wsm.p[seg];
        float v = src[k * 128 + n];
        if (seg < 12 && (seg % 3) == 0) v -= src[16384 + k * 128 + n];
        WTs[idx] = (_Float16)v;
    } else {                                // zero hist+fill: 393216 floats
        size_t i = (size_t)(blk - 1920) * 1024 + (size_t)tid * 4;
        *(float4*)(hf + i) = make_float4(0.f, 0.f, 0.f, 0.f);
    }
}

// ---------------- counting sort phase 1 ----------------
__global__ __launch_bounds__(256) void k_hist(
    const int* __restrict__ attr, const int* __restrict__ edst,
    int* __restrict__ hist)
{
    int e = blockIdx.x * 256 + threadIdx.x;
    int a = attr[e], d = edst[e];
    bool m[6]; eval_masks(a, m);
#pragma unroll
    for (int j = 0; j < 6; ++j)
        if (m[j]) atomicAdd(&hist[j * NNn + d], 1);
}

// ---------------- hierarchical exclusive scan ----------------
__global__ __launch_bounds__(256) void k_scan_a(
    const int* __restrict__ hist, int* __restrict__ base, int* __restrict__ bsum)
{
    __shared__ int wsum[4];
    int idx = blockIdx.x * 256 + threadIdx.x;
    int tid = threadIdx.x, lane = tid & 63, wv = tid >> 6;
    int v = hist[idx];
    int x = v;
#pragma unroll
    for (int off = 1; off < 64; off <<= 1) {
        int y = __shfl_up(x, off, 64);
        if (lane >= off) x += y;
    }
    if (lane == 63) wsum[wv] = x;
    __syncthreads();
    int add = 0;
    for (int w = 0; w < wv; ++w) add += wsum[w];
    base[idx] = add + x - v;
    if (tid == 255) bsum[blockIdx.x] = add + x;
}

__global__ __launch_bounds__(384) void k_scan_b(int* __restrict__ bsum, int* __restrict__ cnts)
{
    int wv = threadIdx.x >> 6;
    int lane = threadIdx.x & 63;
    int run = 0;
#pragma unroll
    for (int c0 = 0; c0 < 128; c0 += 64) {
        int v = bsum[wv * 128 + c0 + lane];
        int x = v;
#pragma unroll
        for (int off = 1; off < 64; off <<= 1) {
            int y = __shfl_up(x, off, 64);
            if (lane >= off) x += y;
        }
        bsum[wv * 128 + c0 + lane] = run + (x - v);
        run += __shfl(x, 63, 64);
    }
    if (lane == 0) cnts[wv] = run;
}

__global__ __launch_bounds__(256) void k_scan_c(int* __restrict__ base, const int* __restrict__ bsum)
{
    base[blockIdx.x * 256 + threadIdx.x] += bsum[blockIdx.x];
}

// ---------------- merged: fill sorted lists | zero AH atomicMax-path rows ----------------
__global__ __launch_bounds__(256) void k_fill_zero(
    const int* __restrict__ esrc, const int* __restrict__ edst,
    const int* __restrict__ attr, const int* __restrict__ base,
    int* __restrict__ fill, int2* __restrict__ arena, const int* __restrict__ hist,
    float* __restrict__ AH0, float* __restrict__ AH1,
    float* __restrict__ AH2, float* __restrict__ AH3)
{
    int blk = blockIdx.x, tid = threadIdx.x;
    if (blk < 1024) {
        int e = blk * 256 + tid;
        int a = attr[e];
        int s = esrc[e], d = edst[e];
        bool m[6]; eval_masks(a, m);
        const int caps[6] = {CAP0, CAP1, CAP2, CAP3, CAP4, CAP5};
        const int offs[6] = {OFF0, OFF1, OFF2, OFF3, OFF4, OFF5};
#pragma unroll
        for (int j = 0; j < 6; ++j) {
            if (m[j]) {
                int pos = base[j * NNn + d] + atomicAdd(&fill[j * NNn + d], 1);
                if (pos < caps[j]) arena[offs[j] + pos] = make_int2(s, d);
            }
        }
    } else {
        int zb = blk - 1024;                  // 0..2047
        int col = tid & 127, sub = tid >> 7;
        const int js[4] = {1, 3, 4, 5};
        float* AHs[4] = {AH0, AH1, AH2, AH3};
        for (int d = zb * 2 + sub; d < NNn; d += 2048 * 2) {
#pragma unroll
            for (int jj = 0; jj < 4; ++jj) {
                int j = js[jj];
                int c = hist[j * NNn + d];
                bool need;
                if (c == 0) need = true;
                else {
                    int b = base[j * NNn + d], e = b + c;
                    need = ((b & 63) == 0) || ((e & 63) == 0) || ((b >> 6) != ((e - 1) >> 6));
                }
                if (need) AHs[jj][(size_t)d * 128 + col] = 0.f;
            }
        }
    }
}

// ---------------- input projection: 64-row blocks, full-K, fused bias ----------------
// Round 5: was 128-row/512-thr/split-K/double-buffer (2 blocks/CU, all pipes idle,
// 62.5us) + separate k_reduce (~50MB traffic). Now: 512 x 256-thr blocks, 64 rows
// each, full K=1024 in 8 chunks, single-buffered B (34.8KB LDS -> 4 blocks/CU),
// bias fused, X written directly, k_reduce deleted.
__global__ __launch_bounds__(256, 4) void k_proj(
    const float* __restrict__ xv, const float* __restrict__ xa,
    const _Float16* __restrict__ BTv, const _Float16* __restrict__ BTa,
    const float* __restrict__ b011, const float* __restrict__ b012,
    float* __restrict__ X)
{
    __shared__ _Float16 Bl[128][136];        // 34816 B single buffer
    const int tid = threadIdx.x, wave = tid >> 6, lane = tid & 63;
    const int tile = blockIdx.x;             // 0..511, 64 rows each
    const float* A; const _Float16* BT; const float* bias; int mbase, obase;
    if (tile < 384) { A = xv; BT = BTv; bias = b011; mbase = tile * 64; obase = mbase; }
    else { A = xa; BT = BTa; bias = b012; mbase = (tile - 384) * 64;
           obase = 24576 + (tile - 384) * 64; }

    const int mrow = mbase + wave * 16 + (lane & 15);
    const int fk   = (lane >> 4) * 8;
    f32x4 acc[8];
#pragma unroll
    for (int i = 0; i < 8; ++i) acc[i] = (f32x4){0,0,0,0};

    // stage B chunk kc (128n x 128k f16) with 256 threads
#define STAGE_B(kc_) {                                                          \
    _Pragma("unroll")                                                           \
    for (int it = 0; it < 8; ++it) {                                            \
        int c = it * 256 + tid;                                                 \
        int n = c >> 4, koff = (c & 15) * 8;                                    \
        *(f16x8*)&Bl[n][koff] = *(const f16x8*)(BT + (size_t)n * 1024 + (kc_) * 128 + koff); \
    } }

#define LOAD_A(kc_, dst_) {                                                     \
    _Pragma("unroll")                                                           \
    for (int t4 = 0; t4 < 4; ++t4) {                                            \
        const float* asrc = A + (size_t)mrow * 1024 + (kc_) * 128 + t4 * 32 + fk; \
        float4 a0 = *(const float4*)asrc;                                       \
        float4 a1 = *(const float4*)(asrc + 4);                                 \
        dst_[t4] = (f16x8){ (_Float16)a0.x, (_Float16)a0.y, (_Float16)a0.z, (_Float16)a0.w, \
                            (_Float16)a1.x, (_Float16)a1.y, (_Float16)a1.z, (_Float16)a1.w }; \
    } }

    f16x8 af[4], nf[4];
    STAGE_B(0);
    LOAD_A(0, af);
    __syncthreads();

    for (int kc = 0; kc < 8; ++kc) {
        if (kc < 7) LOAD_A(kc + 1, nf);      // issue next A early: HBM latency hides under MFMA
#pragma unroll
        for (int t4 = 0; t4 < 4; ++t4)
#pragma unroll
            for (int nt = 0; nt < 8; ++nt) {
                f16x8 bf = *(const f16x8*)&Bl[nt * 16 + (lane & 15)][t4 * 32 + fk];
                acc[nt] = __builtin_amdgcn_mfma_f32_16x16x32_f16(af[t4], bf, acc[nt], 0, 0, 0);
            }
        __syncthreads();                     // Bl fully consumed
        if (kc < 7) {
            STAGE_B(kc + 1);
#pragma unroll
            for (int t4 = 0; t4 < 4; ++t4) af[t4] = nf[t4];
            __syncthreads();                 // Bl ready
        }
    }
#undef STAGE_B
#undef LOAD_A

    // epilogue: acc + bias -> X via LDS coalesce (4 waves, disjoint regions;
    // same-wave write->read ordering, same pattern as proven pv_body epilogue)
    float* Hsf = (float*)&Bl[0][0] + (size_t)wave * 16 * 132;   // 4*16*132*4 = 33792 <= 34816
    const int cbase = lane & 15, rloc = (lane >> 4) * 4;
#pragma unroll
    for (int nt = 0; nt < 8; ++nt) {
        int c2 = nt * 16 + cbase;
        float bv = bias[c2];
#pragma unroll
        for (int rr = 0; rr < 4; ++rr)
            Hsf[(rloc + rr) * 132 + c2] = acc[nt][rr] + bv;
    }
#pragma unroll
    for (int it = 0; it < 8; ++it) {
        int id = it * 64 + lane;
        int row = id >> 5, off = (id & 31) * 4;
        float4 v = *(float4*)&Hsf[row * 132 + off];
        *(float4*)&X[(size_t)(obase + wave * 16 + row) * 128 + off] = v;
    }
}

// ---------------- PV GEMM body (shared by audio + pv3) ----------------
__device__ __forceinline__ void pv_body(
    const float* __restrict__ A, const _Float16* __restrict__ BT1,
    const float* __restrict__ b1, const _Float16* __restrict__ BT2,
    _Float16* __restrict__ P, _Float16* __restrict__ V, int tileblk,
    _Float16 (*Bl1)[136], _Float16 (*Bl2)[136], float* bb)
{
    const int tid = threadIdx.x, wave = tid >> 6, lane = tid & 63;
    const int r0 = tileblk * 64 + wave * 16;
    const int fk = (lane >> 4) * 8;
    const int mrow = r0 + (lane & 15);
    float4 a0[4], a1[4];
#pragma unroll
    for (int t4 = 0; t4 < 4; ++t4) {
        const float* asrc = A + (size_t)mrow * 128 + t4 * 32 + fk;
        a0[t4] = *(const float4*)asrc;
        a1[t4] = *(const float4*)(asrc + 4);
    }
#pragma unroll
    for (int it = 0; it < 8; ++it) {
        int c = it * 256 + tid;
        int n = c >> 4, koff = (c & 15) * 8;
        *(f16x8*)&Bl1[n][koff] = *(const f16x8*)(BT1 + (size_t)n * 128 + koff);
        *(f16x8*)&Bl2[n][koff] = *(const f16x8*)(BT2 + (size_t)n * 128 + koff);
    }
    if (tid < 128) bb[tid] = b1[tid];
    __syncthreads();

    f16x8 af[4];
#pragma unroll
    for (int t4 = 0; t4 < 4; ++t4)
        af[t4] = (f16x8){ (_Float16)a0[t4].x, (_Float16)a0[t4].y, (_Float16)a0[t4].z, (_Float16)a0[t4].w,
                          (_Float16)a1[t4].x, (_Float16)a1[t4].y, (_Float16)a1[t4].z, (_Float16)a1[t4].w };
    f32x4 acc1[8], acc2[8];
#pragma unroll
    for (int i = 0; i < 8; ++i) { acc1[i] = (f32x4){0,0,0,0}; acc2[i] = (f32x4){0,0,0,0}; }
#pragma unroll
    for (int t4 = 0; t4 < 4; ++t4)
#pragma unroll
        for (int nt = 0; nt < 8; ++nt) {
            f16x8 bf1 = *(const f16x8*)&Bl1[nt * 16 + (lane & 15)][t4 * 32 + fk];
            f16x8 bf2 = *(const f16x8*)&Bl2[nt * 16 + (lane & 15)][t4 * 32 + fk];
            acc1[nt] = __builtin_amdgcn_mfma_f32_16x16x32_f16(af[t4], bf1, acc1[nt], 0, 0, 0);
            acc2[nt] = __builtin_amdgcn_mfma_f32_16x16x32_f16(af[t4], bf2, acc2[nt], 0, 0, 0);
        }
    __syncthreads();
    _Float16* Hs = &Bl1[0][0] + (size_t)wave * 16 * 136;
    const int cbase = lane & 15, rloc = (lane >> 4) * 4;
#pragma unroll
    for (int nt = 0; nt < 8; ++nt) {
        int c2 = nt * 16 + cbase;
        float bvv = bb[c2];
#pragma unroll
        for (int rr = 0; rr < 4; ++rr)
            Hs[(rloc + rr) * 136 + c2] = (_Float16)(acc1[nt][rr] + bvv);
    }
#pragma unroll
    for (int it = 0; it < 4; ++it) {
        int id = it * 64 + lane;
        int row = id >> 4, koff = (id & 15) * 8;
        *(f16x8*)&P[(size_t)(r0 + row) * 128 + koff] = *(f16x8*)&Hs[row * 136 + koff];
    }
#pragma unroll
    for (int nt = 0; nt < 8; ++nt) {
        int c2 = nt * 16 + cbase;
#pragma unroll
        for (int rr = 0; rr < 4; ++rr)
            Hs[(rloc + rr) * 136 + c2] = (_Float16)acc2[nt][rr];
    }
#pragma unroll
    for (int it = 0; it < 4; ++it) {
        int id = it * 64 + lane;
        int row = id >> 4, koff = (id & 15) * 8;
        *(f16x8*)&V[(size_t)(r0 + row) * 128 + koff] = *(f16x8*)&Hs[row * 136 + koff];
    }
}

__global__ __launch_bounds__(256) void k_pv(
    const float* __restrict__ A, const _Float16* __restrict__ BT1,
    const float* __restrict__ b1, const _Float16* __restrict__ BT2,
    _Float16* __restrict__ P, _Float16* __restrict__ V)
{
    __shared__ _Float16 Bl1[128][136];
    __shared__ _Float16 Bl2[128][136];
    __shared__ float bb[128];
    pv_body(A, BT1, b1, BT2, P, V, blockIdx.x, Bl1, Bl2, bb);
}

// all 3 branches in one dispatch: 1536 blocks = branch(3) x tile(512)
__global__ __launch_bounds__(256) void k_pv3(const float* __restrict__ A, PV3 p)
{
    __shared__ _Float16 Bl1[128][136];
    __shared__ _Float16 Bl2[128][136];
    __shared__ float bb[128];
    int b = blockIdx.x >> 9, t = blockIdx.x & 511;
    pv_body(A, p.Wd[b], p.b1[b], p.Wv[b], p.P[b], p.V[b], t, Bl1, Bl2, bb);
}

// ---------------- edge MLP: W2 load (once per 512-thread block) ----------------
__device__ __forceinline__ void mlp_loadW(
    const _Float16* __restrict__ W2T, const float* __restrict__ b2,
    _Float16 (*W2l)[MPAD], float* __restrict__ b2l)
{
    int tid = threadIdx.x;       // 0..511
#pragma unroll
    for (int i = 0; i < 4; ++i) {
        int c = tid + i * 512;
        int n = c >> 4, koff = (c & 15) * 8;
        *(f16x8*)&W2l[n][koff] = *(const f16x8*)(W2T + n * 128 + koff);
    }
    if (tid < 128) b2l[tid] = b2[tid];
}

// ---------------- edge MLP tile body (team-scoped; 256 threads/team) ----------------
__device__ __forceinline__ void mlp_tile2(
    const _Float16* __restrict__ P, const _Float16* __restrict__ V,
    const int2* __restrict__ list, int cnt, int t, float* __restrict__ agg,
    _Float16 (*Rl)[MPAD], const _Float16 (*W2l)[MPAD], const float* __restrict__ b2l,
    int2* __restrict__ eSD, unsigned char* __restrict__ gstart,
    int* __restrict__ gdst, int* __restrict__ ngrS)
{
    const int tid  = threadIdx.x & 255;      // team-local
    const int wave = tid >> 6;               // 0..3 within team
    const int lane = threadIdx.x & 63;
    if (tid < 64) {
        int e = t * 64 + tid;
        eSD[tid] = (e < cnt) ? list[e] : make_int2(0, -1);
    }
    __syncthreads();
    if (tid < 64) {
        int d = eSD[tid].y;
        bool flag = (tid == 0) || (d != eSD[tid - 1].y);
        unsigned long long bm = __ballot(flag);
        int rank = (int)__popcll(bm & ((1ull << tid) - 1ull));
        if (flag) { gstart[rank] = (unsigned char)tid; gdst[rank] = d; }
        if (tid == 0) {
            int ng = (int)__popcll(bm);
            *ngrS = ng;
            gstart[ng] = 64;
        }
    }
    const int rrow = tid >> 4;
    const int rch  = (tid & 15) * 8;
#pragma unroll
    for (int p = 0; p < 4; ++p) {
        int i = p * 16 + rrow;
        int2 sd = eSD[i];
        f16x8 rv = {0, 0, 0, 0, 0, 0, 0, 0};
        if (sd.y >= 0) {
            f16x8 pv = *(const f16x8*)(P + (size_t)sd.y * 128 + rch);
            f16x8 vv = *(const f16x8*)(V + (size_t)sd.x * 128 + rch);
            rv = pv + vv;
#pragma unroll
            for (int q = 0; q < 8; ++q)
                rv[q] = (rv[q] > (_Float16)0.f) ? rv[q] : (_Float16)0.f;
        }
        *(f16x8*)&Rl[i][rch] = rv;
    }
    __syncthreads();

    const int frow  = wave * 16 + (lane & 15);
    const int fq    = (lane >> 4) * 8;
    f32x4 acc[8];
#pragma unroll
    for (int i = 0; i < 8; ++i) acc[i] = (f32x4){0,0,0,0};
#pragma unroll
    for (int t4 = 0; t4 < 4; ++t4) {
        f16x8 af = *(const f16x8*)&Rl[frow][t4 * 32 + fq];
#pragma unroll
        for (int nt = 0; nt < 8; ++nt) {
            f16x8 bf = *(const f16x8*)&W2l[nt * 16 + (lane & 15)][t4 * 32 + fq];
            acc[nt] = __builtin_amdgcn_mfma_f32_16x16x32_f16(af, bf, acc[nt], 0, 0, 0);
        }
    }
    __syncthreads();
    const int rbase = wave * 16 + (lane >> 4) * 4;
    const int cbase = lane & 15;
#pragma unroll
    for (int nt = 0; nt < 8; ++nt) {
        int c2 = nt * 16 + cbase;
        float bv = b2l[c2];
#pragma unroll
        for (int rr = 0; rr < 4; ++rr) {
            int row = rbase + rr;
            Rl[row][c2 ^ (((row >> 3) & 1) << 4)] = (_Float16)fmaxf(acc[nt][rr] + bv, 0.f);
        }
    }
    __syncthreads();
    const int col  = tid & 127;
    const int half = tid >> 7;
    int ng = *ngrS;
    for (int g = half; g < ng; g += 2) {
        int s = gstart[g], e = gstart[g + 1];
        int d = gdst[g];
        if (d < 0) continue;
        float m = 0.f;
        for (int i = s; i < e; ++i)
            m = fmaxf(m, (float)Rl[i][col ^ (((i >> 3) & 1) << 4)]);
        size_t o = (size_t)d * 128 + col;
        if (s == 0 || e == 64)
            atomicMax((unsigned int*)&agg[o], __float_as_uint(m));
        else
            agg[o] = m;
    }
}

// audio (single mask): 512-thread blocks, 2 tile-teams share one W2 LDS copy
__global__ __launch_bounds__(512, 2) void k_edge_mlp(
    const _Float16* __restrict__ P, const _Float16* __restrict__ V,
    const _Float16* __restrict__ W2T, const float* __restrict__ b2,
    const int2* __restrict__ list, const int* __restrict__ cntp, int cap,
    float* __restrict__ agg)
{
    __shared__ _Float16 W2l[128][MPAD];
    __shared__ float b2l[128];
    __shared__ _Float16 Rl[2][64][MPAD];
    __shared__ int2 eSD[2][64];
    __shared__ unsigned char gstart[2][68];
    __shared__ int gdst[2][64];
    __shared__ int ngrS[2];
    int cnt = min(*cntp, cap);
    int ntiles = (cnt + 63) >> 6;
    if ((int)blockIdx.x * 2 >= ntiles) return;
    mlp_loadW(W2T, b2, W2l, b2l);
    const int team = threadIdx.x >> 8;
    for (int base = blockIdx.x * 2; base < ntiles; base += gridDim.x * 2) {
        mlp_tile2(P, V, list, cnt, base + team, agg,
                  Rl[team], W2l, b2l, eSD[team], gstart[team], gdst[team], &ngrS[team]);
    }
}

// all 3 branch masks: branch-static grid-stride blocks (W2 loaded once/block)
#define MLP3_G0 146
#define MLP3_G1 146
#define MLP3_G2 220
#define MLP3_GRID (MLP3_G0 + MLP3_G1 + MLP3_G2)   // 512

__global__ __launch_bounds__(512, 2) void k_edge_mlp3(
    MLP3 p, const int2* __restrict__ arena, const int* __restrict__ cnts)
{
    __shared__ _Float16 W2l[128][MPAD];
    __shared__ float b2l[128];
    __shared__ _Float16 Rl[2][64][MPAD];
    __shared__ int2 eSD[2][64];
    __shared__ unsigned char gstart[2][68];
    __shared__ int gdst[2][64];
    __shared__ int ngrS[2];
    const int caps[3] = {CAP3, CAP4, CAP5};
    const int offs[3] = {OFF3, OFF4, OFF5};
    int blk = blockIdx.x;
    int b, i, G;
    if (blk < MLP3_G0)                 { b = 0; i = blk;                       G = MLP3_G0; }
    else if (blk < MLP3_G0 + MLP3_G1)  { b = 1; i = blk - MLP3_G0;             G = MLP3_G1; }
    else                               { b = 2; i = blk - (MLP3_G0 + MLP3_G1); G = MLP3_G2; }
    int cnt = min(cnts[3 + b], caps[b]);
    int ntiles = (cnt + 63) >> 6;
    if (i * 2 >= ntiles) return;
    mlp_loadW(p.W2[b], p.b2[b], W2l, b2l);
    const int team = threadIdx.x >> 8;
    const int2* list = arena + offs[b];
    for (int base = i * 2; base < ntiles; base += G * 2) {
        mlp_tile2(p.P[b], p.V[b], list, cnt, base + team, p.AH[b],
                  Rl[team], W2l, b2l, eSD[team], gstart[team], gdst[team], &ngrS[team]);
    }
}

// ---------------- CSR gather-reduce kernels ----------------
__global__ __launch_bounds__(256) void k_csr_vpa(
    const float* __restrict__ X, const int2* __restrict__ list,
    const int* __restrict__ base, const int* __restrict__ cntarr, int cap,
    float* __restrict__ S)
{
    int col = threadIdx.x & 127;
    int sub = threadIdx.x >> 7;
    for (int d = blockIdx.x * 2 + sub; d < NNn; d += gridDim.x * 2) {
        int c = cntarr[d];
        float v = 0.f;
        if (c > 0) {
            int b = base[d];
            int end = min(b + c, cap);
            float mx = -3.0e38f;
            for (int i = b; i < end; ++i)
                mx = fmaxf(mx, X[(size_t)list[i].x * 128 + col]);
            v = fmaxf(X[(size_t)d * 128 + col] + mx, 0.f);
        }
        S[(size_t)d * 128 + col] = v;
    }
}

__global__ __launch_bounds__(256) void k_csr_acv(
    const float* __restrict__ X, const float* __restrict__ ares,
    const int2* __restrict__ list,
    const int* __restrict__ base, const int* __restrict__ cntarr, int cap,
    float* __restrict__ S)
{
    int col = threadIdx.x & 127;
    int sub = threadIdx.x >> 7;
    for (int d = blockIdx.x * 2 + sub; d < NNn; d += gridDim.x * 2) {
        int c = cntarr[d];
        float v = 0.f;
        if (c > 0) {
            int b = base[d];
            int end = min(b + c, cap);
            float s = 0.f;
            for (int i = b; i < end; ++i) {
                int sr = list[i].x;
                s += ares[sr] * X[(size_t)sr * 128 + col];
            }
            v = fmaxf(s + (float)c * X[(size_t)d * 128 + col], 0.f);
        }
        S[(size_t)d * 128 + col] = v;
    }
}

// sage mean at target nodes for all 3 branches in one dispatch
__global__ __launch_bounds__(256) void k_meanc3(
    float* const AH1, float* const AH2, float* const AH3,
    const int2* __restrict__ arena,
    const int* __restrict__ base, const int* __restrict__ hist,
    const int* __restrict__ spk, int ntarg,
    float* __restrict__ S1c, float* __restrict__ AHc)
{
    int col = threadIdx.x & 127;
    int sub = threadIdx.x >> 7;
    int step = spk[0] * TT;
    const int caps[3] = {CAP3, CAP4, CAP5};
    const int offs[3] = {OFF3, OFF4, OFF5};
    const float* AHs[3] = {AH1, AH2, AH3};
    int total = 3 * ntarg;
    for (int ci2 = blockIdx.x * 2 + sub; ci2 < total; ci2 += gridDim.x * 2) {
        int b = ci2 / ntarg;
        int ci = ci2 - b * ntarg;
        int j = 3 + b;
        const float* AH = AHs[b];
        const int2* list = arena + offs[b];
        int d = (ci >> 7) * step + (ci & 127);
        int c = hist[j * NNn + d];
        float v = 0.f;
        if (c > 0) {
            int bs = base[j * NNn + d];
            int end = min(bs + c, caps[b]);
            float s = 0.f;
            for (int i = bs; i < end; ++i)
                s += AH[(size_t)list[i].x * 128 + col];
            v = s / (float)c;
        }
        S1c[(size_t)ci2 * 128 + col] = v;
        AHc[(size_t)ci2 * 128 + col] = AH[(size_t)d * 128 + col];
    }
}

// ---------------- fc ----------------
__global__ __launch_bounds__(256) void k_fc(
    const float* __restrict__ A, const float* __restrict__ W,
    const float* __restrict__ b, float* __restrict__ ares)
{
    int node = blockIdx.x * 4 + (threadIdx.x >> 6);
    int lane = threadIdx.x & 63;
    const float* row = A + (size_t)node * 128;
    float v = row[lane] * W[lane] + row[lane + 64] * W[lane + 64];
#pragma unroll
    for (int off = 32; off > 0; off >>= 1) v += __shfl_down(v, off, 64);
    if (lane == 0) ares[node] = v + b[0];
}

// ---------------- fused SAGE output ----------------
__global__ __launch_bounds__(256) void k_sage_out(
    const float* __restrict__ S1c, const float* __restrict__ AHc,
    const _Float16* __restrict__ WlT, const _Float16* __restrict__ WrT,
    const float* __restrict__ bl, float* __restrict__ out, int ntarg)
{
    __shared__ _Float16 Al[64][40];
    __shared__ _Float16 Bl[128][40];
    const int tid  = threadIdx.x;
    const int wave = tid >> 6;
    const int lane = tid & 63;
    const int m0   = blockIdx.x * 64;

    f32x4 accB[8], accO[8];
#pragma unroll
    for (int i = 0; i < 8; ++i) { accB[i] = (f32x4){0,0,0,0}; accO[i] = (f32x4){0,0,0,0}; }

    const int ar = tid >> 2;
    const int ak = (tid & 3) * 8;
    const int fr = wave * 16 + (lane & 15);
    const int fk = (lane >> 4) * 8;
    const int rbase = wave * 16 + (lane >> 4) * 4;
    const int cbase = lane & 15;

    for (int seg = 0; seg < 6; ++seg) {
        int b = seg >> 1, which = seg & 1;
        const float* A = (which ? AHc : S1c) + (size_t)b * ntarg * 128;
        const _Float16* BT = which ? WrT : WlT;
        for (int k0 = 0; k0 < 128; k0 += 32) {
            __syncthreads();
            const float* asrc = A + (size_t)(m0 + ar) * 128 + (k0 + ak);
            float4 a0 = *(const float4*)asrc;
            float4 a1 = *(const float4*)(asrc + 4);
            f16x8 av = { (_Float16)a0.x, (_Float16)a0.y, (_Float16)a0.z, (_Float16)a0.w,
                         (_Float16)a1.x, (_Float16)a1.y, (_Float16)a1.z, (_Float16)a1.w };
            *(f16x8*)&Al[ar][ak] = av;
#pragma unroll
            for (int i = 0; i < 2; ++i) {
                int c = tid + i * 256;
                int n = c >> 2, koff = (c & 3) * 8;
                *(f16x8*)&Bl[n][koff] = *(const f16x8*)(BT + (size_t)n * 128 + k0 + koff);
            }
            __syncthreads();
            f16x8 af = *(const f16x8*)&Al[fr][fk];
#pragma unroll
            for (int nt = 0; nt < 8; ++nt) {
                f16x8 bf = *(const f16x8*)&Bl[nt * 16 + (lane & 15)][fk];
                accB[nt] = __builtin_amdgcn_mfma_f32_16x16x32_f16(af, bf, accB[nt], 0, 0, 0);
            }
        }
        if (which) {
#pragma unroll
            for (int nt = 0; nt < 8; ++nt) {
                int col = nt * 16 + cbase;
                float bv = bl[col];
#pragma unroll
                for (int rr = 0; rr < 4; ++rr) {
                    accO[nt][rr] += fmaxf(accB[nt][rr] + bv, 0.f);
                    accB[nt][rr] = 0.f;
                }
            }
        }
    }
#pragma unroll
    for (int nt = 0; nt < 8; ++nt) {
        int col = nt * 16 + cbase;
#pragma unroll
        for (int rr = 0; rr < 4; ++rr)
            out[(size_t)(m0 + rbase + rr) * 128 + col] = accO[nt][rr];
    }
}

extern "C" void kernel_launch(void* const* d_in, const int* in_sizes, int n_in,
                              void* d_out, int out_size, void* d_ws, size_t ws_size,
                              hipStream_t stream)
{
    (void)in_sizes; (void)n_in; (void)ws_size;
    const float* xv   = (const float*)d_in[0];
    const float* xa   = (const float*)d_in[1];
    const float* W011 = (const float*)d_in[2];
    const float* b011 = (const float*)d_in[3];
    const float* W012 = (const float*)d_in[4];
    const float* b012 = (const float*)d_in[5];
    const float* ecW1[4] = {(const float*)d_in[6],  (const float*)d_in[10],
                            (const float*)d_in[14], (const float*)d_in[18]};
    const float* ecb1[4] = {(const float*)d_in[7],  (const float*)d_in[11],
                            (const float*)d_in[15], (const float*)d_in[19]};
    const float* ecW2[4] = {(const float*)d_in[8],  (const float*)d_in[12],
                            (const float*)d_in[16], (const float*)d_in[20]};
    const float* ecb2[4] = {(const float*)d_in[9],  (const float*)d_in[13],
                            (const float*)d_in[17], (const float*)d_in[21]};
    const float* sageWl = (const float*)d_in[22];
    const float* sagebl = (const float*)d_in[23];
    const float* sageWr = (const float*)d_in[24];
    const float* fcW    = (const float*)d_in[25];
    const float* fcb    = (const float*)d_in[26];
    const int*   esrc   = (const int*)d_in[27];
    const int*   edst   = esrc + EEe;
    const int*   attr   = (const int*)d_in[28];
    const int*   spk    = (const int*)d_in[29];
    float* out = (float*)d_out;
    const int ntarg = out_size >> 7;       // 8192 target nodes

    const size_t NC = (size_t)NNn * CCc;   // 4194304
    float* ws   = (float*)d_ws;
    float* X    = ws;                      // [N,C] f32; later P1/V1 overlay
    float* S1   = ws + 1 * NC;             // vpa out / S1c slices
    float* XV2  = ws + 2 * NC;             // xv2
    float* AHc  = ws + 3 * NC;             // P2/V2 overlay, then AH compact snapshots
    float* AH0  = ws + 4 * NC;
    float* AH1  = ws + 5 * NC;
    float* AH2  = ws + 6 * NC;
    float* AH3  = ws + 7 * NC;
    _Float16* P0 = (_Float16*)(ws + 8 * NC);
    _Float16* V0 = P0 + NC;
    _Float16* P1 = (_Float16*)X;           // X dead after csr_acv
    _Float16* V1 = P1 + NC;
    _Float16* P2 = (_Float16*)AHc;         // AHc written only by meanc3 (after mlp3)
    _Float16* V2 = P2 + NC;
    float* ARES = ws + 9 * NC;             // 32768
    int*   cnts = (int*)(ARES + NNn);
    int*   bsum = cnts + 16;
    int*   hist = bsum + 1024;             // 6*32768
    int*   fill = hist + 6 * NNn;
    int*   base = fill + 6 * NNn;
    int2*  arena = (int2*)(base + 6 * NNn);
    _Float16* WT = (_Float16*)(arena + ARENA_TOTAL);

    const _Float16* W011T = WT;
    const _Float16* W012T = WT + 131072;
    _Float16* WTs = WT + 262144;
    const _Float16* WlT   = WTs + 12 * 16384;
    const _Float16* WrT   = WTs + 13 * 16384;

    // ---- merged setup + counting-sort CSR build ----
    WSmall wsm;
    for (int i = 0; i < 4; ++i) {
        wsm.p[3*i + 0] = ecW1[i];
        wsm.p[3*i + 1] = ecW1[i] + 16384;
        wsm.p[3*i + 2] = ecW2[i];
    }
    wsm.p[12] = sageWl; wsm.p[13] = sageWr;
    k_setup<<<2304, 256, 0, stream>>>(W011, W012, wsm, WT, WTs, (float*)hist);
    k_hist<<<EEe / 256, 256, 0, stream>>>(attr, edst, hist);
    k_scan_a<<<768, 256, 0, stream>>>(hist, base, bsum);
    k_scan_b<<<1, 384, 0, stream>>>(bsum, cnts);
    k_scan_c<<<768, 256, 0, stream>>>(base, bsum);
    k_fill_zero<<<3072, 256, 0, stream>>>(esrc, edst, attr, base, fill, arena, hist,
                                          AH0, AH1, AH2, AH3);

    // ---- input projection: full-K, fused bias, writes X directly ----
    k_proj<<<512, 256, 0, stream>>>(xv, xa, W011T, W012T, b011, b012, X);
    // ---- xa_g (mask 0) ----
    k_csr_vpa<<<2048, 256, 0, stream>>>(X, arena + OFF0, base + 0 * NNn,
                                        hist + 0 * NNn, CAP0, S1);
    // ---- EdgeConv A (mask 1) ----
    k_pv<<<512, 256, 0, stream>>>(S1, WTs, ecb1[0], WTs + 16384, P0, V0);
    k_edge_mlp<<<512, 512, 0, stream>>>(P0, V0, WTs + 2 * 16384, ecb2[0],
                                        arena + OFF1, cnts + 1, CAP1, AH0);
    k_fc<<<NNn / 4, 256, 0, stream>>>(AH0, fcW, fcb, ARES);
    // ---- xv2 (mask 2); XV2 fully overwritten; last read of X ----
    k_csr_acv<<<2048, 256, 0, stream>>>(X, ARES, arena + OFF2, base + 2 * NNn,
                                        hist + 2 * NNn, CAP2, XV2);
    // ---- three branches merged ----
    PV3 pv3;
    MLP3 m3;
    _Float16* Pb[3] = {P0, P1, P2};
    _Float16* Vb[3] = {V0, V1, V2};
    float* AHb[3] = {AH1, AH2, AH3};
    for (int b = 0; b < 3; ++b) {
        _Float16* Wd = WTs + (3 * (b + 1)) * 16384;
        pv3.Wd[b] = Wd; pv3.Wv[b] = Wd + 16384; pv3.b1[b] = ecb1[b + 1];
        pv3.P[b] = Pb[b]; pv3.V[b] = Vb[b];
        m3.W2[b] = Wd + 2 * 16384; m3.b2[b] = ecb2[b + 1];
        m3.P[b] = Pb[b]; m3.V[b] = Vb[b]; m3.AH[b] = AHb[b];
    }
    k_pv3<<<1536, 256, 0, stream>>>(XV2, pv3);
    k_edge_mlp3<<<MLP3_GRID, 512, 0, stream>>>(m3, arena, cnts);
    k_meanc3<<<2048, 256, 0, stream>>>(AH1, AH2, AH3, arena, base, hist,
                                       spk, ntarg, S1, AHc);
    // ---- fused SAGE epilogue -> d_out ----
    k_sage_out<<<ntarg / 64, 256, 0, stream>>>(S1, AHc, WlT, WrT, sagebl, out, ntarg);
}

// Round 6
// 521.485 us; speedup vs baseline: 1.0208x; 1.0208x over previous
//
#include <hip/hip_runtime.h>
#include <cstdint>
#include <cstddef>

#define NVv 192
#define NAa 64
#define TT 128
#define FDd 1024
#define CCc 128
#define EEe 262144
#define NNn 32768

typedef _Float16 f16x8 __attribute__((ext_vector_type(8)));
typedef float f32x4 __attribute__((ext_vector_type(4)));

#define CAP0 65536
#define CAP1 65536
#define CAP2 65536
#define CAP3 98304
#define CAP4 98304
#define CAP5 147456
#define ARENA_TOTAL (CAP0+CAP1+CAP2+CAP3+CAP4+CAP5)   // 540672
#define OFF0 0
#define OFF1 CAP0
#define OFF2 (CAP0+CAP1)
#define OFF3 (CAP0+CAP1+CAP2)
#define OFF4 (CAP0+CAP1+CAP2+CAP3)
#define OFF5 (CAP0+CAP1+CAP2+CAP3+CAP4)

// Edge-MLP LDS row stride: MUST be 136 (272B = 17x16B) so f16x8 LDS ops stay
// 16B-aligned (132 -> misaligned b128, 2x regression; Round 2 A/B).
#define MPAD 136

__device__ __forceinline__ void eval_masks(int a, bool m[6]) {
    m[0] = (a == -3); m[1] = (a == -2); m[2] = (a == 3);
    m[3] = (a >= 0) & (a <= 1);
    m[4] = (a >= -1) & (a <= 0);
    m[5] = (a >= -1) & (a <= 1);
}

struct WSmall { const float* p[14]; };
struct PV3  { const _Float16* Wd[3]; const _Float16* Wv[3]; const float* b1[3];
              _Float16* P[3]; _Float16* V[3]; };
struct MLP3 { const _Float16* W2[3]; const float* b2[3];
              const _Float16* P[3]; const _Float16* V[3]; float* AH[3]; };

// ---------------- merged setup: wprep_big | wprep_small | zero(hist+fill) ----------------
__global__ __launch_bounds__(256) void k_setup(
    const float* __restrict__ W011, const float* __restrict__ W012,
    WSmall wsm, _Float16* __restrict__ WT, _Float16* __restrict__ WTs,
    float* __restrict__ hf)
{
    int blk = blockIdx.x, tid = threadIdx.x;
    if (blk < 1024) {                       // wprep_big: 262144 elems
        int idx = blk * 256 + tid;
        int which = idx >> 17;
        int r = idx & 131071;
        int n = r >> 10, k = r & 1023;
        const float* src = which ? W012 : W011;
        WT[idx] = (_Float16)src[k * 128 + n];
    } else if (blk < 1920) {                // wprep_small: 229376 elems
        int idx = (blk - 1024) * 256 + tid;
        int seg = idx >> 14;
        int r = idx & 16383;
        int n = r >> 7, k = r & 127;
        const float* src = wsm.p[seg];
        float v = src[k * 128 + n];
        if (seg < 12 && (seg % 3) == 0) v -= src[16384 + k * 128 + n];
        WTs[idx] = (_Float16)v;
    } else {                                // zero hist+fill: 393216 floats
        size_t i = (size_t)(blk - 1920) * 1024 + (size_t)tid * 4;
        *(float4*)(hf + i) = make_float4(0.f, 0.f, 0.f, 0.f);
    }
}

// ---------------- counting sort phase 1 ----------------
__global__ __launch_bounds__(256) void k_hist(
    const int* __restrict__ attr, const int* __restrict__ edst,
    int* __restrict__ hist)
{
    int e = blockIdx.x * 256 + threadIdx.x;
    int a = attr[e], d = edst[e];
    bool m[6]; eval_masks(a, m);
#pragma unroll
    for (int j = 0; j < 6; ++j)
        if (m[j]) atomicAdd(&hist[j * NNn + d], 1);
}

// ---------------- hierarchical exclusive scan ----------------
__global__ __launch_bounds__(256) void k_scan_a(
    const int* __restrict__ hist, int* __restrict__ base, int* __restrict__ bsum)
{
    __shared__ int wsum[4];
    int idx = blockIdx.x * 256 + threadIdx.x;
    int tid = threadIdx.x, lane = tid & 63, wv = tid >> 6;
    int v = hist[idx];
    int x = v;
#pragma unroll
    for (int off = 1; off < 64; off <<= 1) {
        int y = __shfl_up(x, off, 64);
        if (lane >= off) x += y;
    }
    if (lane == 63) wsum[wv] = x;
    __syncthreads();
    int add = 0;
    for (int w = 0; w < wv; ++w) add += wsum[w];
    base[idx] = add + x - v;
    if (tid == 255) bsum[blockIdx.x] = add + x;
}

__global__ __launch_bounds__(384) void k_scan_b(int* __restrict__ bsum, int* __restrict__ cnts)
{
    int wv = threadIdx.x >> 6;
    int lane = threadIdx.x & 63;
    int run = 0;
#pragma unroll
    for (int c0 = 0; c0 < 128; c0 += 64) {
        int v = bsum[wv * 128 + c0 + lane];
        int x = v;
#pragma unroll
        for (int off = 1; off < 64; off <<= 1) {
            int y = __shfl_up(x, off, 64);
            if (lane >= off) x += y;
        }
        bsum[wv * 128 + c0 + lane] = run + (x - v);
        run += __shfl(x, 63, 64);
    }
    if (lane == 0) cnts[wv] = run;
}

__global__ __launch_bounds__(256) void k_scan_c(int* __restrict__ base, const int* __restrict__ bsum)
{
    base[blockIdx.x * 256 + threadIdx.x] += bsum[blockIdx.x];
}

// ---------------- merged: fill sorted lists | zero AH atomicMax-path rows ----------------
__global__ __launch_bounds__(256) void k_fill_zero(
    const int* __restrict__ esrc, const int* __restrict__ edst,
    const int* __restrict__ attr, const int* __restrict__ base,
    int* __restrict__ fill, int2* __restrict__ arena, const int* __restrict__ hist,
    float* __restrict__ AH0, float* __restrict__ AH1,
    float* __restrict__ AH2, float* __restrict__ AH3)
{
    int blk = blockIdx.x, tid = threadIdx.x;
    if (blk < 1024) {
        int e = blk * 256 + tid;
        int a = attr[e];
        int s = esrc[e], d = edst[e];
        bool m[6]; eval_masks(a, m);
        const int caps[6] = {CAP0, CAP1, CAP2, CAP3, CAP4, CAP5};
        const int offs[6] = {OFF0, OFF1, OFF2, OFF3, OFF4, OFF5};
#pragma unroll
        for (int j = 0; j < 6; ++j) {
            if (m[j]) {
                int pos = base[j * NNn + d] + atomicAdd(&fill[j * NNn + d], 1);
                if (pos < caps[j]) arena[offs[j] + pos] = make_int2(s, d);
            }
        }
    } else {
        int zb = blk - 1024;                  // 0..2047
        int col = tid & 127, sub = tid >> 7;
        const int js[4] = {1, 3, 4, 5};
        float* AHs[4] = {AH0, AH1, AH2, AH3};
        for (int d = zb * 2 + sub; d < NNn; d += 2048 * 2) {
#pragma unroll
            for (int jj = 0; jj < 4; ++jj) {
                int j = js[jj];
                int c = hist[j * NNn + d];
                bool need;
                if (c == 0) need = true;
                else {
                    int b = base[j * NNn + d], e = b + c;
                    need = ((b & 63) == 0) || ((e & 63) == 0) || ((b >> 6) != ((e - 1) >> 6));
                }
                if (need) AHs[jj][(size_t)d * 128 + col] = 0.f;
            }
        }
    }
}

// ---------------- input projection: split-K, double-buffered B, A-prefetch depth 2 ----
// Round 6: Round-4 structure (512 x 512-thr, 16 waves/CU, 62.5us) + 2-deep A
// prefetch. R4 was Little's-law-bound: 1.64 TB/s = 16 waves/CU x ~12 x 16B
// outstanding / ~900cyc. Issuing chunk kc+2's A loads (8 more in flight, issued
// BEFORE B staging so HBM loads progress under B's L2 waits) -> ~1.67x MLP.
__global__ __launch_bounds__(512) void k_proj(
    const float* __restrict__ xv, const float* __restrict__ xa,
    const _Float16* __restrict__ BTv, const _Float16* __restrict__ BTa,
    float* __restrict__ Pp0, float* __restrict__ Pp1)
{
    __shared__ _Float16 Bl[2][128][136];
    const int tid = threadIdx.x, wave = tid >> 6, lane = tid & 63;
    const int tile = blockIdx.x >> 1, kh = blockIdx.x & 1;
    const float* A; const _Float16* BT; int mbase, obase;
    if (tile < 192) { A = xv; BT = BTv; mbase = tile * 128; obase = mbase; }
    else { A = xa; BT = BTa; mbase = (tile - 192) * 128; obase = 24576 + mbase; }
    float* Pout = kh ? Pp1 : Pp0;
    const int kbase = kh * 512;

    const int mrow = mbase + wave * 16 + (lane & 15);
    const int fk   = (lane >> 4) * 8;
    f32x4 acc[8];
#pragma unroll
    for (int i = 0; i < 8; ++i) acc[i] = (f32x4){0,0,0,0};

#define STAGE_B(buf_, kc_) {                                                    \
    _Pragma("unroll")                                                           \
    for (int it = 0; it < 4; ++it) {                                            \
        int c = it * 512 + tid;                                                 \
        int n = c >> 4, koff = (c & 15) * 8;                                    \
        *(f16x8*)&Bl[buf_][n][koff] =                                           \
            *(const f16x8*)(BT + (size_t)n * 1024 + kbase + (kc_) * 128 + koff); \
    } }

#define LOAD_A(kc_, dst_) {                                                     \
    _Pragma("unroll")                                                           \
    for (int t4 = 0; t4 < 4; ++t4) {                                            \
        const float* asrc = A + (size_t)mrow * 1024 + kbase + (kc_) * 128 + t4 * 32 + fk; \
        float4 a0 = *(const float4*)asrc;                                       \
        float4 a1 = *(const float4*)(asrc + 4);                                 \
        dst_[t4] = (f16x8){ (_Float16)a0.x, (_Float16)a0.y, (_Float16)a0.z, (_Float16)a0.w, \
                            (_Float16)a1.x, (_Float16)a1.y, (_Float16)a1.z, (_Float16)a1.w }; \
    } }

    f16x8 af[4], nf1[4], nf2[4];
    LOAD_A(0, af);            // HBM loads first: longest latency
    LOAD_A(1, nf1);
    STAGE_B(0, 0);            // B from L2 (hot after first tiles)
    __syncthreads();

#pragma unroll
    for (int kc = 0; kc < 4; ++kc) {
        const int cur = kc & 1;
        if (kc < 2) LOAD_A(kc + 2, nf2);          // A prefetch depth 2
        if (kc < 3) STAGE_B(cur ^ 1, kc + 1);     // B double-buffer stage
#pragma unroll
        for (int t4 = 0; t4 < 4; ++t4)
#pragma unroll
            for (int nt = 0; nt < 8; ++nt) {
                f16x8 bf = *(const f16x8*)&Bl[cur][nt * 16 + (lane & 15)][t4 * 32 + fk];
                acc[nt] = __builtin_amdgcn_mfma_f32_16x16x32_f16(af[t4], bf, acc[nt], 0, 0, 0);
            }
        if (kc < 3) {
#pragma unroll
            for (int t4 = 0; t4 < 4; ++t4) af[t4] = nf1[t4];
        }
        if (kc < 2) {
#pragma unroll
            for (int t4 = 0; t4 < 4; ++t4) nf1[t4] = nf2[t4];
        }
        __syncthreads();
    }
#undef STAGE_B
#undef LOAD_A

    const int cbase = lane & 15, rloc = (lane >> 4) * 4;
    const int wgrp = wave & 3;
    float* Hsf = (float*)&Bl[0][0][0] + (size_t)wgrp * 16 * 132;
#pragma unroll
    for (int grp = 0; grp < 2; ++grp) {
        if ((wave >> 2) == grp) {
#pragma unroll
            for (int nt = 0; nt < 8; ++nt) {
                int c2 = nt * 16 + cbase;
#pragma unroll
                for (int rr = 0; rr < 4; ++rr)
                    Hsf[(rloc + rr) * 132 + c2] = acc[nt][rr];
            }
#pragma unroll
            for (int it = 0; it < 8; ++it) {
                int id = it * 64 + lane;
                int row = id >> 5, off = (id & 31) * 4;
                float4 v = *(float4*)&Hsf[row * 132 + off];
                *(float4*)&Pout[(size_t)(obase + wave * 16 + row) * 128 + off] = v;
            }
        }
        __syncthreads();
    }
}

// ---------------- reduce: X = Pp0 + Pp1 + bias(row) ----------------
__global__ __launch_bounds__(256) void k_reduce(
    const float* __restrict__ Pp0, const float* __restrict__ Pp1,
    const float* __restrict__ b011, const float* __restrict__ b012,
    float* __restrict__ X)
{
    size_t f = (size_t)blockIdx.x * 256 + threadIdx.x;
    size_t i = f * 4;
    int col = (int)(i & 127);
    int row = (int)(i >> 7);
    const float* bias = (row < 24576) ? b011 : b012;
    float4 a = *(const float4*)(Pp0 + i);
    float4 b = *(const float4*)(Pp1 + i);
    float4 bb = *(const float4*)(bias + col);
    *(float4*)(X + i) = make_float4(a.x + b.x + bb.x, a.y + b.y + bb.y,
                                    a.z + b.z + bb.z, a.w + b.w + bb.w);
}

// ---------------- PV GEMM body (shared by audio + pv3) ----------------
__device__ __forceinline__ void pv_body(
    const float* __restrict__ A, const _Float16* __restrict__ BT1,
    const float* __restrict__ b1, const _Float16* __restrict__ BT2,
    _Float16* __restrict__ P, _Float16* __restrict__ V, int tileblk,
    _Float16 (*Bl1)[136], _Float16 (*Bl2)[136], float* bb)
{
    const int tid = threadIdx.x, wave = tid >> 6, lane = tid & 63;
    const int r0 = tileblk * 64 + wave * 16;
    const int fk = (lane >> 4) * 8;
    const int mrow = r0 + (lane & 15);
    float4 a0[4], a1[4];
#pragma unroll
    for (int t4 = 0; t4 < 4; ++t4) {
        const float* asrc = A + (size_t)mrow * 128 + t4 * 32 + fk;
        a0[t4] = *(const float4*)asrc;
        a1[t4] = *(const float4*)(asrc + 4);
    }
#pragma unroll
    for (int it = 0; it < 8; ++it) {
        int c = it * 256 + tid;
        int n = c >> 4, koff = (c & 15) * 8;
        *(f16x8*)&Bl1[n][koff] = *(const f16x8*)(BT1 + (size_t)n * 128 + koff);
        *(f16x8*)&Bl2[n][koff] = *(const f16x8*)(BT2 + (size_t)n * 128 + koff);
    }
    if (tid < 128) bb[tid] = b1[tid];
    __syncthreads();

    f16x8 af[4];
#pragma unroll
    for (int t4 = 0; t4 < 4; ++t4)
        af[t4] = (f16x8){ (_Float16)a0[t4].x, (_Float16)a0[t4].y, (_Float16)a0[t4].z, (_Float16)a0[t4].w,
                          (_Float16)a1[t4].x, (_Float16)a1[t4].y, (_Float16)a1[t4].z, (_Float16)a1[t4].w };
    f32x4 acc1[8], acc2[8];
#pragma unroll
    for (int i = 0; i < 8; ++i) { acc1[i] = (f32x4){0,0,0,0}; acc2[i] = (f32x4){0,0,0,0}; }
#pragma unroll
    for (int t4 = 0; t4 < 4; ++t4)
#pragma unroll
        for (int nt = 0; nt < 8; ++nt) {
            f16x8 bf1 = *(const f16x8*)&Bl1[nt * 16 + (lane & 15)][t4 * 32 + fk];
            f16x8 bf2 = *(const f16x8*)&Bl2[nt * 16 + (lane & 15)][t4 * 32 + fk];
            acc1[nt] = __builtin_amdgcn_mfma_f32_16x16x32_f16(af[t4], bf1, acc1[nt], 0, 0, 0);
            acc2[nt] = __builtin_amdgcn_mfma_f32_16x16x32_f16(af[t4], bf2, acc2[nt], 0, 0, 0);
        }
    __syncthreads();
    _Float16* Hs = &Bl1[0][0] + (size_t)wave * 16 * 136;
    const int cbase = lane & 15, rloc = (lane >> 4) * 4;
#pragma unroll
    for (int nt = 0; nt < 8; ++nt) {
        int c2 = nt * 16 + cbase;
        float bvv = bb[c2];
#pragma unroll
        for (int rr = 0; rr < 4; ++rr)
            Hs[(rloc + rr) * 136 + c2] = (_Float16)(acc1[nt][rr] + bvv);
    }
#pragma unroll
    for (int it = 0; it < 4; ++it) {
        int id = it * 64 + lane;
        int row = id >> 4, koff = (id & 15) * 8;
        *(f16x8*)&P[(size_t)(r0 + row) * 128 + koff] = *(f16x8*)&Hs[row * 136 + koff];
    }
#pragma unroll
    for (int nt = 0; nt < 8; ++nt) {
        int c2 = nt * 16 + cbase;
#pragma unroll
        for (int rr = 0; rr < 4; ++rr)
            Hs[(rloc + rr) * 136 + c2] = (_Float16)acc2[nt][rr];
    }
#pragma unroll
    for (int it = 0; it < 4; ++it) {
        int id = it * 64 + lane;
        int row = id >> 4, koff = (id & 15) * 8;
        *(f16x8*)&V[(size_t)(r0 + row) * 128 + koff] = *(f16x8*)&Hs[row * 136 + koff];
    }
}

__global__ __launch_bounds__(256) void k_pv(
    const float* __restrict__ A, const _Float16* __restrict__ BT1,
    const float* __restrict__ b1, const _Float16* __restrict__ BT2,
    _Float16* __restrict__ P, _Float16* __restrict__ V)
{
    __shared__ _Float16 Bl1[128][136];
    __shared__ _Float16 Bl2[128][136];
    __shared__ float bb[128];
    pv_body(A, BT1, b1, BT2, P, V, blockIdx.x, Bl1, Bl2, bb);
}

// all 3 branches in one dispatch: 1536 blocks = branch(3) x tile(512)
__global__ __launch_bounds__(256) void k_pv3(const float* __restrict__ A, PV3 p)
{
    __shared__ _Float16 Bl1[128][136];
    __shared__ _Float16 Bl2[128][136];
    __shared__ float bb[128];
    int b = blockIdx.x >> 9, t = blockIdx.x & 511;
    pv_body(A, p.Wd[b], p.b1[b], p.Wv[b], p.P[b], p.V[b], t, Bl1, Bl2, bb);
}

// ---------------- edge MLP: W2 load (once per 512-thread block) ----------------
__device__ __forceinline__ void mlp_loadW(
    const _Float16* __restrict__ W2T, const float* __restrict__ b2,
    _Float16 (*W2l)[MPAD], float* __restrict__ b2l)
{
    int tid = threadIdx.x;       // 0..511
#pragma unroll
    for (int i = 0; i < 4; ++i) {
        int c = tid + i * 512;
        int n = c >> 4, koff = (c & 15) * 8;
        *(f16x8*)&W2l[n][koff] = *(const f16x8*)(W2T + n * 128 + koff);
    }
    if (tid < 128) b2l[tid] = b2[tid];
}

// ---------------- edge MLP tile body (team-scoped; 256 threads/team) ----------------
__device__ __forceinline__ void mlp_tile2(
    const _Float16* __restrict__ P, const _Float16* __restrict__ V,
    const int2* __restrict__ list, int cnt, int t, float* __restrict__ agg,
    _Float16 (*Rl)[MPAD], const _Float16 (*W2l)[MPAD], const float* __restrict__ b2l,
    int2* __restrict__ eSD, unsigned char* __restrict__ gstart,
    int* __restrict__ gdst, int* __restrict__ ngrS)
{
    const int tid  = threadIdx.x & 255;      // team-local
    const int wave = tid >> 6;               // 0..3 within team
    const int lane = threadIdx.x & 63;
    if (tid < 64) {
        int e = t * 64 + tid;
        eSD[tid] = (e < cnt) ? list[e] : make_int2(0, -1);
    }
    __syncthreads();
    if (tid < 64) {
        int d = eSD[tid].y;
        bool flag = (tid == 0) || (d != eSD[tid - 1].y);
        unsigned long long bm = __ballot(flag);
        int rank = (int)__popcll(bm & ((1ull << tid) - 1ull));
        if (flag) { gstart[rank] = (unsigned char)tid; gdst[rank] = d; }
        if (tid == 0) {
            int ng = (int)__popcll(bm);
            *ngrS = ng;
            gstart[ng] = 64;
        }
    }
    const int rrow = tid >> 4;
    const int rch  = (tid & 15) * 8;
#pragma unroll
    for (int p = 0; p < 4; ++p) {
        int i = p * 16 + rrow;
        int2 sd = eSD[i];
        f16x8 rv = {0, 0, 0, 0, 0, 0, 0, 0};
        if (sd.y >= 0) {
            f16x8 pv = *(const f16x8*)(P + (size_t)sd.y * 128 + rch);
            f16x8 vv = *(const f16x8*)(V + (size_t)sd.x * 128 + rch);
            rv = pv + vv;
#pragma unroll
            for (int q = 0; q < 8; ++q)
                rv[q] = (rv[q] > (_Float16)0.f) ? rv[q] : (_Float16)0.f;
        }
        *(f16x8*)&Rl[i][rch] = rv;
    }
    __syncthreads();

    const int frow  = wave * 16 + (lane & 15);
    const int fq    = (lane >> 4) * 8;
    f32x4 acc[8];
#pragma unroll
    for (int i = 0; i < 8; ++i) acc[i] = (f32x4){0,0,0,0};
#pragma unroll
    for (int t4 = 0; t4 < 4; ++t4) {
        f16x8 af = *(const f16x8*)&Rl[frow][t4 * 32 + fq];
#pragma unroll
        for (int nt = 0; nt < 8; ++nt) {
            f16x8 bf = *(const f16x8*)&W2l[nt * 16 + (lane & 15)][t4 * 32 + fq];
            acc[nt] = __builtin_amdgcn_mfma_f32_16x16x32_f16(af, bf, acc[nt], 0, 0, 0);
        }
    }
    __syncthreads();
    const int rbase = wave * 16 + (lane >> 4) * 4;
    const int cbase = lane & 15;
#pragma unroll
    for (int nt = 0; nt < 8; ++nt) {
        int c2 = nt * 16 + cbase;
        float bv = b2l[c2];
#pragma unroll
        for (int rr = 0; rr < 4; ++rr) {
            int row = rbase + rr;
            Rl[row][c2 ^ (((row >> 3) & 1) << 4)] = (_Float16)fmaxf(acc[nt][rr] + bv, 0.f);
        }
    }
    __syncthreads();
    const int col  = tid & 127;
    const int half = tid >> 7;
    int ng = *ngrS;
    for (int g = half; g < ng; g += 2) {
        int s = gstart[g], e = gstart[g + 1];
        int d = gdst[g];
        if (d < 0) continue;
        float m = 0.f;
        for (int i = s; i < e; ++i)
            m = fmaxf(m, (float)Rl[i][col ^ (((i >> 3) & 1) << 4)]);
        size_t o = (size_t)d * 128 + col;
        if (s == 0 || e == 64)
            atomicMax((unsigned int*)&agg[o], __float_as_uint(m));
        else
            agg[o] = m;
    }
}

// audio (single mask): 512-thread blocks, 2 tile-teams share one W2 LDS copy
__global__ __launch_bounds__(512, 2) void k_edge_mlp(
    const _Float16* __restrict__ P, const _Float16* __restrict__ V,
    const _Float16* __restrict__ W2T, const float* __restrict__ b2,
    const int2* __restrict__ list, const int* __restrict__ cntp, int cap,
    float* __restrict__ agg)
{
    __shared__ _Float16 W2l[128][MPAD];
    __shared__ float b2l[128];
    __shared__ _Float16 Rl[2][64][MPAD];
    __shared__ int2 eSD[2][64];
    __shared__ unsigned char gstart[2][68];
    __shared__ int gdst[2][64];
    __shared__ int ngrS[2];
    int cnt = min(*cntp, cap);
    int ntiles = (cnt + 63) >> 6;
    if ((int)blockIdx.x * 2 >= ntiles) return;
    mlp_loadW(W2T, b2, W2l, b2l);
    const int team = threadIdx.x >> 8;
    for (int base = blockIdx.x * 2; base < ntiles; base += gridDim.x * 2) {
        mlp_tile2(P, V, list, cnt, base + team, agg,
                  Rl[team], W2l, b2l, eSD[team], gstart[team], gdst[team], &ngrS[team]);
    }
}

// all 3 branch masks: branch-static grid-stride blocks (W2 loaded once/block)
#define MLP3_G0 146
#define MLP3_G1 146
#define MLP3_G2 220
#define MLP3_GRID (MLP3_G0 + MLP3_G1 + MLP3_G2)   // 512

__global__ __launch_bounds__(512, 2) void k_edge_mlp3(
    MLP3 p, const int2* __restrict__ arena, const int* __restrict__ cnts)
{
    __shared__ _Float16 W2l[128][MPAD];
    __shared__ float b2l[128];
    __shared__ _Float16 Rl[2][64][MPAD];
    __shared__ int2 eSD[2][64];
    __shared__ unsigned char gstart[2][68];
    __shared__ int gdst[2][64];
    __shared__ int ngrS[2];
    const int caps[3] = {CAP3, CAP4, CAP5};
    const int offs[3] = {OFF3, OFF4, OFF5};
    int blk = blockIdx.x;
    int b, i, G;
    if (blk < MLP3_G0)                 { b = 0; i = blk;                       G = MLP3_G0; }
    else if (blk < MLP3_G0 + MLP3_G1)  { b = 1; i = blk - MLP3_G0;             G = MLP3_G1; }
    else                               { b = 2; i = blk - (MLP3_G0 + MLP3_G1); G = MLP3_G2; }
    int cnt = min(cnts[3 + b], caps[b]);
    int ntiles = (cnt + 63) >> 6;
    if (i * 2 >= ntiles) return;
    mlp_loadW(p.W2[b], p.b2[b], W2l, b2l);
    const int team = threadIdx.x >> 8;
    const int2* list = arena + offs[b];
    for (int base = i * 2; base < ntiles; base += G * 2) {
        mlp_tile2(p.P[b], p.V[b], list, cnt, base + team, p.AH[b],
                  Rl[team], W2l, b2l, eSD[team], gstart[team], gdst[team], &ngrS[team]);
    }
}

// ---------------- CSR gather-reduce kernels ----------------
__global__ __launch_bounds__(256) void k_csr_vpa(
    const float* __restrict__ X, const int2* __restrict__ list,
    const int* __restrict__ base, const int* __restrict__ cntarr, int cap,
    float* __restrict__ S)
{
    int col = threadIdx.x & 127;
    int sub = threadIdx.x >> 7;
    for (int d = blockIdx.x * 2 + sub; d < NNn; d += gridDim.x * 2) {
        int c = cntarr[d];
        float v = 0.f;
        if (c > 0) {
            int b = base[d];
            int end = min(b + c, cap);
            float mx = -3.0e38f;
            for (int i = b; i < end; ++i)
                mx = fmaxf(mx, X[(size_t)list[i].x * 128 + col]);
            v = fmaxf(X[(size_t)d * 128 + col] + mx, 0.f);
        }
        S[(size_t)d * 128 + col] = v;
    }
}

__global__ __launch_bounds__(256) void k_csr_acv(
    const float* __restrict__ X, const float* __restrict__ ares,
    const int2* __restrict__ list,
    const int* __restrict__ base, const int* __restrict__ cntarr, int cap,
    float* __restrict__ S)
{
    int col = threadIdx.x & 127;
    int sub = threadIdx.x >> 7;
    for (int d = blockIdx.x * 2 + sub; d < NNn; d += gridDim.x * 2) {
        int c = cntarr[d];
        float v = 0.f;
        if (c > 0) {
            int b = base[d];
            int end = min(b + c, cap);
            float s = 0.f;
            for (int i = b; i < end; ++i) {
                int sr = list[i].x;
                s += ares[sr] * X[(size_t)sr * 128 + col];
            }
            v = fmaxf(s + (float)c * X[(size_t)d * 128 + col], 0.f);
        }
        S[(size_t)d * 128 + col] = v;
    }
}

// sage mean at target nodes for all 3 branches in one dispatch
__global__ __launch_bounds__(256) void k_meanc3(
    float* const AH1, float* const AH2, float* const AH3,
    const int2* __restrict__ arena,
    const int* __restrict__ base, const int* __restrict__ hist,
    const int* __restrict__ spk, int ntarg,
    float* __restrict__ S1c, float* __restrict__ AHc)
{
    int col = threadIdx.x & 127;
    int sub = threadIdx.x >> 7;
    int step = spk[0] * TT;
    const int caps[3] = {CAP3, CAP4, CAP5};
    const int offs[3] = {OFF3, OFF4, OFF5};
    const float* AHs[3] = {AH1, AH2, AH3};
    int total = 3 * ntarg;
    for (int ci2 = blockIdx.x * 2 + sub; ci2 < total; ci2 += gridDim.x * 2) {
        int b = ci2 / ntarg;
        int ci = ci2 - b * ntarg;
        int j = 3 + b;
        const float* AH = AHs[b];
        const int2* list = arena + offs[b];
        int d = (ci >> 7) * step + (ci & 127);
        int c = hist[j * NNn + d];
        float v = 0.f;
        if (c > 0) {
            int bs = base[j * NNn + d];
            int end = min(bs + c, caps[b]);
            float s = 0.f;
            for (int i = bs; i < end; ++i)
                s += AH[(size_t)list[i].x * 128 + col];
            v = s / (float)c;
        }
        S1c[(size_t)ci2 * 128 + col] = v;
        AHc[(size_t)ci2 * 128 + col] = AH[(size_t)d * 128 + col];
    }
}

// ---------------- fc ----------------
__global__ __launch_bounds__(256) void k_fc(
    const float* __restrict__ A, const float* __restrict__ W,
    const float* __restrict__ b, float* __restrict__ ares)
{
    int node = blockIdx.x * 4 + (threadIdx.x >> 6);
    int lane = threadIdx.x & 63;
    const float* row = A + (size_t)node * 128;
    float v = row[lane] * W[lane] + row[lane + 64] * W[lane + 64];
#pragma unroll
    for (int off = 32; off > 0; off >>= 1) v += __shfl_down(v, off, 64);
    if (lane == 0) ares[node] = v + b[0];
}

// ---------------- fused SAGE output ----------------
__global__ __launch_bounds__(256) void k_sage_out(
    const float* __restrict__ S1c, const float* __restrict__ AHc,
    const _Float16* __restrict__ WlT, const _Float16* __restrict__ WrT,
    const float* __restrict__ bl, float* __restrict__ out, int ntarg)
{
    __shared__ _Float16 Al[64][40];
    __shared__ _Float16 Bl[128][40];
    const int tid  = threadIdx.x;
    const int wave = tid >> 6;
    const int lane = tid & 63;
    const int m0   = blockIdx.x * 64;

    f32x4 accB[8], accO[8];
#pragma unroll
    for (int i = 0; i < 8; ++i) { accB[i] = (f32x4){0,0,0,0}; accO[i] = (f32x4){0,0,0,0}; }

    const int ar = tid >> 2;
    const int ak = (tid & 3) * 8;
    const int fr = wave * 16 + (lane & 15);
    const int fk = (lane >> 4) * 8;
    const int rbase = wave * 16 + (lane >> 4) * 4;
    const int cbase = lane & 15;

    for (int seg = 0; seg < 6; ++seg) {
        int b = seg >> 1, which = seg & 1;
        const float* A = (which ? AHc : S1c) + (size_t)b * ntarg * 128;
        const _Float16* BT = which ? WrT : WlT;
        for (int k0 = 0; k0 < 128; k0 += 32) {
            __syncthreads();
            const float* asrc = A + (size_t)(m0 + ar) * 128 + (k0 + ak);
            float4 a0 = *(const float4*)asrc;
            float4 a1 = *(const float4*)(asrc + 4);
            f16x8 av = { (_Float16)a0.x, (_Float16)a0.y, (_Float16)a0.z, (_Float16)a0.w,
                         (_Float16)a1.x, (_Float16)a1.y, (_Float16)a1.z, (_Float16)a1.w };
            *(f16x8*)&Al[ar][ak] = av;
#pragma unroll
            for (int i = 0; i < 2; ++i) {
                int c = tid + i * 256;
                int n = c >> 2, koff = (c & 3) * 8;
                *(f16x8*)&Bl[n][koff] = *(const f16x8*)(BT + (size_t)n * 128 + k0 + koff);
            }
            __syncthreads();
            f16x8 af = *(const f16x8*)&Al[fr][fk];
#pragma unroll
            for (int nt = 0; nt < 8; ++nt) {
                f16x8 bf = *(const f16x8*)&Bl[nt * 16 + (lane & 15)][fk];
                accB[nt] = __builtin_amdgcn_mfma_f32_16x16x32_f16(af, bf, accB[nt], 0, 0, 0);
            }
        }
        if (which) {
#pragma unroll
            for (int nt = 0; nt < 8; ++nt) {
                int col = nt * 16 + cbase;
                float bv = bl[col];
#pragma unroll
                for (int rr = 0; rr < 4; ++rr) {
                    accO[nt][rr] += fmaxf(accB[nt][rr] + bv, 0.f);
                    accB[nt][rr] = 0.f;
                }
            }
        }
    }
#pragma unroll
    for (int nt = 0; nt < 8; ++nt) {
        int col = nt * 16 + cbase;
#pragma unroll
        for (int rr = 0; rr < 4; ++rr)
            out[(size_t)(m0 + rbase + rr) * 128 + col] = accO[nt][rr];
    }
}

extern "C" void kernel_launch(void* const* d_in, const int* in_sizes, int n_in,
                              void* d_out, int out_size, void* d_ws, size_t ws_size,
                              hipStream_t stream)
{
    (void)in_sizes; (void)n_in; (void)ws_size;
    const float* xv   = (const float*)d_in[0];
    const float* xa   = (const float*)d_in[1];
    const float* W011 = (const float*)d_in[2];
    const float* b011 = (const float*)d_in[3];
    const float* W012 = (const float*)d_in[4];
    const float* b012 = (const float*)d_in[5];
    const float* ecW1[4] = {(const float*)d_in[6],  (const float*)d_in[10],
                            (const float*)d_in[14], (const float*)d_in[18]};
    const float* ecb1[4] = {(const float*)d_in[7],  (const float*)d_in[11],
                            (const float*)d_in[15], (const float*)d_in[19]};
    const float* ecW2[4] = {(const float*)d_in[8],  (const float*)d_in[12],
                            (const float*)d_in[16], (const float*)d_in[20]};
    const float* ecb2[4] = {(const float*)d_in[9],  (const float*)d_in[13],
                            (const float*)d_in[17], (const float*)d_in[21]};
    const float* sageWl = (const float*)d_in[22];
    const float* sagebl = (const float*)d_in[23];
    const float* sageWr = (const float*)d_in[24];
    const float* fcW    = (const float*)d_in[25];
    const float* fcb    = (const float*)d_in[26];
    const int*   esrc   = (const int*)d_in[27];
    const int*   edst   = esrc + EEe;
    const int*   attr   = (const int*)d_in[28];
    const int*   spk    = (const int*)d_in[29];
    float* out = (float*)d_out;
    const int ntarg = out_size >> 7;       // 8192 target nodes

    const size_t NC = (size_t)NNn * CCc;   // 4194304
    float* ws   = (float*)d_ws;
    float* X    = ws;                      // [N,C] f32; later P1/V1 overlay
    float* S1   = ws + 1 * NC;             // proj partial 0 / vpa out / S1c slices
    float* XV2  = ws + 2 * NC;             // proj partial 1 / xv2
    float* AHc  = ws + 3 * NC;             // P2/V2 overlay, then AH compact snapshots
    float* AH0  = ws + 4 * NC;
    float* AH1  = ws + 5 * NC;
    float* AH2  = ws + 6 * NC;
    float* AH3  = ws + 7 * NC;
    _Float16* P0 = (_Float16*)(ws + 8 * NC);
    _Float16* V0 = P0 + NC;
    _Float16* P1 = (_Float16*)X;           // X dead after csr_acv
    _Float16* V1 = P1 + NC;
    _Float16* P2 = (_Float16*)AHc;         // AHc written only by meanc3 (after mlp3)
    _Float16* V2 = P2 + NC;
    float* ARES = ws + 9 * NC;             // 32768
    int*   cnts = (int*)(ARES + NNn);
    int*   bsum = cnts + 16;
    int*   hist = bsum + 1024;             // 6*32768
    int*   fill = hist + 6 * NNn;
    int*   base = fill + 6 * NNn;
    int2*  arena = (int2*)(base + 6 * NNn);
    _Float16* WT = (_Float16*)(arena + ARENA_TOTAL);

    const _Float16* W011T = WT;
    const _Float16* W012T = WT + 131072;
    _Float16* WTs = WT + 262144;
    const _Float16* WlT   = WTs + 12 * 16384;
    const _Float16* WrT   = WTs + 13 * 16384;

    // ---- merged setup + counting-sort CSR build ----
    WSmall wsm;
    for (int i = 0; i < 4; ++i) {
        wsm.p[3*i + 0] = ecW1[i];
        wsm.p[3*i + 1] = ecW1[i] + 16384;
        wsm.p[3*i + 2] = ecW2[i];
    }
    wsm.p[12] = sageWl; wsm.p[13] = sageWr;
    k_setup<<<2304, 256, 0, stream>>>(W011, W012, wsm, WT, WTs, (float*)hist);
    k_hist<<<EEe / 256, 256, 0, stream>>>(attr, edst, hist);
    k_scan_a<<<768, 256, 0, stream>>>(hist, base, bsum);
    k_scan_b<<<1, 384, 0, stream>>>(bsum, cnts);
    k_scan_c<<<768, 256, 0, stream>>>(base, bsum);
    k_fill_zero<<<3072, 256, 0, stream>>>(esrc, edst, attr, base, fill, arena, hist,
                                          AH0, AH1, AH2, AH3);

    // ---- input projection (split-K, A-prefetch-2) + reduce ----
    k_proj<<<512, 512, 0, stream>>>(xv, xa, W011T, W012T, S1, XV2);
    k_reduce<<<(int)(NC / 1024), 256, 0, stream>>>(S1, XV2, b011, b012, X);
    // ---- xa_g (mask 0); S1 fully overwritten ----
    k_csr_vpa<<<2048, 256, 0, stream>>>(X, arena + OFF0, base + 0 * NNn,
                                        hist + 0 * NNn, CAP0, S1);
    // ---- EdgeConv A (mask 1) ----
    k_pv<<<512, 256, 0, stream>>>(S1, WTs, ecb1[0], WTs + 16384, P0, V0);
    k_edge_mlp<<<512, 512, 0, stream>>>(P0, V0, WTs + 2 * 16384, ecb2[0],
                                        arena + OFF1, cnts + 1, CAP1, AH0);
    k_fc<<<NNn / 4, 256, 0, stream>>>(AH0, fcW, fcb, ARES);
    // ---- xv2 (mask 2); XV2 fully overwritten; last read of X ----
    k_csr_acv<<<2048, 256, 0, stream>>>(X, ARES, arena + OFF2, base + 2 * NNn,
                                        hist + 2 * NNn, CAP2, XV2);
    // ---- three branches merged ----
    PV3 pv3;
    MLP3 m3;
    _Float16* Pb[3] = {P0, P1, P2};
    _Float16* Vb[3] = {V0, V1, V2};
    float* AHb[3] = {AH1, AH2, AH3};
    for (int b = 0; b < 3; ++b) {
        _Float16* Wd = WTs + (3 * (b + 1)) * 16384;
        pv3.Wd[b] = Wd; pv3.Wv[b] = Wd + 16384; pv3.b1[b] = ecb1[b + 1];
        pv3.P[b] = Pb[b]; pv3.V[b] = Vb[b];
        m3.W2[b] = Wd + 2 * 16384; m3.b2[b] = ecb2[b + 1];
        m3.P[b] = Pb[b]; m3.V[b] = Vb[b]; m3.AH[b] = AHb[b];
    }
    k_pv3<<<1536, 256, 0, stream>>>(XV2, pv3);
    k_edge_mlp3<<<MLP3_GRID, 512, 0, stream>>>(m3, arena, cnts);
    k_meanc3<<<2048, 256, 0, stream>>>(AH1, AH2, AH3, arena, base, hist,
                                       spk, ntarg, S1, AHc);
    // ---- fused SAGE epilogue -> d_out ----
    k_sage_out<<<ntarg / 64, 256, 0, stream>>>(S1, AHc, WlT, WrT, sagebl, out, ntarg);
}

// Round 7
// 515.382 us; speedup vs baseline: 1.0329x; 1.0118x over previous
//
#include <hip/hip_runtime.h>
#include <cstdint>
#include <cstddef>

#define NVv 192
#define NAa 64
#define TT 128
#define FDd 1024
#define CCc 128
#define EEe 262144
#define NNn 32768

typedef _Float16 f16x8 __attribute__((ext_vector_type(8)));
typedef float f32x4 __attribute__((ext_vector_type(4)));

#define CAP0 65536
#define CAP1 65536
#define CAP2 65536
#define CAP3 98304
#define CAP4 98304
#define CAP5 147456
#define ARENA_TOTAL (CAP0+CAP1+CAP2+CAP3+CAP4+CAP5)   // 540672
#define OFF0 0
#define OFF1 CAP0
#define OFF2 (CAP0+CAP1)
#define OFF3 (CAP0+CAP1+CAP2)
#define OFF4 (CAP0+CAP1+CAP2+CAP3)
#define OFF5 (CAP0+CAP1+CAP2+CAP3+CAP4)

// Edge-MLP LDS row stride: MUST be 136 (272B = 17x16B) so f16x8 LDS ops stay
// 16B-aligned (132 -> misaligned b128, 2x regression; Round 2 A/B).
#define MPAD 136

__device__ __forceinline__ void eval_masks(int a, bool m[6]) {
    m[0] = (a == -3); m[1] = (a == -2); m[2] = (a == 3);
    m[3] = (a >= 0) & (a <= 1);
    m[4] = (a >= -1) & (a <= 0);
    m[5] = (a >= -1) & (a <= 1);
}

struct WSmall { const float* p[14]; };
struct PV3  { const _Float16* Wd[3]; const _Float16* Wv[3]; const float* b1[3];
              _Float16* P[3]; _Float16* V[3]; };
struct MLP3 { const _Float16* W2[3]; const float* b2[3];
              const _Float16* P[3]; const _Float16* V[3]; float* AH[3]; };

// ---------------- merged setup: wprep_big | wprep_small | zero(hist+fill) ----------------
__global__ __launch_bounds__(256) void k_setup(
    const float* __restrict__ W011, const float* __restrict__ W012,
    WSmall wsm, _Float16* __restrict__ WT, _Float16* __restrict__ WTs,
    float* __restrict__ hf)
{
    int blk = blockIdx.x, tid = threadIdx.x;
    if (blk < 1024) {                       // wprep_big: 262144 elems
        int idx = blk * 256 + tid;
        int which = idx >> 17;
        int r = idx & 131071;
        int n = r >> 10, k = r & 1023;
        const float* src = which ? W012 : W011;
        WT[idx] = (_Float16)src[k * 128 + n];
    } else if (blk < 1920) {                // wprep_small: 229376 elems
        int idx = (blk - 1024) * 256 + tid;
        int seg = idx >> 14;
        int r = idx & 16383;
        int n = r >> 7, k = r & 127;
        const float* src = wsm.p[seg];
        float v = src[k * 128 + n];
        if (seg < 12 && (seg % 3) == 0) v -= src[16384 + k * 128 + n];
        WTs[idx] = (_Float16)v;
    } else {                                // zero hist+fill: 393216 floats
        size_t i = (size_t)(blk - 1920) * 1024 + (size_t)tid * 4;
        *(float4*)(hf + i) = make_float4(0.f, 0.f, 0.f, 0.f);
    }
}

// ---------------- counting sort phase 1 ----------------
__global__ __launch_bounds__(256) void k_hist(
    const int* __restrict__ attr, const int* __restrict__ edst,
    int* __restrict__ hist)
{
    int e = blockIdx.x * 256 + threadIdx.x;
    int a = attr[e], d = edst[e];
    bool m[6]; eval_masks(a, m);
#pragma unroll
    for (int j = 0; j < 6; ++j)
        if (m[j]) atomicAdd(&hist[j * NNn + d], 1);
}

// ---------------- hierarchical exclusive scan ----------------
__global__ __launch_bounds__(256) void k_scan_a(
    const int* __restrict__ hist, int* __restrict__ base, int* __restrict__ bsum)
{
    __shared__ int wsum[4];
    int idx = blockIdx.x * 256 + threadIdx.x;
    int tid = threadIdx.x, lane = tid & 63, wv = tid >> 6;
    int v = hist[idx];
    int x = v;
#pragma unroll
    for (int off = 1; off < 64; off <<= 1) {
        int y = __shfl_up(x, off, 64);
        if (lane >= off) x += y;
    }
    if (lane == 63) wsum[wv] = x;
    __syncthreads();
    int add = 0;
    for (int w = 0; w < wv; ++w) add += wsum[w];
    base[idx] = add + x - v;
    if (tid == 255) bsum[blockIdx.x] = add + x;
}

__global__ __launch_bounds__(384) void k_scan_b(int* __restrict__ bsum, int* __restrict__ cnts)
{
    int wv = threadIdx.x >> 6;
    int lane = threadIdx.x & 63;
    int run = 0;
#pragma unroll
    for (int c0 = 0; c0 < 128; c0 += 64) {
        int v = bsum[wv * 128 + c0 + lane];
        int x = v;
#pragma unroll
        for (int off = 1; off < 64; off <<= 1) {
            int y = __shfl_up(x, off, 64);
            if (lane >= off) x += y;
        }
        bsum[wv * 128 + c0 + lane] = run + (x - v);
        run += __shfl(x, 63, 64);
    }
    if (lane == 0) cnts[wv] = run;
}

__global__ __launch_bounds__(256) void k_scan_c(int* __restrict__ base, const int* __restrict__ bsum)
{
    base[blockIdx.x * 256 + threadIdx.x] += bsum[blockIdx.x];
}

// ---------------- merged: fill sorted lists | zero AH atomicMax-path rows ----------------
__global__ __launch_bounds__(256) void k_fill_zero(
    const int* __restrict__ esrc, const int* __restrict__ edst,
    const int* __restrict__ attr, const int* __restrict__ base,
    int* __restrict__ fill, int2* __restrict__ arena, const int* __restrict__ hist,
    float* __restrict__ AH0, float* __restrict__ AH1,
    float* __restrict__ AH2, float* __restrict__ AH3)
{
    int blk = blockIdx.x, tid = threadIdx.x;
    if (blk < 1024) {
        int e = blk * 256 + tid;
        int a = attr[e];
        int s = esrc[e], d = edst[e];
        bool m[6]; eval_masks(a, m);
        const int caps[6] = {CAP0, CAP1, CAP2, CAP3, CAP4, CAP5};
        const int offs[6] = {OFF0, OFF1, OFF2, OFF3, OFF4, OFF5};
#pragma unroll
        for (int j = 0; j < 6; ++j) {
            if (m[j]) {
                int pos = base[j * NNn + d] + atomicAdd(&fill[j * NNn + d], 1);
                if (pos < caps[j]) arena[offs[j] + pos] = make_int2(s, d);
            }
        }
    } else {
        int zb = blk - 1024;                  // 0..2047
        int col = tid & 127, sub = tid >> 7;
        const int js[4] = {1, 3, 4, 5};
        float* AHs[4] = {AH0, AH1, AH2, AH3};
        for (int d = zb * 2 + sub; d < NNn; d += 2048 * 2) {
#pragma unroll
            for (int jj = 0; jj < 4; ++jj) {
                int j = js[jj];
                int c = hist[j * NNn + d];
                bool need;
                if (c == 0) need = true;
                else {
                    int b = base[j * NNn + d], e = b + c;
                    need = ((b & 63) == 0) || ((e & 63) == 0) || ((b >> 6) != ((e - 1) >> 6));
                }
                if (need) AHs[jj][(size_t)d * 128 + col] = 0.f;
            }
        }
    }
}

// ---------------- input projection: split-K, dbuf B, raw-f32 depth-2 A pipeline ----
// Round 7: R6's prefetch was silently collapsed by the 64-VGPR cap (VGPR_Count
// stayed 64 with 3 live fragment sets declared -> impossible). Fix: allow 128
// VGPRs (launch_bounds(512,4); occupancy unchanged, LDS caps at 2 blocks/CU
// = 16 waves = 4 waves/SIMD) and keep chunk kc+2's A as RAW float4 (no cvt ->
// no early waitcnt consumer). cvt to f16 happens only at the iteration end
// that feeds the NEXT chunk's MFMAs, i.e. after this chunk's MFMA block.
__global__ __launch_bounds__(512, 4) void k_proj(
    const float* __restrict__ xv, const float* __restrict__ xa,
    const _Float16* __restrict__ BTv, const _Float16* __restrict__ BTa,
    float* __restrict__ Pp0, float* __restrict__ Pp1)
{
    __shared__ _Float16 Bl[2][128][136];
    const int tid = threadIdx.x, wave = tid >> 6, lane = tid & 63;
    const int tile = blockIdx.x >> 1, kh = blockIdx.x & 1;
    const float* A; const _Float16* BT; int mbase, obase;
    if (tile < 192) { A = xv; BT = BTv; mbase = tile * 128; obase = mbase; }
    else { A = xa; BT = BTa; mbase = (tile - 192) * 128; obase = 24576 + mbase; }
    float* Pout = kh ? Pp1 : Pp0;
    const int kbase = kh * 512;

    const int mrow = mbase + wave * 16 + (lane & 15);
    const int fk   = (lane >> 4) * 8;
    f32x4 acc[8];
#pragma unroll
    for (int i = 0; i < 8; ++i) acc[i] = (f32x4){0,0,0,0};

#define STAGE_B(buf_, kc_) {                                                    \
    _Pragma("unroll")                                                           \
    for (int it = 0; it < 4; ++it) {                                            \
        int c = it * 512 + tid;                                                 \
        int n = c >> 4, koff = (c & 15) * 8;                                    \
        *(f16x8*)&Bl[buf_][n][koff] =                                           \
            *(const f16x8*)(BT + (size_t)n * 1024 + kbase + (kc_) * 128 + koff); \
    } }

    // raw (no-convert) A loads for one K-chunk: 8 x float4 per lane
#define LOAD_A_RAW(kc_, r0_, r1_) {                                             \
    _Pragma("unroll")                                                           \
    for (int t4 = 0; t4 < 4; ++t4) {                                            \
        const float* asrc = A + (size_t)mrow * 1024 + kbase + (kc_) * 128 + t4 * 32 + fk; \
        r0_[t4] = *(const float4*)asrc;                                         \
        r1_[t4] = *(const float4*)(asrc + 4);                                   \
    } }

#define CVT_A(r0_, r1_, dst_) {                                                 \
    _Pragma("unroll")                                                           \
    for (int t4 = 0; t4 < 4; ++t4)                                              \
        dst_[t4] = (f16x8){ (_Float16)r0_[t4].x, (_Float16)r0_[t4].y,           \
                            (_Float16)r0_[t4].z, (_Float16)r0_[t4].w,           \
                            (_Float16)r1_[t4].x, (_Float16)r1_[t4].y,           \
                            (_Float16)r1_[t4].z, (_Float16)r1_[t4].w };         \
    }

    float4 ra0[4], ra1[4], rb0[4], rb1[4];
    f16x8 af[4];
    LOAD_A_RAW(0, ra0, ra1);     // chunk0 raw (HBM, longest latency, first)
    LOAD_A_RAW(1, rb0, rb1);     // chunk1 raw
    STAGE_B(0, 0);               // B chunk0 (L2)
    CVT_A(ra0, ra1, af);         // af = chunk0 (ra free after this)
    __syncthreads();

#pragma unroll
    for (int kc = 0; kc < 4; ++kc) {
        const int cur = kc & 1;
        // issue chunk kc+2 raw loads into the buffer freed by chunk kc's cvt:
        // kc even -> ra (cvt'd pre-loop / at end of kc-1), kc odd -> rb
        if (kc == 0) LOAD_A_RAW(2, ra0, ra1);
        if (kc == 1) LOAD_A_RAW(3, rb0, rb1);
        if (kc < 3) STAGE_B(cur ^ 1, kc + 1);
#pragma unroll
        for (int t4 = 0; t4 < 4; ++t4)
#pragma unroll
            for (int nt = 0; nt < 8; ++nt) {
                f16x8 bf = *(const f16x8*)&Bl[cur][nt * 16 + (lane & 15)][t4 * 32 + fk];
                acc[nt] = __builtin_amdgcn_mfma_f32_16x16x32_f16(af[t4], bf, acc[nt], 0, 0, 0);
            }
        // convert the chunk kc+1 raw buffer for next iteration (after MFMAs)
        if (kc < 3) {
            if ((kc & 1) == 0) { CVT_A(rb0, rb1, af); }   // kc even: next is odd chunk in rb
            else               { CVT_A(ra0, ra1, af); }   // kc odd: next is even chunk in ra
        }
        __syncthreads();
    }
#undef STAGE_B
#undef LOAD_A_RAW
#undef CVT_A

    const int cbase = lane & 15, rloc = (lane >> 4) * 4;
    const int wgrp = wave & 3;
    float* Hsf = (float*)&Bl[0][0][0] + (size_t)wgrp * 16 * 132;
#pragma unroll
    for (int grp = 0; grp < 2; ++grp) {
        if ((wave >> 2) == grp) {
#pragma unroll
            for (int nt = 0; nt < 8; ++nt) {
                int c2 = nt * 16 + cbase;
#pragma unroll
                for (int rr = 0; rr < 4; ++rr)
                    Hsf[(rloc + rr) * 132 + c2] = acc[nt][rr];
            }
#pragma unroll
            for (int it = 0; it < 8; ++it) {
                int id = it * 64 + lane;
                int row = id >> 5, off = (id & 31) * 4;
                float4 v = *(float4*)&Hsf[row * 132 + off];
                *(float4*)&Pout[(size_t)(obase + wave * 16 + row) * 128 + off] = v;
            }
        }
        __syncthreads();
    }
}

// ---------------- reduce: X = Pp0 + Pp1 + bias(row) ----------------
__global__ __launch_bounds__(256) void k_reduce(
    const float* __restrict__ Pp0, const float* __restrict__ Pp1,
    const float* __restrict__ b011, const float* __restrict__ b012,
    float* __restrict__ X)
{
    size_t f = (size_t)blockIdx.x * 256 + threadIdx.x;
    size_t i = f * 4;
    int col = (int)(i & 127);
    int row = (int)(i >> 7);
    const float* bias = (row < 24576) ? b011 : b012;
    float4 a = *(const float4*)(Pp0 + i);
    float4 b = *(const float4*)(Pp1 + i);
    float4 bb = *(const float4*)(bias + col);
    *(float4*)(X + i) = make_float4(a.x + b.x + bb.x, a.y + b.y + bb.y,
                                    a.z + b.z + bb.z, a.w + b.w + bb.w);
}

// ---------------- PV GEMM body (shared by audio + pv3) ----------------
__device__ __forceinline__ void pv_body(
    const float* __restrict__ A, const _Float16* __restrict__ BT1,
    const float* __restrict__ b1, const _Float16* __restrict__ BT2,
    _Float16* __restrict__ P, _Float16* __restrict__ V, int tileblk,
    _Float16 (*Bl1)[136], _Float16 (*Bl2)[136], float* bb)
{
    const int tid = threadIdx.x, wave = tid >> 6, lane = tid & 63;
    const int r0 = tileblk * 64 + wave * 16;
    const int fk = (lane >> 4) * 8;
    const int mrow = r0 + (lane & 15);
    float4 a0[4], a1[4];
#pragma unroll
    for (int t4 = 0; t4 < 4; ++t4) {
        const float* asrc = A + (size_t)mrow * 128 + t4 * 32 + fk;
        a0[t4] = *(const float4*)asrc;
        a1[t4] = *(const float4*)(asrc + 4);
    }
#pragma unroll
    for (int it = 0; it < 8; ++it) {
        int c = it * 256 + tid;
        int n = c >> 4, koff = (c & 15) * 8;
        *(f16x8*)&Bl1[n][koff] = *(const f16x8*)(BT1 + (size_t)n * 128 + koff);
        *(f16x8*)&Bl2[n][koff] = *(const f16x8*)(BT2 + (size_t)n * 128 + koff);
    }
    if (tid < 128) bb[tid] = b1[tid];
    __syncthreads();

    f16x8 af[4];
#pragma unroll
    for (int t4 = 0; t4 < 4; ++t4)
        af[t4] = (f16x8){ (_Float16)a0[t4].x, (_Float16)a0[t4].y, (_Float16)a0[t4].z, (_Float16)a0[t4].w,
                          (_Float16)a1[t4].x, (_Float16)a1[t4].y, (_Float16)a1[t4].z, (_Float16)a1[t4].w };
    f32x4 acc1[8], acc2[8];
#pragma unroll
    for (int i = 0; i < 8; ++i) { acc1[i] = (f32x4){0,0,0,0}; acc2[i] = (f32x4){0,0,0,0}; }
#pragma unroll
    for (int t4 = 0; t4 < 4; ++t4)
#pragma unroll
        for (int nt = 0; nt < 8; ++nt) {
            f16x8 bf1 = *(const f16x8*)&Bl1[nt * 16 + (lane & 15)][t4 * 32 + fk];
            f16x8 bf2 = *(const f16x8*)&Bl2[nt * 16 + (lane & 15)][t4 * 32 + fk];
            acc1[nt] = __builtin_amdgcn_mfma_f32_16x16x32_f16(af[t4], bf1, acc1[nt], 0, 0, 0);
            acc2[nt] = __builtin_amdgcn_mfma_f32_16x16x32_f16(af[t4], bf2, acc2[nt], 0, 0, 0);
        }
    __syncthreads();
    _Float16* Hs = &Bl1[0][0] + (size_t)wave * 16 * 136;
    const int cbase = lane & 15, rloc = (lane >> 4) * 4;
#pragma unroll
    for (int nt = 0; nt < 8; ++nt) {
        int c2 = nt * 16 + cbase;
        float bvv = bb[c2];
#pragma unroll
        for (int rr = 0; rr < 4; ++rr)
            Hs[(rloc + rr) * 136 + c2] = (_Float16)(acc1[nt][rr] + bvv);
    }
#pragma unroll
    for (int it = 0; it < 4; ++it) {
        int id = it * 64 + lane;
        int row = id >> 4, koff = (id & 15) * 8;
        *(f16x8*)&P[(size_t)(r0 + row) * 128 + koff] = *(f16x8*)&Hs[row * 136 + koff];
    }
#pragma unroll
    for (int nt = 0; nt < 8; ++nt) {
        int c2 = nt * 16 + cbase;
#pragma unroll
        for (int rr = 0; rr < 4; ++rr)
            Hs[(rloc + rr) * 136 + c2] = (_Float16)acc2[nt][rr];
    }
#pragma unroll
    for (int it = 0; it < 4; ++it) {
        int id = it * 64 + lane;
        int row = id >> 4, koff = (id & 15) * 8;
        *(f16x8*)&V[(size_t)(r0 + row) * 128 + koff] = *(f16x8*)&Hs[row * 136 + koff];
    }
}

__global__ __launch_bounds__(256) void k_pv(
    const float* __restrict__ A, const _Float16* __restrict__ BT1,
    const float* __restrict__ b1, const _Float16* __restrict__ BT2,
    _Float16* __restrict__ P, _Float16* __restrict__ V)
{
    __shared__ _Float16 Bl1[128][136];
    __shared__ _Float16 Bl2[128][136];
    __shared__ float bb[128];
    pv_body(A, BT1, b1, BT2, P, V, blockIdx.x, Bl1, Bl2, bb);
}

// all 3 branches in one dispatch: 1536 blocks = branch(3) x tile(512)
__global__ __launch_bounds__(256) void k_pv3(const float* __restrict__ A, PV3 p)
{
    __shared__ _Float16 Bl1[128][136];
    __shared__ _Float16 Bl2[128][136];
    __shared__ float bb[128];
    int b = blockIdx.x >> 9, t = blockIdx.x & 511;
    pv_body(A, p.Wd[b], p.b1[b], p.Wv[b], p.P[b], p.V[b], t, Bl1, Bl2, bb);
}

// ---------------- edge MLP: W2 load (once per 512-thread block) ----------------
__device__ __forceinline__ void mlp_loadW(
    const _Float16* __restrict__ W2T, const float* __restrict__ b2,
    _Float16 (*W2l)[MPAD], float* __restrict__ b2l)
{
    int tid = threadIdx.x;       // 0..511
#pragma unroll
    for (int i = 0; i < 4; ++i) {
        int c = tid + i * 512;
        int n = c >> 4, koff = (c & 15) * 8;
        *(f16x8*)&W2l[n][koff] = *(const f16x8*)(W2T + n * 128 + koff);
    }
    if (tid < 128) b2l[tid] = b2[tid];
}

// ---------------- edge MLP tile body (team-scoped; 256 threads/team) ----------------
__device__ __forceinline__ void mlp_tile2(
    const _Float16* __restrict__ P, const _Float16* __restrict__ V,
    const int2* __restrict__ list, int cnt, int t, float* __restrict__ agg,
    _Float16 (*Rl)[MPAD], const _Float16 (*W2l)[MPAD], const float* __restrict__ b2l,
    int2* __restrict__ eSD, unsigned char* __restrict__ gstart,
    int* __restrict__ gdst, int* __restrict__ ngrS)
{
    const int tid  = threadIdx.x & 255;      // team-local
    const int wave = tid >> 6;               // 0..3 within team
    const int lane = threadIdx.x & 63;
    if (tid < 64) {
        int e = t * 64 + tid;
        eSD[tid] = (e < cnt) ? list[e] : make_int2(0, -1);
    }
    __syncthreads();
    if (tid < 64) {
        int d = eSD[tid].y;
        bool flag = (tid == 0) || (d != eSD[tid - 1].y);
        unsigned long long bm = __ballot(flag);
        int rank = (int)__popcll(bm & ((1ull << tid) - 1ull));
        if (flag) { gstart[rank] = (unsigned char)tid; gdst[rank] = d; }
        if (tid == 0) {
            int ng = (int)__popcll(bm);
            *ngrS = ng;
            gstart[ng] = 64;
        }
    }
    const int rrow = tid >> 4;
    const int rch  = (tid & 15) * 8;
#pragma unroll
    for (int p = 0; p < 4; ++p) {
        int i = p * 16 + rrow;
        int2 sd = eSD[i];
        f16x8 rv = {0, 0, 0, 0, 0, 0, 0, 0};
        if (sd.y >= 0) {
            f16x8 pv = *(const f16x8*)(P + (size_t)sd.y * 128 + rch);
            f16x8 vv = *(const f16x8*)(V + (size_t)sd.x * 128 + rch);
            rv = pv + vv;
#pragma unroll
            for (int q = 0; q < 8; ++q)
                rv[q] = (rv[q] > (_Float16)0.f) ? rv[q] : (_Float16)0.f;
        }
        *(f16x8*)&Rl[i][rch] = rv;
    }
    __syncthreads();

    const int frow  = wave * 16 + (lane & 15);
    const int fq    = (lane >> 4) * 8;
    f32x4 acc[8];
#pragma unroll
    for (int i = 0; i < 8; ++i) acc[i] = (f32x4){0,0,0,0};
#pragma unroll
    for (int t4 = 0; t4 < 4; ++t4) {
        f16x8 af = *(const f16x8*)&Rl[frow][t4 * 32 + fq];
#pragma unroll
        for (int nt = 0; nt < 8; ++nt) {
            f16x8 bf = *(const f16x8*)&W2l[nt * 16 + (lane & 15)][t4 * 32 + fq];
            acc[nt] = __builtin_amdgcn_mfma_f32_16x16x32_f16(af, bf, acc[nt], 0, 0, 0);
        }
    }
    __syncthreads();
    const int rbase = wave * 16 + (lane >> 4) * 4;
    const int cbase = lane & 15;
#pragma unroll
    for (int nt = 0; nt < 8; ++nt) {
        int c2 = nt * 16 + cbase;
        float bv = b2l[c2];
#pragma unroll
        for (int rr = 0; rr < 4; ++rr) {
            int row = rbase + rr;
            Rl[row][c2 ^ (((row >> 3) & 1) << 4)] = (_Float16)fmaxf(acc[nt][rr] + bv, 0.f);
        }
    }
    __syncthreads();
    const int col  = tid & 127;
    const int half = tid >> 7;
    int ng = *ngrS;
    for (int g = half; g < ng; g += 2) {
        int s = gstart[g], e = gstart[g + 1];
        int d = gdst[g];
        if (d < 0) continue;
        float m = 0.f;
        for (int i = s; i < e; ++i)
            m = fmaxf(m, (float)Rl[i][col ^ (((i >> 3) & 1) << 4)]);
        size_t o = (size_t)d * 128 + col;
        if (s == 0 || e == 64)
            atomicMax((unsigned int*)&agg[o], __float_as_uint(m));
        else
            agg[o] = m;
    }
}

// audio (single mask): 512-thread blocks, 2 tile-teams share one W2 LDS copy
__global__ __launch_bounds__(512, 2) void k_edge_mlp(
    const _Float16* __restrict__ P, const _Float16* __restrict__ V,
    const _Float16* __restrict__ W2T, const float* __restrict__ b2,
    const int2* __restrict__ list, const int* __restrict__ cntp, int cap,
    float* __restrict__ agg)
{
    __shared__ _Float16 W2l[128][MPAD];
    __shared__ float b2l[128];
    __shared__ _Float16 Rl[2][64][MPAD];
    __shared__ int2 eSD[2][64];
    __shared__ unsigned char gstart[2][68];
    __shared__ int gdst[2][64];
    __shared__ int ngrS[2];
    int cnt = min(*cntp, cap);
    int ntiles = (cnt + 63) >> 6;
    if ((int)blockIdx.x * 2 >= ntiles) return;
    mlp_loadW(W2T, b2, W2l, b2l);
    const int team = threadIdx.x >> 8;
    for (int base = blockIdx.x * 2; base < ntiles; base += gridDim.x * 2) {
        mlp_tile2(P, V, list, cnt, base + team, agg,
                  Rl[team], W2l, b2l, eSD[team], gstart[team], gdst[team], &ngrS[team]);
    }
}

// all 3 branch masks: branch-static grid-stride blocks (W2 loaded once/block)
#define MLP3_G0 146
#define MLP3_G1 146
#define MLP3_G2 220
#define MLP3_GRID (MLP3_G0 + MLP3_G1 + MLP3_G2)   // 512

__global__ __launch_bounds__(512, 2) void k_edge_mlp3(
    MLP3 p, const int2* __restrict__ arena, const int* __restrict__ cnts)
{
    __shared__ _Float16 W2l[128][MPAD];
    __shared__ float b2l[128];
    __shared__ _Float16 Rl[2][64][MPAD];
    __shared__ int2 eSD[2][64];
    __shared__ unsigned char gstart[2][68];
    __shared__ int gdst[2][64];
    __shared__ int ngrS[2];
    const int caps[3] = {CAP3, CAP4, CAP5};
    const int offs[3] = {OFF3, OFF4, OFF5};
    int blk = blockIdx.x;
    int b, i, G;
    if (blk < MLP3_G0)                 { b = 0; i = blk;                       G = MLP3_G0; }
    else if (blk < MLP3_G0 + MLP3_G1)  { b = 1; i = blk - MLP3_G0;             G = MLP3_G1; }
    else                               { b = 2; i = blk - (MLP3_G0 + MLP3_G1); G = MLP3_G2; }
    int cnt = min(cnts[3 + b], caps[b]);
    int ntiles = (cnt + 63) >> 6;
    if (i * 2 >= ntiles) return;
    mlp_loadW(p.W2[b], p.b2[b], W2l, b2l);
    const int team = threadIdx.x >> 8;
    const int2* list = arena + offs[b];
    for (int base = i * 2; base < ntiles; base += G * 2) {
        mlp_tile2(p.P[b], p.V[b], list, cnt, base + team, p.AH[b],
                  Rl[team], W2l, b2l, eSD[team], gstart[team], gdst[team], &ngrS[team]);
    }
}

// ---------------- CSR gather-reduce kernels ----------------
__global__ __launch_bounds__(256) void k_csr_vpa(
    const float* __restrict__ X, const int2* __restrict__ list,
    const int* __restrict__ base, const int* __restrict__ cntarr, int cap,
    float* __restrict__ S)
{
    int col = threadIdx.x & 127;
    int sub = threadIdx.x >> 7;
    for (int d = blockIdx.x * 2 + sub; d < NNn; d += gridDim.x * 2) {
        int c = cntarr[d];
        float v = 0.f;
        if (c > 0) {
            int b = base[d];
            int end = min(b + c, cap);
            float mx = -3.0e38f;
            for (int i = b; i < end; ++i)
                mx = fmaxf(mx, X[(size_t)list[i].x * 128 + col]);
            v = fmaxf(X[(size_t)d * 128 + col] + mx, 0.f);
        }
        S[(size_t)d * 128 + col] = v;
    }
}

__global__ __launch_bounds__(256) void k_csr_acv(
    const float* __restrict__ X, const float* __restrict__ ares,
    const int2* __restrict__ list,
    const int* __restrict__ base, const int* __restrict__ cntarr, int cap,
    float* __restrict__ S)
{
    int col = threadIdx.x & 127;
    int sub = threadIdx.x >> 7;
    for (int d = blockIdx.x * 2 + sub; d < NNn; d += gridDim.x * 2) {
        int c = cntarr[d];
        float v = 0.f;
        if (c > 0) {
            int b = base[d];
            int end = min(b + c, cap);
            float s = 0.f;
            for (int i = b; i < end; ++i) {
                int sr = list[i].x;
                s += ares[sr] * X[(size_t)sr * 128 + col];
            }
            v = fmaxf(s + (float)c * X[(size_t)d * 128 + col], 0.f);
        }
        S[(size_t)d * 128 + col] = v;
    }
}

// sage mean at target nodes for all 3 branches in one dispatch
__global__ __launch_bounds__(256) void k_meanc3(
    float* const AH1, float* const AH2, float* const AH3,
    const int2* __restrict__ arena,
    const int* __restrict__ base, const int* __restrict__ hist,
    const int* __restrict__ spk, int ntarg,
    float* __restrict__ S1c, float* __restrict__ AHc)
{
    int col = threadIdx.x & 127;
    int sub = threadIdx.x >> 7;
    int step = spk[0] * TT;
    const int caps[3] = {CAP3, CAP4, CAP5};
    const int offs[3] = {OFF3, OFF4, OFF5};
    const float* AHs[3] = {AH1, AH2, AH3};
    int total = 3 * ntarg;
    for (int ci2 = blockIdx.x * 2 + sub; ci2 < total; ci2 += gridDim.x * 2) {
        int b = ci2 / ntarg;
        int ci = ci2 - b * ntarg;
        int j = 3 + b;
        const float* AH = AHs[b];
        const int2* list = arena + offs[b];
        int d = (ci >> 7) * step + (ci & 127);
        int c = hist[j * NNn + d];
        float v = 0.f;
        if (c > 0) {
            int bs = base[j * NNn + d];
            int end = min(bs + c, caps[b]);
            float s = 0.f;
            for (int i = bs; i < end; ++i)
                s += AH[(size_t)list[i].x * 128 + col];
            v = s / (float)c;
        }
        S1c[(size_t)ci2 * 128 + col] = v;
        AHc[(size_t)ci2 * 128 + col] = AH[(size_t)d * 128 + col];
    }
}

// ---------------- fc ----------------
__global__ __launch_bounds__(256) void k_fc(
    const float* __restrict__ A, const float* __restrict__ W,
    const float* __restrict__ b, float* __restrict__ ares)
{
    int node = blockIdx.x * 4 + (threadIdx.x >> 6);
    int lane = threadIdx.x & 63;
    const float* row = A + (size_t)node * 128;
    float v = row[lane] * W[lane] + row[lane + 64] * W[lane + 64];
#pragma unroll
    for (int off = 32; off > 0; off >>= 1) v += __shfl_down(v, off, 64);
    if (lane == 0) ares[node] = v + b[0];
}

// ---------------- fused SAGE output ----------------
__global__ __launch_bounds__(256) void k_sage_out(
    const float* __restrict__ S1c, const float* __restrict__ AHc,
    const _Float16* __restrict__ WlT, const _Float16* __restrict__ WrT,
    const float* __restrict__ bl, float* __restrict__ out, int ntarg)
{
    __shared__ _Float16 Al[64][40];
    __shared__ _Float16 Bl[128][40];
    const int tid  = threadIdx.x;
    const int wave = tid >> 6;
    const int lane = tid & 63;
    const int m0   = blockIdx.x * 64;

    f32x4 accB[8], accO[8];
#pragma unroll
    for (int i = 0; i < 8; ++i) { accB[i] = (f32x4){0,0,0,0}; accO[i] = (f32x4){0,0,0,0}; }

    const int ar = tid >> 2;
    const int ak = (tid & 3) * 8;
    const int fr = wave * 16 + (lane & 15);
    const int fk = (lane >> 4) * 8;
    const int rbase = wave * 16 + (lane >> 4) * 4;
    const int cbase = lane & 15;

    for (int seg = 0; seg < 6; ++seg) {
        int b = seg >> 1, which = seg & 1;
        const float* A = (which ? AHc : S1c) + (size_t)b * ntarg * 128;
        const _Float16* BT = which ? WrT : WlT;
        for (int k0 = 0; k0 < 128; k0 += 32) {
            __syncthreads();
            const float* asrc = A + (size_t)(m0 + ar) * 128 + (k0 + ak);
            float4 a0 = *(const float4*)asrc;
            float4 a1 = *(const float4*)(asrc + 4);
            f16x8 av = { (_Float16)a0.x, (_Float16)a0.y, (_Float16)a0.z, (_Float16)a0.w,
                         (_Float16)a1.x, (_Float16)a1.y, (_Float16)a1.z, (_Float16)a1.w };
            *(f16x8*)&Al[ar][ak] = av;
#pragma unroll
            for (int i = 0; i < 2; ++i) {
                int c = tid + i * 256;
                int n = c >> 2, koff = (c & 3) * 8;
                *(f16x8*)&Bl[n][koff] = *(const f16x8*)(BT + (size_t)n * 128 + k0 + koff);
            }
            __syncthreads();
            f16x8 af = *(const f16x8*)&Al[fr][fk];
#pragma unroll
            for (int nt = 0; nt < 8; ++nt) {
                f16x8 bf = *(const f16x8*)&Bl[nt * 16 + (lane & 15)][fk];
                accB[nt] = __builtin_amdgcn_mfma_f32_16x16x32_f16(af, bf, accB[nt], 0, 0, 0);
            }
        }
        if (which) {
#pragma unroll
            for (int nt = 0; nt < 8; ++nt) {
                int col = nt * 16 + cbase;
                float bv = bl[col];
#pragma unroll
                for (int rr = 0; rr < 4; ++rr) {
                    accO[nt][rr] += fmaxf(accB[nt][rr] + bv, 0.f);
                    accB[nt][rr] = 0.f;
                }
            }
        }
    }
#pragma unroll
    for (int nt = 0; nt < 8; ++nt) {
        int col = nt * 16 + cbase;
#pragma unroll
        for (int rr = 0; rr < 4; ++rr)
            out[(size_t)(m0 + rbase + rr) * 128 + col] = accO[nt][rr];
    }
}

extern "C" void kernel_launch(void* const* d_in, const int* in_sizes, int n_in,
                              void* d_out, int out_size, void* d_ws, size_t ws_size,
                              hipStream_t stream)
{
    (void)in_sizes; (void)n_in; (void)ws_size;
    const float* xv   = (const float*)d_in[0];
    const float* xa   = (const float*)d_in[1];
    const float* W011 = (const float*)d_in[2];
    const float* b011 = (const float*)d_in[3];
    const float* W012 = (const float*)d_in[4];
    const float* b012 = (const float*)d_in[5];
    const float* ecW1[4] = {(const float*)d_in[6],  (const float*)d_in[10],
                            (const float*)d_in[14], (const float*)d_in[18]};
    const float* ecb1[4] = {(const float*)d_in[7],  (const float*)d_in[11],
                            (const float*)d_in[15], (const float*)d_in[19]};
    const float* ecW2[4] = {(const float*)d_in[8],  (const float*)d_in[12],
                            (const float*)d_in[16], (const float*)d_in[20]};
    const float* ecb2[4] = {(const float*)d_in[9],  (const float*)d_in[13],
                            (const float*)d_in[17], (const float*)d_in[21]};
    const float* sageWl = (const float*)d_in[22];
    const float* sagebl = (const float*)d_in[23];
    const float* sageWr = (const float*)d_in[24];
    const float* fcW    = (const float*)d_in[25];
    const float* fcb    = (const float*)d_in[26];
    const int*   esrc   = (const int*)d_in[27];
    const int*   edst   = esrc + EEe;
    const int*   attr   = (const int*)d_in[28];
    const int*   spk    = (const int*)d_in[29];
    float* out = (float*)d_out;
    const int ntarg = out_size >> 7;       // 8192 target nodes

    const size_t NC = (size_t)NNn * CCc;   // 4194304
    float* ws   = (float*)d_ws;
    float* X    = ws;                      // [N,C] f32; later P1/V1 overlay
    float* S1   = ws + 1 * NC;             // proj partial 0 / vpa out / S1c slices
    float* XV2  = ws + 2 * NC;             // proj partial 1 / xv2
    float* AHc  = ws + 3 * NC;             // P2/V2 overlay, then AH compact snapshots
    float* AH0  = ws + 4 * NC;
    float* AH1  = ws + 5 * NC;
    float* AH2  = ws + 6 * NC;
    float* AH3  = ws + 7 * NC;
    _Float16* P0 = (_Float16*)(ws + 8 * NC);
    _Float16* V0 = P0 + NC;
    _Float16* P1 = (_Float16*)X;           // X dead after csr_acv
    _Float16* V1 = P1 + NC;
    _Float16* P2 = (_Float16*)AHc;         // AHc written only by meanc3 (after mlp3)
    _Float16* V2 = P2 + NC;
    float* ARES = ws + 9 * NC;             // 32768
    int*   cnts = (int*)(ARES + NNn);
    int*   bsum = cnts + 16;
    int*   hist = bsum + 1024;             // 6*32768
    int*   fill = hist + 6 * NNn;
    int*   base = fill + 6 * NNn;
    int2*  arena = (int2*)(base + 6 * NNn);
    _Float16* WT = (_Float16*)(arena + ARENA_TOTAL);

    const _Float16* W011T = WT;
    const _Float16* W012T = WT + 131072;
    _Float16* WTs = WT + 262144;
    const _Float16* WlT   = WTs + 12 * 16384;
    const _Float16* WrT   = WTs + 13 * 16384;

    // ---- merged setup + counting-sort CSR build ----
    WSmall wsm;
    for (int i = 0; i < 4; ++i) {
        wsm.p[3*i + 0] = ecW1[i];
        wsm.p[3*i + 1] = ecW1[i] + 16384;
        wsm.p[3*i + 2] = ecW2[i];
    }
    wsm.p[12] = sageWl; wsm.p[13] = sageWr;
    k_setup<<<2304, 256, 0, stream>>>(W011, W012, wsm, WT, WTs, (float*)hist);
    k_hist<<<EEe / 256, 256, 0, stream>>>(attr, edst, hist);
    k_scan_a<<<768, 256, 0, stream>>>(hist, base, bsum);
    k_scan_b<<<1, 384, 0, stream>>>(bsum, cnts);
    k_scan_c<<<768, 256, 0, stream>>>(base, bsum);
    k_fill_zero<<<3072, 256, 0, stream>>>(esrc, edst, attr, base, fill, arena, hist,
                                          AH0, AH1, AH2, AH3);

    // ---- input projection (split-K, raw-A depth-2 pipeline) + reduce ----
    k_proj<<<512, 512, 0, stream>>>(xv, xa, W011T, W012T, S1, XV2);
    k_reduce<<<(int)(NC / 1024), 256, 0, stream>>>(S1, XV2, b011, b012, X);
    // ---- xa_g (mask 0); S1 fully overwritten ----
    k_csr_vpa<<<2048, 256, 0, stream>>>(X, arena + OFF0, base + 0 * NNn,
                                        hist + 0 * NNn, CAP0, S1);
    // ---- EdgeConv A (mask 1) ----
    k_pv<<<512, 256, 0, stream>>>(S1, WTs, ecb1[0], WTs + 16384, P0, V0);
    k_edge_mlp<<<512, 512, 0, stream>>>(P0, V0, WTs + 2 * 16384, ecb2[0],
                                        arena + OFF1, cnts + 1, CAP1, AH0);
    k_fc<<<NNn / 4, 256, 0, stream>>>(AH0, fcW, fcb, ARES);
    // ---- xv2 (mask 2); XV2 fully overwritten; last read of X ----
    k_csr_acv<<<2048, 256, 0, stream>>>(X, ARES, arena + OFF2, base + 2 * NNn,
                                        hist + 2 * NNn, CAP2, XV2);
    // ---- three branches merged ----
    PV3 pv3;
    MLP3 m3;
    _Float16* Pb[3] = {P0, P1, P2};
    _Float16* Vb[3] = {V0, V1, V2};
    float* AHb[3] = {AH1, AH2, AH3};
    for (int b = 0; b < 3; ++b) {
        _Float16* Wd = WTs + (3 * (b + 1)) * 16384;
        pv3.Wd[b] = Wd; pv3.Wv[b] = Wd + 16384; pv3.b1[b] = ecb1[b + 1];
        pv3.P[b] = Pb[b]; pv3.V[b] = Vb[b];
        m3.W2[b] = Wd + 2 * 16384; m3.b2[b] = ecb2[b + 1];
        m3.P[b] = Pb[b]; m3.V[b] = Vb[b]; m3.AH[b] = AHb[b];
    }
    k_pv3<<<1536, 256, 0, stream>>>(XV2, pv3);
    k_edge_mlp3<<<MLP3_GRID, 512, 0, stream>>>(m3, arena, cnts);
    k_meanc3<<<2048, 256, 0, stream>>>(AH1, AH2, AH3, arena, base, hist,
                                       spk, ntarg, S1, AHc);
    // ---- fused SAGE epilogue -> d_out ----
    k_sage_out<<<ntarg / 64, 256, 0, stream>>>(S1, AHc, WlT, WrT, sagebl, out, ntarg);
}

// Round 8
// 513.914 us; speedup vs baseline: 1.0359x; 1.0029x over previous
//
#include <hip/hip_runtime.h>
#include <cstdint>
#include <cstddef>

#define NVv 192
#define NAa 64
#define TT 128
#define FDd 1024
#define CCc 128
#define EEe 262144
#define NNn 32768

typedef _Float16 f16x8 __attribute__((ext_vector_type(8)));
typedef float f32x4 __attribute__((ext_vector_type(4)));

#define CAP0 65536
#define CAP1 65536
#define CAP2 65536
#define CAP3 98304
#define CAP4 98304
#define CAP5 147456
#define ARENA_TOTAL (CAP0+CAP1+CAP2+CAP3+CAP4+CAP5)   // 540672
#define OFF0 0
#define OFF1 CAP0
#define OFF2 (CAP0+CAP1)
#define OFF3 (CAP0+CAP1+CAP2)
#define OFF4 (CAP0+CAP1+CAP2+CAP3)
#define OFF5 (CAP0+CAP1+CAP2+CAP3+CAP4)

// Edge-MLP LDS row stride: MUST be 136 (272B = 17x16B) so f16x8 LDS ops stay
// 16B-aligned (132 -> misaligned b128, 2x regression; Round 2 A/B).
#define MPAD 136

__device__ __forceinline__ void eval_masks(int a, bool m[6]) {
    m[0] = (a == -3); m[1] = (a == -2); m[2] = (a == 3);
    m[3] = (a >= 0) & (a <= 1);
    m[4] = (a >= -1) & (a <= 0);
    m[5] = (a >= -1) & (a <= 1);
}

struct WSmall { const float* p[14]; };
struct PV3  { const _Float16* Wd[3]; const _Float16* Wv[3]; const float* b1[3];
              _Float16* P[3]; _Float16* V[3]; };
struct MLP3 { const _Float16* W2[3]; const float* b2[3];
              const _Float16* P[3]; const _Float16* V[3]; float* AH[3]; };

// ---------------- merged setup: wprep_big | wprep_small | zero(hist+fill) ----------------
__global__ __launch_bounds__(256) void k_setup(
    const float* __restrict__ W011, const float* __restrict__ W012,
    WSmall wsm, _Float16* __restrict__ WT, _Float16* __restrict__ WTs,
    float* __restrict__ hf)
{
    int blk = blockIdx.x, tid = threadIdx.x;
    if (blk < 1024) {                       // wprep_big: 262144 elems
        int idx = blk * 256 + tid;
        int which = idx >> 17;
        int r = idx & 131071;
        int n = r >> 10, k = r & 1023;
        const float* src = which ? W012 : W011;
        WT[idx] = (_Float16)src[k * 128 + n];
    } else if (blk < 1920) {                // wprep_small: 229376 elems
        int idx = (blk - 1024) * 256 + tid;
        int seg = idx >> 14;
        int r = idx & 16383;
        int n = r >> 7, k = r & 127;
        const float* src = wsm.p[seg];
        float v = src[k * 128 + n];
        if (seg < 12 && (seg % 3) == 0) v -= src[16384 + k * 128 + n];
        WTs[idx] = (_Float16)v;
    } else {                                // zero hist+fill: 393216 floats
        size_t i = (size_t)(blk - 1920) * 1024 + (size_t)tid * 4;
        *(float4*)(hf + i) = make_float4(0.f, 0.f, 0.f, 0.f);
    }
}

// ---------------- counting sort phase 1 ----------------
__global__ __launch_bounds__(256) void k_hist(
    const int* __restrict__ attr, const int* __restrict__ edst,
    int* __restrict__ hist)
{
    int e = blockIdx.x * 256 + threadIdx.x;
    int a = attr[e], d = edst[e];
    bool m[6]; eval_masks(a, m);
#pragma unroll
    for (int j = 0; j < 6; ++j)
        if (m[j]) atomicAdd(&hist[j * NNn + d], 1);
}

// ---------------- hierarchical exclusive scan ----------------
__global__ __launch_bounds__(256) void k_scan_a(
    const int* __restrict__ hist, int* __restrict__ base, int* __restrict__ bsum)
{
    __shared__ int wsum[4];
    int idx = blockIdx.x * 256 + threadIdx.x;
    int tid = threadIdx.x, lane = tid & 63, wv = tid >> 6;
    int v = hist[idx];
    int x = v;
#pragma unroll
    for (int off = 1; off < 64; off <<= 1) {
        int y = __shfl_up(x, off, 64);
        if (lane >= off) x += y;
    }
    if (lane == 63) wsum[wv] = x;
    __syncthreads();
    int add = 0;
    for (int w = 0; w < wv; ++w) add += wsum[w];
    base[idx] = add + x - v;
    if (tid == 255) bsum[blockIdx.x] = add + x;
}

__global__ __launch_bounds__(384) void k_scan_b(int* __restrict__ bsum, int* __restrict__ cnts)
{
    int wv = threadIdx.x >> 6;
    int lane = threadIdx.x & 63;
    int run = 0;
#pragma unroll
    for (int c0 = 0; c0 < 128; c0 += 64) {
        int v = bsum[wv * 128 + c0 + lane];
        int x = v;
#pragma unroll
        for (int off = 1; off < 64; off <<= 1) {
            int y = __shfl_up(x, off, 64);
            if (lane >= off) x += y;
        }
        bsum[wv * 128 + c0 + lane] = run + (x - v);
        run += __shfl(x, 63, 64);
    }
    if (lane == 0) cnts[wv] = run;
}

__global__ __launch_bounds__(256) void k_scan_c(int* __restrict__ base, const int* __restrict__ bsum)
{
    base[blockIdx.x * 256 + threadIdx.x] += bsum[blockIdx.x];
}

// ---------------- merged: fill sorted lists | zero AH atomicMax-path rows ----------------
__global__ __launch_bounds__(256) void k_fill_zero(
    const int* __restrict__ esrc, const int* __restrict__ edst,
    const int* __restrict__ attr, const int* __restrict__ base,
    int* __restrict__ fill, int2* __restrict__ arena, const int* __restrict__ hist,
    float* __restrict__ AH0, float* __restrict__ AH1,
    float* __restrict__ AH2, float* __restrict__ AH3)
{
    int blk = blockIdx.x, tid = threadIdx.x;
    if (blk < 1024) {
        int e = blk * 256 + tid;
        int a = attr[e];
        int s = esrc[e], d = edst[e];
        bool m[6]; eval_masks(a, m);
        const int caps[6] = {CAP0, CAP1, CAP2, CAP3, CAP4, CAP5};
        const int offs[6] = {OFF0, OFF1, OFF2, OFF3, OFF4, OFF5};
#pragma unroll
        for (int j = 0; j < 6; ++j) {
            if (m[j]) {
                int pos = base[j * NNn + d] + atomicAdd(&fill[j * NNn + d], 1);
                if (pos < caps[j]) arena[offs[j] + pos] = make_int2(s, d);
            }
        }
    } else {
        int zb = blk - 1024;                  // 0..2047
        int col = tid & 127, sub = tid >> 7;
        const int js[4] = {1, 3, 4, 5};
        float* AHs[4] = {AH0, AH1, AH2, AH3};
        for (int d = zb * 2 + sub; d < NNn; d += 2048 * 2) {
#pragma unroll
            for (int jj = 0; jj < 4; ++jj) {
                int j = js[jj];
                int c = hist[j * NNn + d];
                bool need;
                if (c == 0) need = true;
                else {
                    int b = base[j * NNn + d], e = b + c;
                    need = ((b & 63) == 0) || ((e & 63) == 0) || ((b >> 6) != ((e - 1) >> 6));
                }
                if (need) AHs[jj][(size_t)d * 128 + col] = 0.f;
            }
        }
    }
}

// ---------------- input projection: split-K, dbuf B, raw-f32 depth-2 A pipeline ----
// (Round 7, verified: proj dropped below the 65us top-5 cutoff with the
// 128-VGPR budget; R6's collapse was the 64-VGPR cap.)
__global__ __launch_bounds__(512, 4) void k_proj(
    const float* __restrict__ xv, const float* __restrict__ xa,
    const _Float16* __restrict__ BTv, const _Float16* __restrict__ BTa,
    float* __restrict__ Pp0, float* __restrict__ Pp1)
{
    __shared__ _Float16 Bl[2][128][136];
    const int tid = threadIdx.x, wave = tid >> 6, lane = tid & 63;
    const int tile = blockIdx.x >> 1, kh = blockIdx.x & 1;
    const float* A; const _Float16* BT; int mbase, obase;
    if (tile < 192) { A = xv; BT = BTv; mbase = tile * 128; obase = mbase; }
    else { A = xa; BT = BTa; mbase = (tile - 192) * 128; obase = 24576 + mbase; }
    float* Pout = kh ? Pp1 : Pp0;
    const int kbase = kh * 512;

    const int mrow = mbase + wave * 16 + (lane & 15);
    const int fk   = (lane >> 4) * 8;
    f32x4 acc[8];
#pragma unroll
    for (int i = 0; i < 8; ++i) acc[i] = (f32x4){0,0,0,0};

#define STAGE_B(buf_, kc_) {                                                    \
    _Pragma("unroll")                                                           \
    for (int it = 0; it < 4; ++it) {                                            \
        int c = it * 512 + tid;                                                 \
        int n = c >> 4, koff = (c & 15) * 8;                                    \
        *(f16x8*)&Bl[buf_][n][koff] =                                           \
            *(const f16x8*)(BT + (size_t)n * 1024 + kbase + (kc_) * 128 + koff); \
    } }

    // raw (no-convert) A loads for one K-chunk: 8 x float4 per lane
#define LOAD_A_RAW(kc_, r0_, r1_) {                                             \
    _Pragma("unroll")                                                           \
    for (int t4 = 0; t4 < 4; ++t4) {                                            \
        const float* asrc = A + (size_t)mrow * 1024 + kbase + (kc_) * 128 + t4 * 32 + fk; \
        r0_[t4] = *(const float4*)asrc;                                         \
        r1_[t4] = *(const float4*)(asrc + 4);                                   \
    } }

#define CVT_A(r0_, r1_, dst_) {                                                 \
    _Pragma("unroll")                                                           \
    for (int t4 = 0; t4 < 4; ++t4)                                              \
        dst_[t4] = (f16x8){ (_Float16)r0_[t4].x, (_Float16)r0_[t4].y,           \
                            (_Float16)r0_[t4].z, (_Float16)r0_[t4].w,           \
                            (_Float16)r1_[t4].x, (_Float16)r1_[t4].y,           \
                            (_Float16)r1_[t4].z, (_Float16)r1_[t4].w };         \
    }

    float4 ra0[4], ra1[4], rb0[4], rb1[4];
    f16x8 af[4];
    LOAD_A_RAW(0, ra0, ra1);     // chunk0 raw (HBM, longest latency, first)
    LOAD_A_RAW(1, rb0, rb1);     // chunk1 raw
    STAGE_B(0, 0);               // B chunk0 (L2)
    CVT_A(ra0, ra1, af);         // af = chunk0 (ra free after this)
    __syncthreads();

#pragma unroll
    for (int kc = 0; kc < 4; ++kc) {
        const int cur = kc & 1;
        // issue chunk kc+2 raw loads into the buffer freed by chunk kc's cvt:
        if (kc == 0) LOAD_A_RAW(2, ra0, ra1);
        if (kc == 1) LOAD_A_RAW(3, rb0, rb1);
        if (kc < 3) STAGE_B(cur ^ 1, kc + 1);
#pragma unroll
        for (int t4 = 0; t4 < 4; ++t4)
#pragma unroll
            for (int nt = 0; nt < 8; ++nt) {
                f16x8 bf = *(const f16x8*)&Bl[cur][nt * 16 + (lane & 15)][t4 * 32 + fk];
                acc[nt] = __builtin_amdgcn_mfma_f32_16x16x32_f16(af[t4], bf, acc[nt], 0, 0, 0);
            }
        // convert the chunk kc+1 raw buffer for next iteration (after MFMAs)
        if (kc < 3) {
            if ((kc & 1) == 0) { CVT_A(rb0, rb1, af); }
            else               { CVT_A(ra0, ra1, af); }
        }
        __syncthreads();
    }
#undef STAGE_B
#undef LOAD_A_RAW
#undef CVT_A

    const int cbase = lane & 15, rloc = (lane >> 4) * 4;
    const int wgrp = wave & 3;
    float* Hsf = (float*)&Bl[0][0][0] + (size_t)wgrp * 16 * 132;
#pragma unroll
    for (int grp = 0; grp < 2; ++grp) {
        if ((wave >> 2) == grp) {
#pragma unroll
            for (int nt = 0; nt < 8; ++nt) {
                int c2 = nt * 16 + cbase;
#pragma unroll
                for (int rr = 0; rr < 4; ++rr)
                    Hsf[(rloc + rr) * 132 + c2] = acc[nt][rr];
            }
#pragma unroll
            for (int it = 0; it < 8; ++it) {
                int id = it * 64 + lane;
                int row = id >> 5, off = (id & 31) * 4;
                float4 v = *(float4*)&Hsf[row * 132 + off];
                *(float4*)&Pout[(size_t)(obase + wave * 16 + row) * 128 + off] = v;
            }
        }
        __syncthreads();
    }
}

// ---------------- reduce: X = Pp0 + Pp1 + bias(row) ----------------
__global__ __launch_bounds__(256) void k_reduce(
    const float* __restrict__ Pp0, const float* __restrict__ Pp1,
    const float* __restrict__ b011, const float* __restrict__ b012,
    float* __restrict__ X)
{
    size_t f = (size_t)blockIdx.x * 256 + threadIdx.x;
    size_t i = f * 4;
    int col = (int)(i & 127);
    int row = (int)(i >> 7);
    const float* bias = (row < 24576) ? b011 : b012;
    float4 a = *(const float4*)(Pp0 + i);
    float4 b = *(const float4*)(Pp1 + i);
    float4 bb = *(const float4*)(bias + col);
    *(float4*)(X + i) = make_float4(a.x + b.x + bb.x, a.y + b.y + bb.y,
                                    a.z + b.z + bb.z, a.w + b.w + bb.w);
}

// ---------------- PV GEMM body: 2 tile-teams share one B staging ----------------
// Round 8: pv blocks were 256-thr with 69.8KB LDS -> 2 blocks/CU = 8 waves/CU,
// and each of the 1536 pv3 tiles re-staged 64KB of branch-constant B from L2.
// Now: 512-thr blocks = 2 tile-teams (proven R4 transformation on edge_mlp3),
// B staged ONCE per block (1536 -> 768 stagings), 16 waves/CU. Epilogue
// scratch = Bl1 + wave*16*136 spans exactly all 8 waves (8*16*136*2B = Bl1).
__device__ __forceinline__ void pv_body2(
    const float* __restrict__ A, const _Float16* __restrict__ BT1,
    const float* __restrict__ b1, const _Float16* __restrict__ BT2,
    _Float16* __restrict__ P, _Float16* __restrict__ V, int tile0,
    _Float16 (*Bl1)[136], _Float16 (*Bl2)[136], float* bb)
{
    const int tid = threadIdx.x;          // 0..511
    const int wave = tid >> 6;            // 0..7
    const int lane = tid & 63;
    const int team = wave >> 2;           // 0,1
    const int twave = wave & 3;           // 0..3 within team
    const int r0 = (tile0 + team) * 64 + twave * 16;
    const int fk = (lane >> 4) * 8;
    const int mrow = r0 + (lane & 15);
    float4 a0[4], a1[4];
#pragma unroll
    for (int t4 = 0; t4 < 4; ++t4) {
        const float* asrc = A + (size_t)mrow * 128 + t4 * 32 + fk;
        a0[t4] = *(const float4*)asrc;
        a1[t4] = *(const float4*)(asrc + 4);
    }
    // stage both 128x128 f16 B matrices with all 512 threads (once per block)
#pragma unroll
    for (int it = 0; it < 4; ++it) {
        int c = it * 512 + tid;
        int n = c >> 4, koff = (c & 15) * 8;
        *(f16x8*)&Bl1[n][koff] = *(const f16x8*)(BT1 + (size_t)n * 128 + koff);
        *(f16x8*)&Bl2[n][koff] = *(const f16x8*)(BT2 + (size_t)n * 128 + koff);
    }
    if (tid < 128) bb[tid] = b1[tid];
    __syncthreads();

    f16x8 af[4];
#pragma unroll
    for (int t4 = 0; t4 < 4; ++t4)
        af[t4] = (f16x8){ (_Float16)a0[t4].x, (_Float16)a0[t4].y, (_Float16)a0[t4].z, (_Float16)a0[t4].w,
                          (_Float16)a1[t4].x, (_Float16)a1[t4].y, (_Float16)a1[t4].z, (_Float16)a1[t4].w };
    f32x4 acc1[8], acc2[8];
#pragma unroll
    for (int i = 0; i < 8; ++i) { acc1[i] = (f32x4){0,0,0,0}; acc2[i] = (f32x4){0,0,0,0}; }
#pragma unroll
    for (int t4 = 0; t4 < 4; ++t4)
#pragma unroll
        for (int nt = 0; nt < 8; ++nt) {
            f16x8 bf1 = *(const f16x8*)&Bl1[nt * 16 + (lane & 15)][t4 * 32 + fk];
            f16x8 bf2 = *(const f16x8*)&Bl2[nt * 16 + (lane & 15)][t4 * 32 + fk];
            acc1[nt] = __builtin_amdgcn_mfma_f32_16x16x32_f16(af[t4], bf1, acc1[nt], 0, 0, 0);
            acc2[nt] = __builtin_amdgcn_mfma_f32_16x16x32_f16(af[t4], bf2, acc2[nt], 0, 0, 0);
        }
    __syncthreads();                      // all 8 waves done reading Bl1/Bl2
    _Float16* Hs = &Bl1[0][0] + (size_t)wave * 16 * 136;   // 8 disjoint regions
    const int cbase = lane & 15, rloc = (lane >> 4) * 4;
#pragma unroll
    for (int nt = 0; nt < 8; ++nt) {
        int c2 = nt * 16 + cbase;
        float bvv = bb[c2];
#pragma unroll
        for (int rr = 0; rr < 4; ++rr)
            Hs[(rloc + rr) * 136 + c2] = (_Float16)(acc1[nt][rr] + bvv);
    }
#pragma unroll
    for (int it = 0; it < 4; ++it) {
        int id = it * 64 + lane;
        int row = id >> 4, koff = (id & 15) * 8;
        *(f16x8*)&P[(size_t)(r0 + row) * 128 + koff] = *(f16x8*)&Hs[row * 136 + koff];
    }
#pragma unroll
    for (int nt = 0; nt < 8; ++nt) {
        int c2 = nt * 16 + cbase;
#pragma unroll
        for (int rr = 0; rr < 4; ++rr)
            Hs[(rloc + rr) * 136 + c2] = (_Float16)acc2[nt][rr];
    }
#pragma unroll
    for (int it = 0; it < 4; ++it) {
        int id = it * 64 + lane;
        int row = id >> 4, koff = (id & 15) * 8;
        *(f16x8*)&V[(size_t)(r0 + row) * 128 + koff] = *(f16x8*)&Hs[row * 136 + koff];
    }
}

__global__ __launch_bounds__(512, 4) void k_pv(
    const float* __restrict__ A, const _Float16* __restrict__ BT1,
    const float* __restrict__ b1, const _Float16* __restrict__ BT2,
    _Float16* __restrict__ P, _Float16* __restrict__ V)
{
    __shared__ _Float16 Bl1[128][136];
    __shared__ _Float16 Bl2[128][136];
    __shared__ float bb[128];
    pv_body2(A, BT1, b1, BT2, P, V, blockIdx.x * 2, Bl1, Bl2, bb);
}

// all 3 branches in one dispatch: 768 blocks = branch(3) x pair(256)
__global__ __launch_bounds__(512, 4) void k_pv3(const float* __restrict__ A, PV3 p)
{
    __shared__ _Float16 Bl1[128][136];
    __shared__ _Float16 Bl2[128][136];
    __shared__ float bb[128];
    int b = blockIdx.x >> 8, t0 = (blockIdx.x & 255) * 2;
    pv_body2(A, p.Wd[b], p.b1[b], p.Wv[b], p.P[b], p.V[b], t0, Bl1, Bl2, bb);
}

// ---------------- edge MLP: W2 load (once per 512-thread block) ----------------
__device__ __forceinline__ void mlp_loadW(
    const _Float16* __restrict__ W2T, const float* __restrict__ b2,
    _Float16 (*W2l)[MPAD], float* __restrict__ b2l)
{
    int tid = threadIdx.x;       // 0..511
#pragma unroll
    for (int i = 0; i < 4; ++i) {
        int c = tid + i * 512;
        int n = c >> 4, koff = (c & 15) * 8;
        *(f16x8*)&W2l[n][koff] = *(const f16x8*)(W2T + n * 128 + koff);
    }
    if (tid < 128) b2l[tid] = b2[tid];
}

// ---------------- edge MLP tile body (team-scoped; 256 threads/team) ----------------
__device__ __forceinline__ void mlp_tile2(
    const _Float16* __restrict__ P, const _Float16* __restrict__ V,
    const int2* __restrict__ list, int cnt, int t, float* __restrict__ agg,
    _Float16 (*Rl)[MPAD], const _Float16 (*W2l)[MPAD], const float* __restrict__ b2l,
    int2* __restrict__ eSD, unsigned char* __restrict__ gstart,
    int* __restrict__ gdst, int* __restrict__ ngrS)
{
    const int tid  = threadIdx.x & 255;      // team-local
    const int wave = tid >> 6;               // 0..3 within team
    const int lane = threadIdx.x & 63;
    if (tid < 64) {
        int e = t * 64 + tid;
        eSD[tid] = (e < cnt) ? list[e] : make_int2(0, -1);
    }
    __syncthreads();
    if (tid < 64) {
        int d = eSD[tid].y;
        bool flag = (tid == 0) || (d != eSD[tid - 1].y);
        unsigned long long bm = __ballot(flag);
        int rank = (int)__popcll(bm & ((1ull << tid) - 1ull));
        if (flag) { gstart[rank] = (unsigned char)tid; gdst[rank] = d; }
        if (tid == 0) {
            int ng = (int)__popcll(bm);
            *ngrS = ng;
            gstart[ng] = 64;
        }
    }
    const int rrow = tid >> 4;
    const int rch  = (tid & 15) * 8;
#pragma unroll
    for (int p = 0; p < 4; ++p) {
        int i = p * 16 + rrow;
        int2 sd = eSD[i];
        f16x8 rv = {0, 0, 0, 0, 0, 0, 0, 0};
        if (sd.y >= 0) {
            f16x8 pv = *(const f16x8*)(P + (size_t)sd.y * 128 + rch);
            f16x8 vv = *(const f16x8*)(V + (size_t)sd.x * 128 + rch);
            rv = pv + vv;
#pragma unroll
            for (int q = 0; q < 8; ++q)
                rv[q] = (rv[q] > (_Float16)0.f) ? rv[q] : (_Float16)0.f;
        }
        *(f16x8*)&Rl[i][rch] = rv;
    }
    __syncthreads();

    const int frow  = wave * 16 + (lane & 15);
    const int fq    = (lane >> 4) * 8;
    f32x4 acc[8];
#pragma unroll
    for (int i = 0; i < 8; ++i) acc[i] = (f32x4){0,0,0,0};
#pragma unroll
    for (int t4 = 0; t4 < 4; ++t4) {
        f16x8 af = *(const f16x8*)&Rl[frow][t4 * 32 + fq];
#pragma unroll
        for (int nt = 0; nt < 8; ++nt) {
            f16x8 bf = *(const f16x8*)&W2l[nt * 16 + (lane & 15)][t4 * 32 + fq];
            acc[nt] = __builtin_amdgcn_mfma_f32_16x16x32_f16(af, bf, acc[nt], 0, 0, 0);
        }
    }
    __syncthreads();
    const int rbase = wave * 16 + (lane >> 4) * 4;
    const int cbase = lane & 15;
#pragma unroll
    for (int nt = 0; nt < 8; ++nt) {
        int c2 = nt * 16 + cbase;
        float bv = b2l[c2];
#pragma unroll
        for (int rr = 0; rr < 4; ++rr) {
            int row = rbase + rr;
            Rl[row][c2 ^ (((row >> 3) & 1) << 4)] = (_Float16)fmaxf(acc[nt][rr] + bv, 0.f);
        }
    }
    __syncthreads();
    const int col  = tid & 127;
    const int half = tid >> 7;
    int ng = *ngrS;
    for (int g = half; g < ng; g += 2) {
        int s = gstart[g], e = gstart[g + 1];
        int d = gdst[g];
        if (d < 0) continue;
        float m = 0.f;
        for (int i = s; i < e; ++i)
            m = fmaxf(m, (float)Rl[i][col ^ (((i >> 3) & 1) << 4)]);
        size_t o = (size_t)d * 128 + col;
        if (s == 0 || e == 64)
            atomicMax((unsigned int*)&agg[o], __float_as_uint(m));
        else
            agg[o] = m;
    }
}

// audio (single mask): 512-thread blocks, 2 tile-teams share one W2 LDS copy
__global__ __launch_bounds__(512, 2) void k_edge_mlp(
    const _Float16* __restrict__ P, const _Float16* __restrict__ V,
    const _Float16* __restrict__ W2T, const float* __restrict__ b2,
    const int2* __restrict__ list, const int* __restrict__ cntp, int cap,
    float* __restrict__ agg)
{
    __shared__ _Float16 W2l[128][MPAD];
    __shared__ float b2l[128];
    __shared__ _Float16 Rl[2][64][MPAD];
    __shared__ int2 eSD[2][64];
    __shared__ unsigned char gstart[2][68];
    __shared__ int gdst[2][64];
    __shared__ int ngrS[2];
    int cnt = min(*cntp, cap);
    int ntiles = (cnt + 63) >> 6;
    if ((int)blockIdx.x * 2 >= ntiles) return;
    mlp_loadW(W2T, b2, W2l, b2l);
    const int team = threadIdx.x >> 8;
    for (int base = blockIdx.x * 2; base < ntiles; base += gridDim.x * 2) {
        mlp_tile2(P, V, list, cnt, base + team, agg,
                  Rl[team], W2l, b2l, eSD[team], gstart[team], gdst[team], &ngrS[team]);
    }
}

// all 3 branch masks: branch-static grid-stride blocks (W2 loaded once/block)
#define MLP3_G0 146
#define MLP3_G1 146
#define MLP3_G2 220
#define MLP3_GRID (MLP3_G0 + MLP3_G1 + MLP3_G2)   // 512

__global__ __launch_bounds__(512, 2) void k_edge_mlp3(
    MLP3 p, const int2* __restrict__ arena, const int* __restrict__ cnts)
{
    __shared__ _Float16 W2l[128][MPAD];
    __shared__ float b2l[128];
    __shared__ _Float16 Rl[2][64][MPAD];
    __shared__ int2 eSD[2][64];
    __shared__ unsigned char gstart[2][68];
    __shared__ int gdst[2][64];
    __shared__ int ngrS[2];
    const int caps[3] = {CAP3, CAP4, CAP5};
    const int offs[3] = {OFF3, OFF4, OFF5};
    int blk = blockIdx.x;
    int b, i, G;
    if (blk < MLP3_G0)                 { b = 0; i = blk;                       G = MLP3_G0; }
    else if (blk < MLP3_G0 + MLP3_G1)  { b = 1; i = blk - MLP3_G0;             G = MLP3_G1; }
    else                               { b = 2; i = blk - (MLP3_G0 + MLP3_G1); G = MLP3_G2; }
    int cnt = min(cnts[3 + b], caps[b]);
    int ntiles = (cnt + 63) >> 6;
    if (i * 2 >= ntiles) return;
    mlp_loadW(p.W2[b], p.b2[b], W2l, b2l);
    const int team = threadIdx.x >> 8;
    const int2* list = arena + offs[b];
    for (int base = i * 2; base < ntiles; base += G * 2) {
        mlp_tile2(p.P[b], p.V[b], list, cnt, base + team, p.AH[b],
                  Rl[team], W2l, b2l, eSD[team], gstart[team], gdst[team], &ngrS[team]);
    }
}

// ---------------- CSR gather-reduce kernels ----------------
__global__ __launch_bounds__(256) void k_csr_vpa(
    const float* __restrict__ X, const int2* __restrict__ list,
    const int* __restrict__ base, const int* __restrict__ cntarr, int cap,
    float* __restrict__ S)
{
    int col = threadIdx.x & 127;
    int sub = threadIdx.x >> 7;
    for (int d = blockIdx.x * 2 + sub; d < NNn; d += gridDim.x * 2) {
        int c = cntarr[d];
        float v = 0.f;
        if (c > 0) {
            int b = base[d];
            int end = min(b + c, cap);
            float mx = -3.0e38f;
            for (int i = b; i < end; ++i)
                mx = fmaxf(mx, X[(size_t)list[i].x * 128 + col]);
            v = fmaxf(X[(size_t)d * 128 + col] + mx, 0.f);
        }
        S[(size_t)d * 128 + col] = v;
    }
}

__global__ __launch_bounds__(256) void k_csr_acv(
    const float* __restrict__ X, const float* __restrict__ ares,
    const int2* __restrict__ list,
    const int* __restrict__ base, const int* __restrict__ cntarr, int cap,
    float* __restrict__ S)
{
    int col = threadIdx.x & 127;
    int sub = threadIdx.x >> 7;
    for (int d = blockIdx.x * 2 + sub; d < NNn; d += gridDim.x * 2) {
        int c = cntarr[d];
        float v = 0.f;
        if (c > 0) {
            int b = base[d];
            int end = min(b + c, cap);
            float s = 0.f;
            for (int i = b; i < end; ++i) {
                int sr = list[i].x;
                s += ares[sr] * X[(size_t)sr * 128 + col];
            }
            v = fmaxf(s + (float)c * X[(size_t)d * 128 + col], 0.f);
        }
        S[(size_t)d * 128 + col] = v;
    }
}

// sage mean at target nodes for all 3 branches in one dispatch
__global__ __launch_bounds__(256) void k_meanc3(
    float* const AH1, float* const AH2, float* const AH3,
    const int2* __restrict__ arena,
    const int* __restrict__ base, const int* __restrict__ hist,
    const int* __restrict__ spk, int ntarg,
    float* __restrict__ S1c, float* __restrict__ AHc)
{
    int col = threadIdx.x & 127;
    int sub = threadIdx.x >> 7;
    int step = spk[0] * TT;
    const int caps[3] = {CAP3, CAP4, CAP5};
    const int offs[3] = {OFF3, OFF4, OFF5};
    const float* AHs[3] = {AH1, AH2, AH3};
    int total = 3 * ntarg;
    for (int ci2 = blockIdx.x * 2 + sub; ci2 < total; ci2 += gridDim.x * 2) {
        int b = ci2 / ntarg;
        int ci = ci2 - b * ntarg;
        int j = 3 + b;
        const float* AH = AHs[b];
        const int2* list = arena + offs[b];
        int d = (ci >> 7) * step + (ci & 127);
        int c = hist[j * NNn + d];
        float v = 0.f;
        if (c > 0) {
            int bs = base[j * NNn + d];
            int end = min(bs + c, caps[b]);
            float s = 0.f;
            for (int i = bs; i < end; ++i)
                s += AH[(size_t)list[i].x * 128 + col];
            v = s / (float)c;
        }
        S1c[(size_t)ci2 * 128 + col] = v;
        AHc[(size_t)ci2 * 128 + col] = AH[(size_t)d * 128 + col];
    }
}

// ---------------- fc ----------------
__global__ __launch_bounds__(256) void k_fc(
    const float* __restrict__ A, const float* __restrict__ W,
    const float* __restrict__ b, float* __restrict__ ares)
{
    int node = blockIdx.x * 4 + (threadIdx.x >> 6);
    int lane = threadIdx.x & 63;
    const float* row = A + (size_t)node * 128;
    float v = row[lane] * W[lane] + row[lane + 64] * W[lane + 64];
#pragma unroll
    for (int off = 32; off > 0; off >>= 1) v += __shfl_down(v, off, 64);
    if (lane == 0) ares[node] = v + b[0];
}

// ---------------- fused SAGE output ----------------
__global__ __launch_bounds__(256) void k_sage_out(
    const float* __restrict__ S1c, const float* __restrict__ AHc,
    const _Float16* __restrict__ WlT, const _Float16* __restrict__ WrT,
    const float* __restrict__ bl, float* __restrict__ out, int ntarg)
{
    __shared__ _Float16 Al[64][40];
    __shared__ _Float16 Bl[128][40];
    const int tid  = threadIdx.x;
    const int wave = tid >> 6;
    const int lane = tid & 63;
    const int m0   = blockIdx.x * 64;

    f32x4 accB[8], accO[8];
#pragma unroll
    for (int i = 0; i < 8; ++i) { accB[i] = (f32x4){0,0,0,0}; accO[i] = (f32x4){0,0,0,0}; }

    const int ar = tid >> 2;
    const int ak = (tid & 3) * 8;
    const int fr = wave * 16 + (lane & 15);
    const int fk = (lane >> 4) * 8;
    const int rbase = wave * 16 + (lane >> 4) * 4;
    const int cbase = lane & 15;

    for (int seg = 0; seg < 6; ++seg) {
        int b = seg >> 1, which = seg & 1;
        const float* A = (which ? AHc : S1c) + (size_t)b * ntarg * 128;
        const _Float16* BT = which ? WrT : WlT;
        for (int k0 = 0; k0 < 128; k0 += 32) {
            __syncthreads();
            const float* asrc = A + (size_t)(m0 + ar) * 128 + (k0 + ak);
            float4 a0 = *(const float4*)asrc;
            float4 a1 = *(const float4*)(asrc + 4);
            f16x8 av = { (_Float16)a0.x, (_Float16)a0.y, (_Float16)a0.z, (_Float16)a0.w,
                         (_Float16)a1.x, (_Float16)a1.y, (_Float16)a1.z, (_Float16)a1.w };
            *(f16x8*)&Al[ar][ak] = av;
#pragma unroll
            for (int i = 0; i < 2; ++i) {
                int c = tid + i * 256;
                int n = c >> 2, koff = (c & 3) * 8;
                *(f16x8*)&Bl[n][koff] = *(const f16x8*)(BT + (size_t)n * 128 + k0 + koff);
            }
            __syncthreads();
            f16x8 af = *(const f16x8*)&Al[fr][fk];
#pragma unroll
            for (int nt = 0; nt < 8; ++nt) {
                f16x8 bf = *(const f16x8*)&Bl[nt * 16 + (lane & 15)][fk];
                accB[nt] = __builtin_amdgcn_mfma_f32_16x16x32_f16(af, bf, accB[nt], 0, 0, 0);
            }
        }
        if (which) {
#pragma unroll
            for (int nt = 0; nt < 8; ++nt) {
                int col = nt * 16 + cbase;
                float bv = bl[col];
#pragma unroll
                for (int rr = 0; rr < 4; ++rr) {
                    accO[nt][rr] += fmaxf(accB[nt][rr] + bv, 0.f);
                    accB[nt][rr] = 0.f;
                }
            }
        }
    }
#pragma unroll
    for (int nt = 0; nt < 8; ++nt) {
        int col = nt * 16 + cbase;
#pragma unroll
        for (int rr = 0; rr < 4; ++rr)
            out[(size_t)(m0 + rbase + rr) * 128 + col] = accO[nt][rr];
    }
}

extern "C" void kernel_launch(void* const* d_in, const int* in_sizes, int n_in,
                              void* d_out, int out_size, void* d_ws, size_t ws_size,
                              hipStream_t stream)
{
    (void)in_sizes; (void)n_in; (void)ws_size;
    const float* xv   = (const float*)d_in[0];
    const float* xa   = (const float*)d_in[1];
    const float* W011 = (const float*)d_in[2];
    const float* b011 = (const float*)d_in[3];
    const float* W012 = (const float*)d_in[4];
    const float* b012 = (const float*)d_in[5];
    const float* ecW1[4] = {(const float*)d_in[6],  (const float*)d_in[10],
                            (const float*)d_in[14], (const float*)d_in[18]};
    const float* ecb1[4] = {(const float*)d_in[7],  (const float*)d_in[11],
                            (const float*)d_in[15], (const float*)d_in[19]};
    const float* ecW2[4] = {(const float*)d_in[8],  (const float*)d_in[12],
                            (const float*)d_in[16], (const float*)d_in[20]};
    const float* ecb2[4] = {(const float*)d_in[9],  (const float*)d_in[13],
                            (const float*)d_in[17], (const float*)d_in[21]};
    const float* sageWl = (const float*)d_in[22];
    const float* sagebl = (const float*)d_in[23];
    const float* sageWr = (const float*)d_in[24];
    const float* fcW    = (const float*)d_in[25];
    const float* fcb    = (const float*)d_in[26];
    const int*   esrc   = (const int*)d_in[27];
    const int*   edst   = esrc + EEe;
    const int*   attr   = (const int*)d_in[28];
    const int*   spk    = (const int*)d_in[29];
    float* out = (float*)d_out;
    const int ntarg = out_size >> 7;       // 8192 target nodes

    const size_t NC = (size_t)NNn * CCc;   // 4194304
    float* ws   = (float*)d_ws;
    float* X    = ws;                      // [N,C] f32; later P1/V1 overlay
    float* S1   = ws + 1 * NC;             // proj partial 0 / vpa out / S1c slices
    float* XV2  = ws + 2 * NC;             // proj partial 1 / xv2
    float* AHc  = ws + 3 * NC;             // P2/V2 overlay, then AH compact snapshots
    float* AH0  = ws + 4 * NC;
    float* AH1  = ws + 5 * NC;
    float* AH2  = ws + 6 * NC;
    float* AH3  = ws + 7 * NC;
    _Float16* P0 = (_Float16*)(ws + 8 * NC);
    _Float16* V0 = P0 + NC;
    _Float16* P1 = (_Float16*)X;           // X dead after csr_acv
    _Float16* V1 = P1 + NC;
    _Float16* P2 = (_Float16*)AHc;         // AHc written only by meanc3 (after mlp3)
    _Float16* V2 = P2 + NC;
    float* ARES = ws + 9 * NC;             // 32768
    int*   cnts = (int*)(ARES + NNn);
    int*   bsum = cnts + 16;
    int*   hist = bsum + 1024;             // 6*32768
    int*   fill = hist + 6 * NNn;
    int*   base = fill + 6 * NNn;
    int2*  arena = (int2*)(base + 6 * NNn);
    _Float16* WT = (_Float16*)(arena + ARENA_TOTAL);

    const _Float16* W011T = WT;
    const _Float16* W012T = WT + 131072;
    _Float16* WTs = WT + 262144;
    const _Float16* WlT   = WTs + 12 * 16384;
    const _Float16* WrT   = WTs + 13 * 16384;

    // ---- merged setup + counting-sort CSR build ----
    WSmall wsm;
    for (int i = 0; i < 4; ++i) {
        wsm.p[3*i + 0] = ecW1[i];
        wsm.p[3*i + 1] = ecW1[i] + 16384;
        wsm.p[3*i + 2] = ecW2[i];
    }
    wsm.p[12] = sageWl; wsm.p[13] = sageWr;
    k_setup<<<2304, 256, 0, stream>>>(W011, W012, wsm, WT, WTs, (float*)hist);
    k_hist<<<EEe / 256, 256, 0, stream>>>(attr, edst, hist);
    k_scan_a<<<768, 256, 0, stream>>>(hist, base, bsum);
    k_scan_b<<<1, 384, 0, stream>>>(bsum, cnts);
    k_scan_c<<<768, 256, 0, stream>>>(base, bsum);
    k_fill_zero<<<3072, 256, 0, stream>>>(esrc, edst, attr, base, fill, arena, hist,
                                          AH0, AH1, AH2, AH3);

    // ---- input projection (split-K, raw-A depth-2 pipeline) + reduce ----
    k_proj<<<512, 512, 0, stream>>>(xv, xa, W011T, W012T, S1, XV2);
    k_reduce<<<(int)(NC / 1024), 256, 0, stream>>>(S1, XV2, b011, b012, X);
    // ---- xa_g (mask 0); S1 fully overwritten ----
    k_csr_vpa<<<2048, 256, 0, stream>>>(X, arena + OFF0, base + 0 * NNn,
                                        hist + 0 * NNn, CAP0, S1);
    // ---- EdgeConv A (mask 1) ----
    k_pv<<<256, 512, 0, stream>>>(S1, WTs, ecb1[0], WTs + 16384, P0, V0);
    k_edge_mlp<<<512, 512, 0, stream>>>(P0, V0, WTs + 2 * 16384, ecb2[0],
                                        arena + OFF1, cnts + 1, CAP1, AH0);
    k_fc<<<NNn / 4, 256, 0, stream>>>(AH0, fcW, fcb, ARES);
    // ---- xv2 (mask 2); XV2 fully overwritten; last read of X ----
    k_csr_acv<<<2048, 256, 0, stream>>>(X, ARES, arena + OFF2, base + 2 * NNn,
                                        hist + 2 * NNn, CAP2, XV2);
    // ---- three branches merged ----
    PV3 pv3;
    MLP3 m3;
    _Float16* Pb[3] = {P0, P1, P2};
    _Float16* Vb[3] = {V0, V1, V2};
    float* AHb[3] = {AH1, AH2, AH3};
    for (int b = 0; b < 3; ++b) {
        _Float16* Wd = WTs + (3 * (b + 1)) * 16384;
        pv3.Wd[b] = Wd; pv3.Wv[b] = Wd + 16384; pv3.b1[b] = ecb1[b + 1];
        pv3.P[b] = Pb[b]; pv3.V[b] = Vb[b];
        m3.W2[b] = Wd + 2 * 16384; m3.b2[b] = ecb2[b + 1];
        m3.P[b] = Pb[b]; m3.V[b] = Vb[b]; m3.AH[b] = AHb[b];
    }
    k_pv3<<<768, 512, 0, stream>>>(XV2, pv3);
    k_edge_mlp3<<<MLP3_GRID, 512, 0, stream>>>(m3, arena, cnts);
    k_meanc3<<<2048, 256, 0, stream>>>(AH1, AH2, AH3, arena, base, hist,
                                       spk, ntarg, S1, AHc);
    // ---- fused SAGE epilogue -> d_out ----
    k_sage_out<<<ntarg / 64, 256, 0, stream>>>(S1, AHc, WlT, WrT, sagebl, out, ntarg);
}

// Round 10
// 497.638 us; speedup vs baseline: 1.0698x; 1.0327x over previous
//
#include <hip/hip_runtime.h>
#include <cstdint>
#include <cstddef>

#define NVv 192
#define NAa 64
#define TT 128
#define FDd 1024
#define CCc 128
#define EEe 262144
#define NNn 32768

typedef _Float16 f16x8 __attribute__((ext_vector_type(8)));
typedef _Float16 f16x2 __attribute__((ext_vector_type(2)));
typedef float f32x4 __attribute__((ext_vector_type(4)));

#define CAP0 65536
#define CAP1 65536
#define CAP2 65536
#define CAP3 98304
#define CAP4 98304
#define CAP5 147456
#define ARENA_TOTAL (CAP0+CAP1+CAP2+CAP3+CAP4+CAP5)   // 540672
#define OFF0 0
#define OFF1 CAP0
#define OFF2 (CAP0+CAP1)
#define OFF3 (CAP0+CAP1+CAP2)
#define OFF4 (CAP0+CAP1+CAP2+CAP3)
#define OFF5 (CAP0+CAP1+CAP2+CAP3+CAP4)

// Edge-MLP LDS row stride: MUST be 136 (272B = 17x16B) so f16x8 LDS ops stay
// 16B-aligned (132 -> misaligned b128, 2x regression; Round 2 A/B).
#define MPAD 136

__device__ __forceinline__ void eval_masks(int a, bool m[6]) {
    m[0] = (a == -3); m[1] = (a == -2); m[2] = (a == 3);
    m[3] = (a >= 0) & (a <= 1);
    m[4] = (a >= -1) & (a <= 0);
    m[5] = (a >= -1) & (a <= 1);
}

struct WSmall { const float* p[14]; };
struct PV3  { const _Float16* Wd[3]; const _Float16* Wv[3]; const float* b1[3];
              _Float16* P[3]; _Float16* V[3]; };
struct MLP3 { const _Float16* W2[3]; const float* b2[3];
              const _Float16* P[3]; const _Float16* V[3]; float* AH[3]; };

// ---------------- merged setup: wprep_big | wprep_small | zero(hist+fill) ----------------
__global__ __launch_bounds__(256) void k_setup(
    const float* __restrict__ W011, const float* __restrict__ W012,
    WSmall wsm, _Float16* __restrict__ WT, _Float16* __restrict__ WTs,
    float* __restrict__ hf)
{
    int blk = blockIdx.x, tid = threadIdx.x;
    if (blk < 1024) {                       // wprep_big: 262144 elems
        int idx = blk * 256 + tid;
        int which = idx >> 17;
        int r = idx & 131071;
        int n = r >> 10, k = r & 1023;
        const float* src = which ? W012 : W011;
        WT[idx] = (_Float16)src[k * 128 + n];
    } else if (blk < 1920) {                // wprep_small: 229376 elems
        int idx = (blk - 1024) * 256 + tid;
        int seg = idx >> 14;
        int r = idx & 16383;
        int n = r >> 7, k = r & 127;
        const float* src = wsm.p[seg];
        float v = src[k * 128 + n];
        if (seg < 12 && (seg % 3) == 0) v -= src[16384 + k * 128 + n];
        WTs[idx] = (_Float16)v;
    } else {                                // zero hist+fill: 393216 floats
        size_t i = (size_t)(blk - 1920) * 1024 + (size_t)tid * 4;
        *(float4*)(hf + i) = make_float4(0.f, 0.f, 0.f, 0.f);
    }
}

// ---------------- counting sort phase 1 ----------------
__global__ __launch_bounds__(256) void k_hist(
    const int* __restrict__ attr, const int* __restrict__ edst,
    int* __restrict__ hist)
{
    int e = blockIdx.x * 256 + threadIdx.x;
    int a = attr[e], d = edst[e];
    bool m[6]; eval_masks(a, m);
#pragma unroll
    for (int j = 0; j < 6; ++j)
        if (m[j]) atomicAdd(&hist[j * NNn + d], 1);
}

// ---------------- hierarchical exclusive scan ----------------
__global__ __launch_bounds__(256) void k_scan_a(
    const int* __restrict__ hist, int* __restrict__ base, int* __restrict__ bsum)
{
    __shared__ int wsum[4];
    int idx = blockIdx.x * 256 + threadIdx.x;
    int tid = threadIdx.x, lane = tid & 63, wv = tid >> 6;
    int v = hist[idx];
    int x = v;
#pragma unroll
    for (int off = 1; off < 64; off <<= 1) {
        int y = __shfl_up(x, off, 64);
        if (lane >= off) x += y;
    }
    if (lane == 63) wsum[wv] = x;
    __syncthreads();
    int add = 0;
    for (int w = 0; w < wv; ++w) add += wsum[w];
    base[idx] = add + x - v;
    if (tid == 255) bsum[blockIdx.x] = add + x;
}

__global__ __launch_bounds__(384) void k_scan_b(int* __restrict__ bsum, int* __restrict__ cnts)
{
    int wv = threadIdx.x >> 6;
    int lane = threadIdx.x & 63;
    int run = 0;
#pragma unroll
    for (int c0 = 0; c0 < 128; c0 += 64) {
        int v = bsum[wv * 128 + c0 + lane];
        int x = v;
#pragma unroll
        for (int off = 1; off < 64; off <<= 1) {
            int y = __shfl_up(x, off, 64);
            if (lane >= off) x += y;
        }
        bsum[wv * 128 + c0 + lane] = run + (x - v);
        run += __shfl(x, 63, 64);
    }
    if (lane == 0) cnts[wv] = run;
}

__global__ __launch_bounds__(256) void k_scan_c(int* __restrict__ base, const int* __restrict__ bsum)
{
    base[blockIdx.x * 256 + threadIdx.x] += bsum[blockIdx.x];
}

// ---------------- merged: fill sorted lists | zero AH atomicMax-path rows ----------------
__global__ __launch_bounds__(256) void k_fill_zero(
    const int* __restrict__ esrc, const int* __restrict__ edst,
    const int* __restrict__ attr, const int* __restrict__ base,
    int* __restrict__ fill, int2* __restrict__ arena, const int* __restrict__ hist,
    float* __restrict__ AH0, float* __restrict__ AH1,
    float* __restrict__ AH2, float* __restrict__ AH3)
{
    int blk = blockIdx.x, tid = threadIdx.x;
    if (blk < 1024) {
        int e = blk * 256 + tid;
        int a = attr[e];
        int s = esrc[e], d = edst[e];
        bool m[6]; eval_masks(a, m);
        const int caps[6] = {CAP0, CAP1, CAP2, CAP3, CAP4, CAP5};
        const int offs[6] = {OFF0, OFF1, OFF2, OFF3, OFF4, OFF5};
#pragma unroll
        for (int j = 0; j < 6; ++j) {
            if (m[j]) {
                int pos = base[j * NNn + d] + atomicAdd(&fill[j * NNn + d], 1);
                if (pos < caps[j]) arena[offs[j] + pos] = make_int2(s, d);
            }
        }
    } else {
        int zb = blk - 1024;                  // 0..2047
        int col = tid & 127, sub = tid >> 7;
        const int js[4] = {1, 3, 4, 5};
        float* AHs[4] = {AH0, AH1, AH2, AH3};
        for (int d = zb * 2 + sub; d < NNn; d += 2048 * 2) {
#pragma unroll
            for (int jj = 0; jj < 4; ++jj) {
                int j = js[jj];
                int c = hist[j * NNn + d];
                bool need;
                if (c == 0) need = true;
                else {
                    int b = base[j * NNn + d], e = b + c;
                    need = ((b & 63) == 0) || ((e & 63) == 0) || ((b >> 6) != ((e - 1) >> 6));
                }
                if (need) AHs[jj][(size_t)d * 128 + col] = 0.f;
            }
        }
    }
}

// ---------------- input projection: split-K, dbuf B, raw-f32 depth-2 A pipeline ----
// (R7/R8: plateaued at ~63us — compiler recycles the prefetch registers
// (VGPR_Count stays 64); structural barrier-drain wall. Left as-is.)
__global__ __launch_bounds__(512, 4) void k_proj(
    const float* __restrict__ xv, const float* __restrict__ xa,
    const _Float16* __restrict__ BTv, const _Float16* __restrict__ BTa,
    float* __restrict__ Pp0, float* __restrict__ Pp1)
{
    __shared__ _Float16 Bl[2][128][136];
    const int tid = threadIdx.x, wave = tid >> 6, lane = tid & 63;
    const int tile = blockIdx.x >> 1, kh = blockIdx.x & 1;
    const float* A; const _Float16* BT; int mbase, obase;
    if (tile < 192) { A = xv; BT = BTv; mbase = tile * 128; obase = mbase; }
    else { A = xa; BT = BTa; mbase = (tile - 192) * 128; obase = 24576 + mbase; }
    float* Pout = kh ? Pp1 : Pp0;
    const int kbase = kh * 512;

    const int mrow = mbase + wave * 16 + (lane & 15);
    const int fk   = (lane >> 4) * 8;
    f32x4 acc[8];
#pragma unroll
    for (int i = 0; i < 8; ++i) acc[i] = (f32x4){0,0,0,0};

#define STAGE_B(buf_, kc_) {                                                    \
    _Pragma("unroll")                                                           \
    for (int it = 0; it < 4; ++it) {                                            \
        int c = it * 512 + tid;                                                 \
        int n = c >> 4, koff = (c & 15) * 8;                                    \
        *(f16x8*)&Bl[buf_][n][koff] =                                           \
            *(const f16x8*)(BT + (size_t)n * 1024 + kbase + (kc_) * 128 + koff); \
    } }

#define LOAD_A_RAW(kc_, r0_, r1_) {                                             \
    _Pragma("unroll")                                                           \
    for (int t4 = 0; t4 < 4; ++t4) {                                            \
        const float* asrc = A + (size_t)mrow * 1024 + kbase + (kc_) * 128 + t4 * 32 + fk; \
        r0_[t4] = *(const float4*)asrc;                                         \
        r1_[t4] = *(const float4*)(asrc + 4);                                   \
    } }

#define CVT_A(r0_, r1_, dst_) {                                                 \
    _Pragma("unroll")                                                           \
    for (int t4 = 0; t4 < 4; ++t4)                                              \
        dst_[t4] = (f16x8){ (_Float16)r0_[t4].x, (_Float16)r0_[t4].y,           \
                            (_Float16)r0_[t4].z, (_Float16)r0_[t4].w,           \
                            (_Float16)r1_[t4].x, (_Float16)r1_[t4].y,           \
                            (_Float16)r1_[t4].z, (_Float16)r1_[t4].w };         \
    }

    float4 ra0[4], ra1[4], rb0[4], rb1[4];
    f16x8 af[4];
    LOAD_A_RAW(0, ra0, ra1);     // chunk0 raw (HBM, longest latency, first)
    LOAD_A_RAW(1, rb0, rb1);     // chunk1 raw
    STAGE_B(0, 0);               // B chunk0 (L2)
    CVT_A(ra0, ra1, af);         // af = chunk0 (ra free after this)
    __syncthreads();

#pragma unroll
    for (int kc = 0; kc < 4; ++kc) {
        const int cur = kc & 1;
        if (kc == 0) LOAD_A_RAW(2, ra0, ra1);
        if (kc == 1) LOAD_A_RAW(3, rb0, rb1);
        if (kc < 3) STAGE_B(cur ^ 1, kc + 1);
#pragma unroll
        for (int t4 = 0; t4 < 4; ++t4)
#pragma unroll
            for (int nt = 0; nt < 8; ++nt) {
                f16x8 bf = *(const f16x8*)&Bl[cur][nt * 16 + (lane & 15)][t4 * 32 + fk];
                acc[nt] = __builtin_amdgcn_mfma_f32_16x16x32_f16(af[t4], bf, acc[nt], 0, 0, 0);
            }
        if (kc < 3) {
            if ((kc & 1) == 0) { CVT_A(rb0, rb1, af); }
            else               { CVT_A(ra0, ra1, af); }
        }
        __syncthreads();
    }
#undef STAGE_B
#undef LOAD_A_RAW
#undef CVT_A

    const int cbase = lane & 15, rloc = (lane >> 4) * 4;
    const int wgrp = wave & 3;
    float* Hsf = (float*)&Bl[0][0][0] + (size_t)wgrp * 16 * 132;
#pragma unroll
    for (int grp = 0; grp < 2; ++grp) {
        if ((wave >> 2) == grp) {
#pragma unroll
            for (int nt = 0; nt < 8; ++nt) {
                int c2 = nt * 16 + cbase;
#pragma unroll
                for (int rr = 0; rr < 4; ++rr)
                    Hsf[(rloc + rr) * 132 + c2] = acc[nt][rr];
            }
#pragma unroll
            for (int it = 0; it < 8; ++it) {
                int id = it * 64 + lane;
                int row = id >> 5, off = (id & 31) * 4;
                float4 v = *(float4*)&Hsf[row * 132 + off];
                *(float4*)&Pout[(size_t)(obase + wave * 16 + row) * 128 + off] = v;
            }
        }
        __syncthreads();
    }
}

// ---------------- reduce: X = Pp0 + Pp1 + bias(row) ----------------
__global__ __launch_bounds__(256) void k_reduce(
    const float* __restrict__ Pp0, const float* __restrict__ Pp1,
    const float* __restrict__ b011, const float* __restrict__ b012,
    float* __restrict__ X)
{
    size_t f = (size_t)blockIdx.x * 256 + threadIdx.x;
    size_t i = f * 4;
    int col = (int)(i & 127);
    int row = (int)(i >> 7);
    const float* bias = (row < 24576) ? b011 : b012;
    float4 a = *(const float4*)(Pp0 + i);
    float4 b = *(const float4*)(Pp1 + i);
    float4 bb = *(const float4*)(bias + col);
    *(float4*)(X + i) = make_float4(a.x + b.x + bb.x, a.y + b.y + bb.y,
                                    a.z + b.z + bb.z, a.w + b.w + bb.w);
}

// ---------------- PV GEMM body: 2 tile-teams share one B staging (R8) ----------------
__device__ __forceinline__ void pv_body2(
    const float* __restrict__ A, const _Float16* __restrict__ BT1,
    const float* __restrict__ b1, const _Float16* __restrict__ BT2,
    _Float16* __restrict__ P, _Float16* __restrict__ V, int tile0,
    _Float16 (*Bl1)[136], _Float16 (*Bl2)[136], float* bb)
{
    const int tid = threadIdx.x;          // 0..511
    const int wave = tid >> 6;            // 0..7
    const int lane = tid & 63;
    const int team = wave >> 2;           // 0,1
    const int twave = wave & 3;           // 0..3 within team
    const int r0 = (tile0 + team) * 64 + twave * 16;
    const int fk = (lane >> 4) * 8;
    const int mrow = r0 + (lane & 15);
    float4 a0[4], a1[4];
#pragma unroll
    for (int t4 = 0; t4 < 4; ++t4) {
        const float* asrc = A + (size_t)mrow * 128 + t4 * 32 + fk;
        a0[t4] = *(const float4*)asrc;
        a1[t4] = *(const float4*)(asrc + 4);
    }
#pragma unroll
    for (int it = 0; it < 4; ++it) {
        int c = it * 512 + tid;
        int n = c >> 4, koff = (c & 15) * 8;
        *(f16x8*)&Bl1[n][koff] = *(const f16x8*)(BT1 + (size_t)n * 128 + koff);
        *(f16x8*)&Bl2[n][koff] = *(const f16x8*)(BT2 + (size_t)n * 128 + koff);
    }
    if (tid < 128) bb[tid] = b1[tid];
    __syncthreads();

    f16x8 af[4];
#pragma unroll
    for (int t4 = 0; t4 < 4; ++t4)
        af[t4] = (f16x8){ (_Float16)a0[t4].x, (_Float16)a0[t4].y, (_Float16)a0[t4].z, (_Float16)a0[t4].w,
                          (_Float16)a1[t4].x, (_Float16)a1[t4].y, (_Float16)a1[t4].z, (_Float16)a1[t4].w };
    f32x4 acc1[8], acc2[8];
#pragma unroll
    for (int i = 0; i < 8; ++i) { acc1[i] = (f32x4){0,0,0,0}; acc2[i] = (f32x4){0,0,0,0}; }
#pragma unroll
    for (int t4 = 0; t4 < 4; ++t4)
#pragma unroll
        for (int nt = 0; nt < 8; ++nt) {
            f16x8 bf1 = *(const f16x8*)&Bl1[nt * 16 + (lane & 15)][t4 * 32 + fk];
            f16x8 bf2 = *(const f16x8*)&Bl2[nt * 16 + (lane & 15)][t4 * 32 + fk];
            acc1[nt] = __builtin_amdgcn_mfma_f32_16x16x32_f16(af[t4], bf1, acc1[nt], 0, 0, 0);
            acc2[nt] = __builtin_amdgcn_mfma_f32_16x16x32_f16(af[t4], bf2, acc2[nt], 0, 0, 0);
        }
    __syncthreads();                      // all 8 waves done reading Bl1/Bl2
    _Float16* Hs = &Bl1[0][0] + (size_t)wave * 16 * 136;   // 8 disjoint regions
    const int cbase = lane & 15, rloc = (lane >> 4) * 4;
#pragma unroll
    for (int nt = 0; nt < 8; ++nt) {
        int c2 = nt * 16 + cbase;
        float bvv = bb[c2];
#pragma unroll
        for (int rr = 0; rr < 4; ++rr)
            Hs[(rloc + rr) * 136 + c2] = (_Float16)(acc1[nt][rr] + bvv);
    }
#pragma unroll
    for (int it = 0; it < 4; ++it) {
        int id = it * 64 + lane;
        int row = id >> 4, koff = (id & 15) * 8;
        *(f16x8*)&P[(size_t)(r0 + row) * 128 + koff] = *(f16x8*)&Hs[row * 136 + koff];
    }
#pragma unroll
    for (int nt = 0; nt < 8; ++nt) {
        int c2 = nt * 16 + cbase;
#pragma unroll
        for (int rr = 0; rr < 4; ++rr)
            Hs[(rloc + rr) * 136 + c2] = (_Float16)acc2[nt][rr];
    }
#pragma unroll
    for (int it = 0; it < 4; ++it) {
        int id = it * 64 + lane;
        int row = id >> 4, koff = (id & 15) * 8;
        *(f16x8*)&V[(size_t)(r0 + row) * 128 + koff] = *(f16x8*)&Hs[row * 136 + koff];
    }
}

__global__ __launch_bounds__(512, 4) void k_pv(
    const float* __restrict__ A, const _Float16* __restrict__ BT1,
    const float* __restrict__ b1, const _Float16* __restrict__ BT2,
    _Float16* __restrict__ P, _Float16* __restrict__ V)
{
    __shared__ _Float16 Bl1[128][136];
    __shared__ _Float16 Bl2[128][136];
    __shared__ float bb[128];
    pv_body2(A, BT1, b1, BT2, P, V, blockIdx.x * 2, Bl1, Bl2, bb);
}

// all 3 branches in one dispatch: 768 blocks = branch(3) x pair(256)
__global__ __launch_bounds__(512, 4) void k_pv3(const float* __restrict__ A, PV3 p)
{
    __shared__ _Float16 Bl1[128][136];
    __shared__ _Float16 Bl2[128][136];
    __shared__ float bb[128];
    int b = blockIdx.x >> 8, t0 = (blockIdx.x & 255) * 2;
    pv_body2(A, p.Wd[b], p.b1[b], p.Wv[b], p.P[b], p.V[b], t0, Bl1, Bl2, bb);
}

// ---------------- edge MLP: W2 load (once per 512-thread block) ----------------
__device__ __forceinline__ void mlp_loadW(
    const _Float16* __restrict__ W2T, const float* __restrict__ b2,
    _Float16 (*W2l)[MPAD], float* __restrict__ b2l)
{
    int tid = threadIdx.x;       // 0..511
#pragma unroll
    for (int i = 0; i < 4; ++i) {
        int c = tid + i * 512;
        int n = c >> 4, koff = (c & 15) * 8;
        *(f16x8*)&W2l[n][koff] = *(const f16x8*)(W2T + n * 128 + koff);
    }
    if (tid < 128) b2l[tid] = b2[tid];
}

// ---------------- edge MLP tile body (team-scoped; 256 threads/team) ----------------
// Round 9: VALU-reduction on the two hot phases (edge_mlp3 was VALUBusy 45%,
// MfmaUtil 6% -> VALU-bound). (a) gather ReLU via packed f16 max;
// (b) segmax: 4 group-slots x 64 col-pairs, packed f16x2 max (was 2 slots x
// scalar f32 cvt+max). Col-pair survives the XOR-16 swizzle (bit4 > bit0).
__device__ __forceinline__ void mlp_tile2(
    const _Float16* __restrict__ P, const _Float16* __restrict__ V,
    const int2* __restrict__ list, int cnt, int t, float* __restrict__ agg,
    _Float16 (*Rl)[MPAD], const _Float16 (*W2l)[MPAD], const float* __restrict__ b2l,
    int2* __restrict__ eSD, unsigned char* __restrict__ gstart,
    int* __restrict__ gdst, int* __restrict__ ngrS)
{
    const int tid  = threadIdx.x & 255;      // team-local
    const int wave = tid >> 6;               // 0..3 within team
    const int lane = threadIdx.x & 63;
    if (tid < 64) {
        int e = t * 64 + tid;
        eSD[tid] = (e < cnt) ? list[e] : make_int2(0, -1);
    }
    __syncthreads();
    if (tid < 64) {
        int d = eSD[tid].y;
        bool flag = (tid == 0) || (d != eSD[tid - 1].y);
        unsigned long long bm = __ballot(flag);
        int rank = (int)__popcll(bm & ((1ull << tid) - 1ull));
        if (flag) { gstart[rank] = (unsigned char)tid; gdst[rank] = d; }
        if (tid == 0) {
            int ng = (int)__popcll(bm);
            *ngrS = ng;
            gstart[ng] = 64;
        }
    }
    const int rrow = tid >> 4;
    const int rch  = (tid & 15) * 8;
#pragma unroll
    for (int p = 0; p < 4; ++p) {
        int i = p * 16 + rrow;
        int2 sd = eSD[i];
        f16x8 rv = {0, 0, 0, 0, 0, 0, 0, 0};
        if (sd.y >= 0) {
            f16x8 pv = *(const f16x8*)(P + (size_t)sd.y * 128 + rch);
            f16x8 vv = *(const f16x8*)(V + (size_t)sd.x * 128 + rch);
            rv = pv + vv;
            f16x8 z = {0, 0, 0, 0, 0, 0, 0, 0};
#if __has_builtin(__builtin_elementwise_max)
            rv = __builtin_elementwise_max(rv, z);
#else
#pragma unroll
            for (int q = 0; q < 8; ++q)
                rv[q] = (rv[q] > (_Float16)0.f) ? rv[q] : (_Float16)0.f;
#endif
        }
        *(f16x8*)&Rl[i][rch] = rv;
    }
    __syncthreads();

    const int frow  = wave * 16 + (lane & 15);
    const int fq    = (lane >> 4) * 8;
    f32x4 acc[8];
#pragma unroll
    for (int i = 0; i < 8; ++i) acc[i] = (f32x4){0,0,0,0};
#pragma unroll
    for (int t4 = 0; t4 < 4; ++t4) {
        f16x8 af = *(const f16x8*)&Rl[frow][t4 * 32 + fq];
#pragma unroll
        for (int nt = 0; nt < 8; ++nt) {
            f16x8 bf = *(const f16x8*)&W2l[nt * 16 + (lane & 15)][t4 * 32 + fq];
            acc[nt] = __builtin_amdgcn_mfma_f32_16x16x32_f16(af, bf, acc[nt], 0, 0, 0);
        }
    }
    __syncthreads();
    const int rbase = wave * 16 + (lane >> 4) * 4;
    const int cbase = lane & 15;
#pragma unroll
    for (int nt = 0; nt < 8; ++nt) {
        int c2 = nt * 16 + cbase;
        float bv = b2l[c2];
#pragma unroll
        for (int rr = 0; rr < 4; ++rr) {
            int row = rbase + rr;
            Rl[row][c2 ^ (((row >> 3) & 1) << 4)] = (_Float16)fmaxf(acc[nt][rr] + bv, 0.f);
        }
    }
    __syncthreads();
    // segmax: slot = tid>>6 (4 group slots), pc = even col pair
    const int slot = tid >> 6;
    const int pc   = (tid & 63) * 2;
    int ng = *ngrS;
    for (int g = slot; g < ng; g += 4) {
        int s = gstart[g], e = gstart[g + 1];
        int d = gdst[g];
        if (d < 0) continue;
        f16x2 m2 = {(_Float16)0.f, (_Float16)0.f};
        for (int i = s; i < e; ++i) {
            f16x2 v = *(const f16x2*)&Rl[i][pc ^ (((i >> 3) & 1) << 4)];
#if __has_builtin(__builtin_elementwise_max)
            m2 = __builtin_elementwise_max(m2, v);
#else
            m2[0] = (v[0] > m2[0]) ? v[0] : m2[0];
            m2[1] = (v[1] > m2[1]) ? v[1] : m2[1];
#endif
        }
        float m0 = (float)m2[0], m1 = (float)m2[1];
        size_t o = (size_t)d * 128 + pc;
        if (s == 0 || e == 64) {
            atomicMax((unsigned int*)&agg[o], __float_as_uint(m0));
            atomicMax((unsigned int*)&agg[o + 1], __float_as_uint(m1));
        } else {
            *(float2*)&agg[o] = make_float2(m0, m1);
        }
    }
}

// audio (single mask): 512-thread blocks, 2 tile-teams share one W2 LDS copy
__global__ __launch_bounds__(512, 2) void k_edge_mlp(
    const _Float16* __restrict__ P, const _Float16* __restrict__ V,
    const _Float16* __restrict__ W2T, const float* __restrict__ b2,
    const int2* __restrict__ list, const int* __restrict__ cntp, int cap,
    float* __restrict__ agg)
{
    __shared__ _Float16 W2l[128][MPAD];
    __shared__ float b2l[128];
    __shared__ _Float16 Rl[2][64][MPAD];
    __shared__ int2 eSD[2][64];
    __shared__ unsigned char gstart[2][68];
    __shared__ int gdst[2][64];
    __shared__ int ngrS[2];
    int cnt = min(*cntp, cap);
    int ntiles = (cnt + 63) >> 6;
    if ((int)blockIdx.x * 2 >= ntiles) return;
    mlp_loadW(W2T, b2, W2l, b2l);
    const int team = threadIdx.x >> 8;
    for (int base = blockIdx.x * 2; base < ntiles; base += gridDim.x * 2) {
        mlp_tile2(P, V, list, cnt, base + team, agg,
                  Rl[team], W2l, b2l, eSD[team], gstart[team], gdst[team], &ngrS[team]);
    }
}

// all 3 branch masks: branch-static grid-stride blocks (W2 loaded once/block)
#define MLP3_G0 146
#define MLP3_G1 146
#define MLP3_G2 220
#define MLP3_GRID (MLP3_G0 + MLP3_G1 + MLP3_G2)   // 512

__global__ __launch_bounds__(512, 2) void k_edge_mlp3(
    MLP3 p, const int2* __restrict__ arena, const int* __restrict__ cnts)
{
    __shared__ _Float16 W2l[128][MPAD];
    __shared__ float b2l[128];
    __shared__ _Float16 Rl[2][64][MPAD];
    __shared__ int2 eSD[2][64];
    __shared__ unsigned char gstart[2][68];
    __shared__ int gdst[2][64];
    __shared__ int ngrS[2];
    const int caps[3] = {CAP3, CAP4, CAP5};
    const int offs[3] = {OFF3, OFF4, OFF5};
    int blk = blockIdx.x;
    int b, i, G;
    if (blk < MLP3_G0)                 { b = 0; i = blk;                       G = MLP3_G0; }
    else if (blk < MLP3_G0 + MLP3_G1)  { b = 1; i = blk - MLP3_G0;             G = MLP3_G1; }
    else                               { b = 2; i = blk - (MLP3_G0 + MLP3_G1); G = MLP3_G2; }
    int cnt = min(cnts[3 + b], caps[b]);
    int ntiles = (cnt + 63) >> 6;
    if (i * 2 >= ntiles) return;
    mlp_loadW(p.W2[b], p.b2[b], W2l, b2l);
    const int team = threadIdx.x >> 8;
    const int2* list = arena + offs[b];
    for (int base = i * 2; base < ntiles; base += G * 2) {
        mlp_tile2(p.P[b], p.V[b], list, cnt, base + team, p.AH[b],
                  Rl[team], W2l, b2l, eSD[team], gstart[team], gdst[team], &ngrS[team]);
    }
}

// ---------------- CSR gather-reduce kernels ----------------
__global__ __launch_bounds__(256) void k_csr_vpa(
    const float* __restrict__ X, const int2* __restrict__ list,
    const int* __restrict__ base, const int* __restrict__ cntarr, int cap,
    float* __restrict__ S)
{
    int col = threadIdx.x & 127;
    int sub = threadIdx.x >> 7;
    for (int d = blockIdx.x * 2 + sub; d < NNn; d += gridDim.x * 2) {
        int c = cntarr[d];
        float v = 0.f;
        if (c > 0) {
            int b = base[d];
            int end = min(b + c, cap);
            float mx = -3.0e38f;
            for (int i = b; i < end; ++i)
                mx = fmaxf(mx, X[(size_t)list[i].x * 128 + col]);
            v = fmaxf(X[(size_t)d * 128 + col] + mx, 0.f);
        }
        S[(size_t)d * 128 + col] = v;
    }
}

__global__ __launch_bounds__(256) void k_csr_acv(
    const float* __restrict__ X, const float* __restrict__ ares,
    const int2* __restrict__ list,
    const int* __restrict__ base, const int* __restrict__ cntarr, int cap,
    float* __restrict__ S)
{
    int col = threadIdx.x & 127;
    int sub = threadIdx.x >> 7;
    for (int d = blockIdx.x * 2 + sub; d < NNn; d += gridDim.x * 2) {
        int c = cntarr[d];
        float v = 0.f;
        if (c > 0) {
            int b = base[d];
            int end = min(b + c, cap);
            float s = 0.f;
            for (int i = b; i < end; ++i) {
                int sr = list[i].x;
                s += ares[sr] * X[(size_t)sr * 128 + col];
            }
            v = fmaxf(s + (float)c * X[(size_t)d * 128 + col], 0.f);
        }
        S[(size_t)d * 128 + col] = v;
    }
}

// sage mean at target nodes for all 3 branches in one dispatch
__global__ __launch_bounds__(256) void k_meanc3(
    float* const AH1, float* const AH2, float* const AH3,
    const int2* __restrict__ arena,
    const int* __restrict__ base, const int* __restrict__ hist,
    const int* __restrict__ spk, int ntarg,
    float* __restrict__ S1c, float* __restrict__ AHc)
{
    int col = threadIdx.x & 127;
    int sub = threadIdx.x >> 7;
    int step = spk[0] * TT;
    const int caps[3] = {CAP3, CAP4, CAP5};
    const int offs[3] = {OFF3, OFF4, OFF5};
    const float* AHs[3] = {AH1, AH2, AH3};
    int total = 3 * ntarg;
    for (int ci2 = blockIdx.x * 2 + sub; ci2 < total; ci2 += gridDim.x * 2) {
        int b = ci2 / ntarg;
        int ci = ci2 - b * ntarg;
        int j = 3 + b;
        const float* AH = AHs[b];
        const int2* list = arena + offs[b];
        int d = (ci >> 7) * step + (ci & 127);
        int c = hist[j * NNn + d];
        float v = 0.f;
        if (c > 0) {
            int bs = base[j * NNn + d];
            int end = min(bs + c, caps[b]);
            float s = 0.f;
            for (int i = bs; i < end; ++i)
                s += AH[(size_t)list[i].x * 128 + col];
            v = s / (float)c;
        }
        S1c[(size_t)ci2 * 128 + col] = v;
        AHc[(size_t)ci2 * 128 + col] = AH[(size_t)d * 128 + col];
    }
}

// ---------------- fc ----------------
__global__ __launch_bounds__(256) void k_fc(
    const float* __restrict__ A, const float* __restrict__ W,
    const float* __restrict__ b, float* __restrict__ ares)
{
    int node = blockIdx.x * 4 + (threadIdx.x >> 6);
    int lane = threadIdx.x & 63;
    const float* row = A + (size_t)node * 128;
    float v = row[lane] * W[lane] + row[lane + 64] * W[lane + 64];
#pragma unroll
    for (int off = 32; off > 0; off >>= 1) v += __shfl_down(v, off, 64);
    if (lane == 0) ares[node] = v + b[0];
}

// ---------------- fused SAGE output ----------------
__global__ __launch_bounds__(256) void k_sage_out(
    const float* __restrict__ S1c, const float* __restrict__ AHc,
    const _Float16* __restrict__ WlT, const _Float16* __restrict__ WrT,
    const float* __restrict__ bl, float* __restrict__ out, int ntarg)
{
    __shared__ _Float16 Al[64][40];
    __shared__ _Float16 Bl[128][40];
    const int tid  = threadIdx.x;
    const int wave = tid >> 6;
    const int lane = tid & 63;
    const int m0   = blockIdx.x * 64;

    f32x4 accB[8], accO[8];
#pragma unroll
    for (int i = 0; i < 8; ++i) { accB[i] = (f32x4){0,0,0,0}; accO[i] = (f32x4){0,0,0,0}; }

    const int ar = tid >> 2;
    const int ak = (tid & 3) * 8;
    const int fr = wave * 16 + (lane & 15);
    const int fk = (lane >> 4) * 8;
    const int rbase = wave * 16 + (lane >> 4) * 4;
    const int cbase = lane & 15;

    for (int seg = 0; seg < 6; ++seg) {
        int b = seg >> 1, which = seg & 1;
        const float* A = (which ? AHc : S1c) + (size_t)b * ntarg * 128;
        const _Float16* BT = which ? WrT : WlT;
        for (int k0 = 0; k0 < 128; k0 += 32) {
            __syncthreads();
            const float* asrc = A + (size_t)(m0 + ar) * 128 + (k0 + ak);
            float4 a0 = *(const float4*)asrc;
            float4 a1 = *(const float4*)(asrc + 4);
            f16x8 av = { (_Float16)a0.x, (_Float16)a0.y, (_Float16)a0.z, (_Float16)a0.w,
                         (_Float16)a1.x, (_Float16)a1.y, (_Float16)a1.z, (_Float16)a1.w };
            *(f16x8*)&Al[ar][ak] = av;
#pragma unroll
            for (int i = 0; i < 2; ++i) {
                int c = tid + i * 256;
                int n = c >> 2, koff = (c & 3) * 8;
                *(f16x8*)&Bl[n][koff] = *(const f16x8*)(BT + (size_t)n * 128 + k0 + koff);
            }
            __syncthreads();
            f16x8 af = *(const f16x8*)&Al[fr][fk];
#pragma unroll
            for (int nt = 0; nt < 8; ++nt) {
                f16x8 bf = *(const f16x8*)&Bl[nt * 16 + (lane & 15)][fk];
                accB[nt] = __builtin_amdgcn_mfma_f32_16x16x32_f16(af, bf, accB[nt], 0, 0, 0);
            }
        }
        if (which) {
#pragma unroll
            for (int nt = 0; nt < 8; ++nt) {
                int col = nt * 16 + cbase;
                float bv = bl[col];
#pragma unroll
                for (int rr = 0; rr < 4; ++rr) {
                    accO[nt][rr] += fmaxf(accB[nt][rr] + bv, 0.f);
                    accB[nt][rr] = 0.f;
                }
            }
        }
    }
#pragma unroll
    for (int nt = 0; nt < 8; ++nt) {
        int col = nt * 16 + cbase;
#pragma unroll
        for (int rr = 0; rr < 4; ++rr)
            out[(size_t)(m0 + rbase + rr) * 128 + col] = accO[nt][rr];
    }
}

extern "C" void kernel_launch(void* const* d_in, const int* in_sizes, int n_in,
                              void* d_out, int out_size, void* d_ws, size_t ws_size,
                              hipStream_t stream)
{
    (void)in_sizes; (void)n_in; (void)ws_size;
    const float* xv   = (const float*)d_in[0];
    const float* xa   = (const float*)d_in[1];
    const float* W011 = (const float*)d_in[2];
    const float* b011 = (const float*)d_in[3];
    const float* W012 = (const float*)d_in[4];
    const float* b012 = (const float*)d_in[5];
    const float* ecW1[4] = {(const float*)d_in[6],  (const float*)d_in[10],
                            (const float*)d_in[14], (const float*)d_in[18]};
    const float* ecb1[4] = {(const float*)d_in[7],  (const float*)d_in[11],
                            (const float*)d_in[15], (const float*)d_in[19]};
    const float* ecW2[4] = {(const float*)d_in[8],  (const float*)d_in[12],
                            (const float*)d_in[16], (const float*)d_in[20]};
    const float* ecb2[4] = {(const float*)d_in[9],  (const float*)d_in[13],
                            (const float*)d_in[17], (const float*)d_in[21]};
    const float* sageWl = (const float*)d_in[22];
    const float* sagebl = (const float*)d_in[23];
    const float* sageWr = (const float*)d_in[24];
    const float* fcW    = (const float*)d_in[25];
    const float* fcb    = (const float*)d_in[26];
    const int*   esrc   = (const int*)d_in[27];
    const int*   edst   = esrc + EEe;
    const int*   attr   = (const int*)d_in[28];
    const int*   spk    = (const int*)d_in[29];
    float* out = (float*)d_out;
    const int ntarg = out_size >> 7;       // 8192 target nodes

    const size_t NC = (size_t)NNn * CCc;   // 4194304
    float* ws   = (float*)d_ws;
    float* X    = ws;                      // [N,C] f32; later P1/V1 overlay
    float* S1   = ws + 1 * NC;             // proj partial 0 / vpa out / S1c slices
    float* XV2  = ws + 2 * NC;             // proj partial 1 / xv2
    float* AHc  = ws + 3 * NC;             // P2/V2 overlay, then AH compact snapshots
    float* AH0  = ws + 4 * NC;
    float* AH1  = ws + 5 * NC;
    float* AH2  = ws + 6 * NC;
    float* AH3  = ws + 7 * NC;
    _Float16* P0 = (_Float16*)(ws + 8 * NC);
    _Float16* V0 = P0 + NC;
    _Float16* P1 = (_Float16*)X;           // X dead after csr_acv
    _Float16* V1 = P1 + NC;
    _Float16* P2 = (_Float16*)AHc;         // AHc written only by meanc3 (after mlp3)
    _Float16* V2 = P2 + NC;
    float* ARES = ws + 9 * NC;             // 32768
    int*   cnts = (int*)(ARES + NNn);
    int*   bsum = cnts + 16;
    int*   hist = bsum + 1024;             // 6*32768
    int*   fill = hist + 6 * NNn;
    int*   base = fill + 6 * NNn;
    int2*  arena = (int2*)(base + 6 * NNn);
    _Float16* WT = (_Float16*)(arena + ARENA_TOTAL);

    const _Float16* W011T = WT;
    const _Float16* W012T = WT + 131072;
    _Float16* WTs = WT + 262144;
    const _Float16* WlT   = WTs + 12 * 16384;
    const _Float16* WrT   = WTs + 13 * 16384;

    // ---- merged setup + counting-sort CSR build ----
    WSmall wsm;
    for (int i = 0; i < 4; ++i) {
        wsm.p[3*i + 0] = ecW1[i];
        wsm.p[3*i + 1] = ecW1[i] + 16384;
        wsm.p[3*i + 2] = ecW2[i];
    }
    wsm.p[12] = sageWl; wsm.p[13] = sageWr;
    k_setup<<<2304, 256, 0, stream>>>(W011, W012, wsm, WT, WTs, (float*)hist);
    k_hist<<<EEe / 256, 256, 0, stream>>>(attr, edst, hist);
    k_scan_a<<<768, 256, 0, stream>>>(hist, base, bsum);
    k_scan_b<<<1, 384, 0, stream>>>(bsum, cnts);
    k_scan_c<<<768, 256, 0, stream>>>(base, bsum);
    k_fill_zero<<<3072, 256, 0, stream>>>(esrc, edst, attr, base, fill, arena, hist,
                                          AH0, AH1, AH2, AH3);

    // ---- input projection (split-K, raw-A depth-2 pipeline) + reduce ----
    k_proj<<<512, 512, 0, stream>>>(xv, xa, W011T, W012T, S1, XV2);
    k_reduce<<<(int)(NC / 1024), 256, 0, stream>>>(S1, XV2, b011, b012, X);
    // ---- xa_g (mask 0); S1 fully overwritten ----
    k_csr_vpa<<<2048, 256, 0, stream>>>(X, arena + OFF0, base + 0 * NNn,
                                        hist + 0 * NNn, CAP0, S1);
    // ---- EdgeConv A (mask 1) ----
    k_pv<<<256, 512, 0, stream>>>(S1, WTs, ecb1[0], WTs + 16384, P0, V0);
    k_edge_mlp<<<512, 512, 0, stream>>>(P0, V0, WTs + 2 * 16384, ecb2[0],
                                        arena + OFF1, cnts + 1, CAP1, AH0);
    k_fc<<<NNn / 4, 256, 0, stream>>>(AH0, fcW, fcb, ARES);
    // ---- xv2 (mask 2); XV2 fully overwritten; last read of X ----
    k_csr_acv<<<2048, 256, 0, stream>>>(X, ARES, arena + OFF2, base + 2 * NNn,
                                        hist + 2 * NNn, CAP2, XV2);
    // ---- three branches merged ----
    PV3 pv3;
    MLP3 m3;
    _Float16* Pb[3] = {P0, P1, P2};
    _Float16* Vb[3] = {V0, V1, V2};
    float* AHb[3] = {AH1, AH2, AH3};
    for (int b = 0; b < 3; ++b) {
        _Float16* Wd = WTs + (3 * (b + 1)) * 16384;
        pv3.Wd[b] = Wd; pv3.Wv[b] = Wd + 16384; pv3.b1[b] = ecb1[b + 1];
        pv3.P[b] = Pb[b]; pv3.V[b] = Vb[b];
        m3.W2[b] = Wd + 2 * 16384; m3.b2[b] = ecb2[b + 1];
        m3.P[b] = Pb[b]; m3.V[b] = Vb[b]; m3.AH[b] = AHb[b];
    }
    k_pv3<<<768, 512, 0, stream>>>(XV2, pv3);
    k_edge_mlp3<<<MLP3_GRID, 512, 0, stream>>>(m3, arena, cnts);
    k_meanc3<<<2048, 256, 0, stream>>>(AH1, AH2, AH3, arena, base, hist,
                                       spk, ntarg, S1, AHc);
    // ---- fused SAGE epilogue -> d_out ----
    k_sage_out<<<ntarg / 64, 256, 0, stream>>>(S1, AHc, WlT, WrT, sagebl, out, ntarg);
}